// Round 2
// baseline (2974.044 us; speedup 1.0000x reference)
//
#include <hip/hip_runtime.h>
#include <hip/hip_bf16.h>

typedef unsigned char u8;
typedef long long i64;

#define TT 4
#define BB 32
#define NNN 256
#define CCC 512
#define HHH 8
#define DDD 64
#define PAIRS 8192
#define BNEPS 1e-5f

// Fused GEMM + bias + BN(eval) + LIF(over T) -> u8 spikes.
// A: (T*PAIRS) x K row-major f32.  AMODE 0: f32   1: u8 spikes   2: f32 + u8
// W: K x NC f32 row-major. out: (T*PAIRS) x NC u8.
template<int AMODE>
__global__ __launch_bounds__(256)
void gemm_bn_lif(const float* __restrict__ Af,
                 const u8* __restrict__ Au8,
                 const float* __restrict__ W,
                 const float* __restrict__ bias,
                 const float* __restrict__ gw,
                 const float* __restrict__ bew,
                 const float* __restrict__ muw,
                 const float* __restrict__ varw,
                 u8* __restrict__ outp,
                 int K, int NC, float vth)
{
    __shared__ __align__(16) float As[TT][16][36];   // +pad across pairs
    __shared__ __align__(16) float Ws[32][64];
    const int tid   = threadIdx.x;
    const int c0    = blockIdx.x * 64;
    const int pair0 = blockIdx.y * 16;

    float acc[TT][4];
    #pragma unroll
    for (int t=0;t<TT;t++)
        #pragma unroll
        for (int j=0;j<4;j++) acc[t][j]=0.f;

    const int kk  = tid & 31;
    const int r0  = tid >> 5;   // 0..7
    const int wc  = tid & 63;
    const int wr0 = tid >> 6;   // 0..3
    const int p   = tid >> 4;   // 0..15  (pair within tile)
    const int c4  = (tid & 15) * 4;

    for (int k0 = 0; k0 < K; k0 += 32) {
        #pragma unroll
        for (int i=0;i<8;i++){
            int r = r0 + 8*i;                 // 0..63  = 4t x 16p
            int t = r >> 4, pp = r & 15;
            i64 grow = (i64)t * PAIRS + pair0 + pp;
            i64 idx  = grow * K + k0 + kk;
            float v;
            if (AMODE==0)      v = Af[idx];
            else if (AMODE==1) v = (float)Au8[idx];
            else               v = Af[idx] + (float)Au8[idx];
            As[t][pp][kk] = v;
        }
        #pragma unroll
        for (int i=0;i<8;i++){
            int krow = wr0 + 4*i;             // 0..31
            Ws[krow][wc] = W[(i64)(k0+krow)*NC + c0 + wc];
        }
        __syncthreads();
        #pragma unroll
        for (int k4=0;k4<8;k4++){
            float a[TT][4];
            #pragma unroll
            for (int t=0;t<TT;t++){
                float4 av = *(const float4*)&As[t][p][k4*4];
                a[t][0]=av.x; a[t][1]=av.y; a[t][2]=av.z; a[t][3]=av.w;
            }
            #pragma unroll
            for (int dd=0;dd<4;dd++){
                float4 wv4 = *(const float4*)&Ws[k4*4+dd][c4];
                float wv[4]={wv4.x,wv4.y,wv4.z,wv4.w};
                #pragma unroll
                for (int t=0;t<TT;t++)
                    #pragma unroll
                    for (int j=0;j<4;j++)
                        acc[t][j] = fmaf(a[t][dd], wv[j], acc[t][j]);
            }
        }
        __syncthreads();
    }

    const i64 pair = pair0 + p;
    #pragma unroll
    for (int j=0;j<4;j++){
        int c = c0 + c4 + j;
        float gs  = gw[c] / sqrtf(varw[c] + BNEPS);  // g * rsqrt(var+eps)
        float bf_ = bias[c];
        float muf = muw[c];
        float bef = bew[c];
        float v = 0.f;
        #pragma unroll
        for (int t=0;t<TT;t++){
            float y = acc[t][j] + bf_;
            float z = (y - muf) * gs + bef;
            v = v + (z - v) * 0.5f;                    // v += (x - v)/tau, tau=2
            float s = ((v - vth) >= 0.f) ? 1.f : 0.f;  // spike(v - v_th)
            outp[((i64)t*PAIRS + pair)*NC + c] = (u8)s;
            v = v * (1.f - s);                         // hard reset
        }
    }
}

// Non-softmax spiking attention + attn-LIF (v_th = 0.5), fused per (b, h, n-tile).
// q/k/v spikes stored in (T,B,N,C) layout; head h occupies cols [h*64, h*64+64).
__global__ __launch_bounds__(256)
void attn_lif_kernel(const u8* __restrict__ qs, const u8* __restrict__ ks,
                     const u8* __restrict__ vs, u8* __restrict__ os)
{
    __shared__ __align__(16) float Qs[64][68];
    __shared__ __align__(16) float KAt[64][68];   // K^T tile, then reused as attn tile
    __shared__ __align__(16) float Vs[64][68];
    const int tid = threadIdx.x;
    const int n0  = blockIdx.x * 64;
    const int h   = blockIdx.y;
    const int b   = blockIdx.z;

    const int rn = (tid >> 4) * 4;   // 4 n-rows per thread
    const int cm = (tid & 15) * 4;   // 4 cols per thread (m in QK, d in AV)
    const int d_ = tid & 63;
    const int r4 = tid >> 6;

    float vmem[4][4];
    #pragma unroll
    for (int i=0;i<4;i++)
        #pragma unroll
        for (int j=0;j<4;j++) vmem[i][j]=0.f;

    for (int t=0;t<TT;t++){
        const i64 base = ((i64)(t*BB + b)*NNN)*CCC + h*DDD;
        #pragma unroll
        for (int i=0;i<16;i++){
            int r = r4 + 4*i;
            Qs[r][d_] = (float)qs[base + (i64)(n0+r)*CCC + d_];
        }
        float oacc[4][4];
        #pragma unroll
        for (int i=0;i<4;i++)
            #pragma unroll
            for (int j=0;j<4;j++) oacc[i][j]=0.f;

        for (int mt=0; mt<4; mt++){
            const int m0 = mt*64;
            __syncthreads();                       // Qs staged; prev KAt/Vs reads done
            #pragma unroll
            for (int i=0;i<16;i++){
                int r = r4 + 4*i;
                KAt[d_][r] = (float)ks[base + (i64)(m0+r)*CCC + d_];  // transposed
                Vs[r][d_]  = (float)vs[base + (i64)(m0+r)*CCC + d_];
            }
            __syncthreads();
            float frag[4][4];
            #pragma unroll
            for (int i=0;i<4;i++)
                #pragma unroll
                for (int j=0;j<4;j++) frag[i][j]=0.f;
            #pragma unroll
            for (int d4=0; d4<64; d4+=4){
                float q[4][4];
                #pragma unroll
                for (int i=0;i<4;i++){
                    float4 qv = *(const float4*)&Qs[rn+i][d4];
                    q[i][0]=qv.x;q[i][1]=qv.y;q[i][2]=qv.z;q[i][3]=qv.w;
                }
                #pragma unroll
                for (int dd=0;dd<4;dd++){
                    float4 kv = *(const float4*)&KAt[d4+dd][cm];
                    float kf[4]={kv.x,kv.y,kv.z,kv.w};
                    #pragma unroll
                    for (int i=0;i<4;i++)
                        #pragma unroll
                        for (int j=0;j<4;j++)
                            frag[i][j] = fmaf(q[i][dd], kf[j], frag[i][j]);
                }
            }
            __syncthreads();                       // all QK reads of KAt done
            #pragma unroll
            for (int i=0;i<4;i++)
                #pragma unroll
                for (int j=0;j<4;j++)
                    KAt[rn+i][cm+j] = frag[i][j] * 0.125f;   // attn * SCALE
            __syncthreads();
            #pragma unroll
            for (int m4=0;m4<64;m4+=4){
                float a[4][4];
                #pragma unroll
                for (int i=0;i<4;i++){
                    float4 av = *(const float4*)&KAt[rn+i][m4];
                    a[i][0]=av.x;a[i][1]=av.y;a[i][2]=av.z;a[i][3]=av.w;
                }
                #pragma unroll
                for (int mm=0;mm<4;mm++){
                    float4 vv = *(const float4*)&Vs[m4+mm][cm];
                    float vf[4]={vv.x,vv.y,vv.z,vv.w};
                    #pragma unroll
                    for (int i=0;i<4;i++)
                        #pragma unroll
                        for (int j=0;j<4;j++)
                            oacc[i][j] = fmaf(a[i][mm], vf[j], oacc[i][j]);
                }
            }
        }
        #pragma unroll
        for (int i=0;i<4;i++)
            #pragma unroll
            for (int j=0;j<4;j++){
                float v = vmem[i][j];
                v = v + (oacc[i][j] - v) * 0.5f;
                float s = ((v - 0.5f) >= 0.f) ? 1.f : 0.f;
                os[base + (i64)(n0+rn+i)*CCC + cm+j] = (u8)s;
                vmem[i][j] = v * (1.f - s);
            }
        __syncthreads();
    }
}

// out = (x + o2) + m, two-step rounding to match reference (x1 then x1+m), f32 out
__global__ __launch_bounds__(256)
void final_add(const float* __restrict__ x, const u8* __restrict__ o2,
               const u8* __restrict__ m, float* __restrict__ outp, i64 n)
{
    i64 i = (i64)blockIdx.x * blockDim.x + threadIdx.x;
    if (i < n) {
        float x1 = x[i] + (float)o2[i];
        outp[i] = x1 + (float)m[i];
    }
}

extern "C" void kernel_launch(void* const* d_in, const int* in_sizes, int n_in,
                              void* d_out, int out_size, void* d_ws, size_t ws_size,
                              hipStream_t stream)
{
    (void)in_sizes; (void)n_in; (void)out_size; (void)ws_size;
    const float* x = (const float*)d_in[0];
    #define GETP(i) ((const float*)d_in[i])

    u8* ws = (u8*)d_ws;
    const i64 SZ = (i64)16777216;        // T*B*N*C
    u8* qs  = ws;                        // [0, SZ)
    u8* ks_ = ws + SZ;                   // [SZ, 2SZ)
    u8* vs_ = ws + 2*SZ;                 // [2SZ, 3SZ)
    u8* os_ = ws + 3*SZ;                 // [3SZ, 4SZ)
    u8* o2  = ws;                        // reuse qs (dead after attn)
    u8* hh  = ws + SZ;                   // 4*SZ bytes, reuse ks/vs/os (dead)
    u8* mm  = ws + 5*SZ;                 // [5SZ, 6SZ)

    dim3 blk(256,1,1);
    // q, k, v stages (A = x f32)
    gemm_bn_lif<0><<<dim3(8,512,1),blk,0,stream>>>(x, nullptr,
        GETP(1),GETP(2),GETP(3),GETP(4),GETP(5),GETP(6),  qs, 512, 512, 1.0f);
    gemm_bn_lif<0><<<dim3(8,512,1),blk,0,stream>>>(x, nullptr,
        GETP(7),GETP(8),GETP(9),GETP(10),GETP(11),GETP(12), ks_, 512, 512, 1.0f);
    gemm_bn_lif<0><<<dim3(8,512,1),blk,0,stream>>>(x, nullptr,
        GETP(13),GETP(14),GETP(15),GETP(16),GETP(17),GETP(18), vs_, 512, 512, 1.0f);
    // spiking attention + attn_lif (v_th = 0.5)
    attn_lif_kernel<<<dim3(4,8,32),blk,0,stream>>>(qs, ks_, vs_, os_);
    // p stage (A = attn spikes u8)
    gemm_bn_lif<1><<<dim3(8,512,1),blk,0,stream>>>(nullptr, os_,
        GETP(19),GETP(20),GETP(21),GETP(22),GETP(23),GETP(24), o2, 512, 512, 1.0f);
    // f1 stage (A = x + o2)
    gemm_bn_lif<2><<<dim3(32,512,1),blk,0,stream>>>(x, o2,
        GETP(25),GETP(26),GETP(27),GETP(28),GETP(29),GETP(30), hh, 512, 2048, 1.0f);
    // f2 stage (A = h spikes u8, K = 2048)
    gemm_bn_lif<1><<<dim3(8,512,1),blk,0,stream>>>(nullptr, hh,
        GETP(31),GETP(32),GETP(33),GETP(34),GETP(35),GETP(36), mm, 2048, 512, 1.0f);
    // out = (x + o2) + m
    final_add<<<dim3(65536,1,1),blk,0,stream>>>(x, o2, mm, (float*)d_out, SZ);
}

// Round 3
// 1186.878 us; speedup vs baseline: 2.5058x; 2.5058x over previous
//
#include <hip/hip_runtime.h>

typedef unsigned char u8;
typedef unsigned short u16;
typedef unsigned int u32;
typedef unsigned long long u64;
typedef long long i64;

#define TT 4
#define PAIRS 8192
#define BNEPS 1e-5f

typedef __attribute__((ext_vector_type(8))) __bf16 bf16x8;
typedef __attribute__((ext_vector_type(4))) float f32x4;

__device__ __forceinline__ float bf2f(u16 b){ return __uint_as_float(((u32)b)<<16); }
__device__ __forceinline__ u16 f2bf_rne(float f){ u32 u = __float_as_uint(f); return (u16)((u + 0x7FFFu + ((u>>16)&1u))>>16); }
__device__ __forceinline__ u16 f2bf_tr(float f){ return (u16)(__float_as_uint(f)>>16); }

// w = h + m + l + eps, |eps| <= 2^-23 |w|  (truncation splits; subs are Sterbenz-exact)
__device__ __forceinline__ void split3(float v, u16& h, u16& m, u16& l){
    h = f2bf_tr(v); float r  = v - bf2f(h);
    m = f2bf_tr(r); float r2 = r - bf2f(m);
    l = f2bf_tr(r2);
}

__device__ __forceinline__ f32x4 MFMA(bf16x8 a, bf16x8 b, f32x4 c){
    return __builtin_amdgcn_mfma_f32_16x16x32_bf16(a, b, c, 0, 0, 0);
}

union BF8 { u16 u[8]; bf16x8 v; };

// XOR swizzles (row-stride in bytes: 64 / 128 / 256)
__device__ __forceinline__ int swzA(int row, int off){ return row*64  + (off ^ ((row&3)<<4)); }
__device__ __forceinline__ int swzK(int row, int off){ return row*128 + (off ^ ((row&7)<<4)); }
__device__ __forceinline__ int swzV(int row, int off){ return row*256 + (off ^ ((row&7)<<4)); }

// ---------------- W split+transpose prep: W [K][NC] f32 -> 3 planes WT [NC][K] bf16
__global__ __launch_bounds__(256)
void wsplit_kernel(const float* __restrict__ W, u16* __restrict__ out, int K, int NC)
{
    __shared__ float tile[64][65];
    const int k0 = blockIdx.x*64, c0 = blockIdx.y*64;
    const int tid = threadIdx.x;
    #pragma unroll
    for (int j=0;j<16;j++){
        int el = tid + j*256; int r = el>>6, c = el&63;
        tile[r][c] = W[(i64)(k0+r)*NC + c0 + c];
    }
    __syncthreads();
    const i64 NCK = (i64)NC*K;
    #pragma unroll
    for (int j=0;j<16;j++){
        int el = tid + j*256; int c = el>>6, k = el&63;
        float v = tile[k][c];
        u16 h,m,l; split3(v,h,m,l);
        i64 idx = (i64)(c0+c)*K + k0 + k;
        out[idx] = h; out[NCK+idx] = m; out[2*NCK+idx] = l;
    }
}

// ---------------- Fused GEMM + bias + BN + LIF -> spikes (u8 or bitpacked)
// AMODE: 0 = f32 A (split3 on the fly), 2 = fl(f32 + u8) split3,
//        1 = u8 spikes (exact bf16), 3 = bitpacked spikes (exact)
template<int AMODE, bool BITOUT>
__global__ __launch_bounds__(256)
void gemm_bn_lif(const float* __restrict__ Af, const u8* __restrict__ Au8,
                 const u8* __restrict__ Abits,
                 const u16* __restrict__ WT,
                 const float* __restrict__ bias, const float* __restrict__ gw,
                 const float* __restrict__ bew,  const float* __restrict__ muw,
                 const float* __restrict__ varw,
                 u8* __restrict__ outp, int K, int NC, float vth)
{
    constexpr int NSPL = (AMODE==0 || AMODE==2) ? 3 : 1;
    __shared__ __align__(16) char smem[NSPL*8192 + 3*4096];
    char* smA = smem;
    char* smB = smem + NSPL*8192;

    const int tid = threadIdx.x;
    const int c0    = blockIdx.x * 64;
    const int pair0 = blockIdx.y * 32;
    const int w  = tid>>6, l = tid&63, g = l>>4, ln = l&15;
    const int wp = w>>1, wc = w&1;
    const i64 NCK = (i64)NC*K;

    f32x4 acc[TT][2];
    #pragma unroll
    for (int t=0;t<TT;t++){ acc[t][0] = (f32x4)0.f; acc[t][1] = (f32x4)0.f; }

    for (int k0 = 0; k0 < K; k0 += 32){
        __syncthreads();
        // ---- stage A (128 rows = 4t x 32 pairs, 32 k)
        {
            const int row = tid>>1;
            const int t = row>>5, pp = row&31;
            const i64 grow = (i64)t*PAIRS + pair0 + pp;
            if (AMODE==0 || AMODE==2){
                const int ks = (tid&1)*16;
                const float* src = Af + grow*K + k0 + ks;
                float vv[16];
                #pragma unroll
                for (int q=0;q<4;q++){ float4 f = *(const float4*)(src + q*4);
                    vv[q*4]=f.x; vv[q*4+1]=f.y; vv[q*4+2]=f.z; vv[q*4+3]=f.w; }
                if (AMODE==2){
                    uint4 ob = *(const uint4*)(Au8 + grow*K + k0 + ks);
                    const u8* pb = (const u8*)&ob;
                    #pragma unroll
                    for (int j=0;j<16;j++) vv[j] = vv[j] + (float)pb[j];
                }
                u16 hs[16], ms[16], ls[16];
                #pragma unroll
                for (int j=0;j<16;j++) split3(vv[j], hs[j], ms[j], ls[j]);
                #pragma unroll
                for (int q=0;q<4;q++){
                    int off = swzA(row, ks*2 + q*8);
                    *(ushort4*)(smA + off)          = make_ushort4(hs[q*4],hs[q*4+1],hs[q*4+2],hs[q*4+3]);
                    *(ushort4*)(smA + 8192  + off)  = make_ushort4(ms[q*4],ms[q*4+1],ms[q*4+2],ms[q*4+3]);
                    *(ushort4*)(smA + 16384 + off)  = make_ushort4(ls[q*4],ls[q*4+1],ls[q*4+2],ls[q*4+3]);
                }
            } else if (AMODE==1){
                const int ks = (tid&1)*16;
                uint4 ob = *(const uint4*)(Au8 + grow*K + k0 + ks);
                const u8* pb = (const u8*)&ob;
                #pragma unroll
                for (int q=0;q<4;q++){
                    u16 b0 = pb[q*4]?0x3F80:0, b1 = pb[q*4+1]?0x3F80:0, b2 = pb[q*4+2]?0x3F80:0, b3 = pb[q*4+3]?0x3F80:0;
                    *(ushort4*)(smA + swzA(row, ks*2 + q*8)) = make_ushort4(b0,b1,b2,b3);
                }
            } else { // AMODE==3: bitpacked, K/8 bytes per row
                const int half = tid&1;
                u16 v16 = *(const u16*)(Abits + grow*(K>>3) + (k0>>3) + half*2);
                #pragma unroll
                for (int q=0;q<4;q++){
                    u16 b0 = (v16>>(q*4  ))&1 ? 0x3F80:0;
                    u16 b1 = (v16>>(q*4+1))&1 ? 0x3F80:0;
                    u16 b2 = (v16>>(q*4+2))&1 ? 0x3F80:0;
                    u16 b3 = (v16>>(q*4+3))&1 ? 0x3F80:0;
                    *(ushort4*)(smA + swzA(row, half*32 + q*8)) = make_ushort4(b0,b1,b2,b3);
                }
            }
        }
        // ---- stage B: 3 planes x 64 cols x 32 k from pre-split/transposed WT
        #pragma unroll
        for (int j=0;j<3;j++){
            int cid = tid + j*256;
            int s = cid>>8, rem = cid&255, col = rem>>2, q = rem&3;
            uint4 d = *(const uint4*)(WT + (i64)s*NCK + (i64)(c0+col)*K + k0 + q*8);
            *(uint4*)(smB + s*4096 + swzA(col, q*16)) = d;
        }
        __syncthreads();

        bf16x8 bfr[NSPL][2];
        #pragma unroll
        for (int s=0;s<NSPL;s++)
            #pragma unroll
            for (int cf=0;cf<2;cf++)
                bfr[s][cf] = *(const bf16x8*)(smB + s*4096 + swzA(wc*32 + cf*16 + ln, g*16));

        #pragma unroll
        for (int t=0;t<TT;t++){
            bf16x8 afr[NSPL];
            #pragma unroll
            for (int s=0;s<NSPL;s++)
                afr[s] = *(const bf16x8*)(smA + s*8192 + swzA(t*32 + wp*16 + ln, g*16));
            #pragma unroll
            for (int cf=0;cf<2;cf++){
                f32x4 a = acc[t][cf];
                a = MFMA(afr[0], bfr[0][cf], a);
                if (NSPL==3){
                    a = MFMA(afr[0], bfr[1][cf], a);
                    a = MFMA(afr[1], bfr[0][cf], a);
                    a = MFMA(afr[1], bfr[1][cf], a);
                    a = MFMA(afr[0], bfr[2][cf], a);
                    a = MFMA(afr[2], bfr[0][cf], a);
                }
                acc[t][cf] = a;
            }
        }
    }

    // ---- epilogue: bias + BN + LIF over t
    #pragma unroll
    for (int cf=0;cf<2;cf++){
        const int c = c0 + wc*32 + cf*16 + ln;
        const float gs  = gw[c] / sqrtf(varw[c] + BNEPS);
        const float bf_ = bias[c], muf = muw[c], bef = bew[c];
        #pragma unroll
        for (int r=0;r<4;r++){
            const i64 pairR = pair0 + wp*16 + g*4 + r;
            float v = 0.f;
            #pragma unroll
            for (int t=0;t<TT;t++){
                float y = acc[t][cf][r] + bf_;
                float z = (y - muf) * gs + bef;
                v = v + (z - v) * 0.5f;
                float s = ((v - vth) >= 0.f) ? 1.f : 0.f;
                if (BITOUT){
                    u64 bal = __ballot(s != 0.f);
                    if (ln == 0){
                        i64 rowG = (i64)t*PAIRS + pair0 + wp*16 + g*4 + r;
                        *(u16*)(outp + rowG*(NC>>3) + ((c0 + wc*32 + cf*16)>>3)) = (u16)(bal >> (g*16));
                    }
                } else {
                    outp[((i64)t*PAIRS + pairR)*NC + c] = (u8)s;
                }
                v = v * (1.f - s);
            }
        }
    }
}

// ---------------- Spiking attention + attn-LIF (v_th=0.5), exact bf16-MFMA
__global__ __launch_bounds__(256)
void attn_lif_kernel(const u8* __restrict__ qs, const u8* __restrict__ ks,
                     const u8* __restrict__ vs, u8* __restrict__ os)
{
    __shared__ __align__(16) char smem[49152];
    char* Kl = smem;            // [128 m][64 d] bf16, swzK
    char* VT = smem + 16384;    // [64 d][128 m] bf16, swzV
    char* AT = smem + 32768;    // [64 n][128 m] bf16, swzV

    const int tid = threadIdx.x;
    const int w = tid>>6, l = tid&63, g = l>>4, ln = l&15;
    const int h = blockIdx.y, b = blockIdx.z;
    const int n0 = blockIdx.x*64 + w*16;       // wave's 16 q-rows

    f32x4 vmem[4];
    #pragma unroll
    for (int cf=0;cf<4;cf++) vmem[cf] = (f32x4)0.f;

    for (int t=0;t<TT;t++){
        const i64 tb = ((i64)(t*32 + b)*256)*512 + h*64;
        // Q fragments (B-operand): direct from global, exact cvt
        bf16x8 qf[2];
        #pragma unroll
        for (int ksl=0;ksl<2;ksl++){
            uint2 qv = *(const uint2*)(qs + tb + (i64)(n0+ln)*512 + ksl*32 + g*8);
            const u8* pb = (const u8*)&qv;
            BF8 f;
            #pragma unroll
            for (int j=0;j<8;j++) f.u[j] = pb[j] ? 0x3F80 : 0;
            qf[ksl] = f.v;
        }
        f32x4 oacc[4];
        #pragma unroll
        for (int cf=0;cf<4;cf++) oacc[cf] = (f32x4)0.f;

        for (int mh=0; mh<2; mh++){
            __syncthreads();
            // stage K half [128][64]
            {
                const int lm = tid>>1, seg = tid&1;
                const u8* src = ks + tb + (i64)(mh*128+lm)*512 + seg*32;
                uint4 a = *(const uint4*)(src), c = *(const uint4*)(src+16);
                const u8* pa = (const u8*)&a; const u8* pc = (const u8*)&c;
                #pragma unroll
                for (int q=0;q<4;q++){
                    *(ushort4*)(Kl + swzK(lm, seg*64 + q*8)) =
                        make_ushort4(pa[q*4]?0x3F80:0, pa[q*4+1]?0x3F80:0, pa[q*4+2]?0x3F80:0, pa[q*4+3]?0x3F80:0);
                    *(ushort4*)(Kl + swzK(lm, seg*64 + 32 + q*8)) =
                        make_ushort4(pc[q*4]?0x3F80:0, pc[q*4+1]?0x3F80:0, pc[q*4+2]?0x3F80:0, pc[q*4+3]?0x3F80:0);
                }
            }
            // stage V half transposed: VT[d][m]
            {
                const int lm = tid>>1, seg = tid&1;
                const u8* src = vs + tb + (i64)(mh*128+lm)*512 + seg*32;
                uint4 a = *(const uint4*)(src), c = *(const uint4*)(src+16);
                const u8* pa = (const u8*)&a; const u8* pc = (const u8*)&c;
                #pragma unroll
                for (int j=0;j<16;j++){
                    *(u16*)(VT + swzV(seg*32 + j,      lm*2)) = pa[j] ? 0x3F80 : 0;
                    *(u16*)(VT + swzV(seg*32 + 16 + j, lm*2)) = pc[j] ? 0x3F80 : 0;
                }
            }
            __syncthreads();
            // QK^T (S^T tiles): A = K rows (m), B = Q -> out col = own n
            #pragma unroll
            for (int rf=0;rf<8;rf++){
                f32x4 s = (f32x4)0.f;
                #pragma unroll
                for (int ksl=0;ksl<2;ksl++){
                    bf16x8 kf = *(const bf16x8*)(Kl + swzK(rf*16+ln, ksl*64 + g*16));
                    s = MFMA(kf, qf[ksl], s);
                }
                // attn = S * 0.125 (exact) -> AT[n][m]
                ushort4 pk = make_ushort4(f2bf_rne(s[0]*0.125f), f2bf_rne(s[1]*0.125f),
                                          f2bf_rne(s[2]*0.125f), f2bf_rne(s[3]*0.125f));
                *(ushort4*)(AT + swzV(w*16+ln, rf*32 + g*8)) = pk;
            }
            // AV: o += attn[n][m] * V[m][d]
            #pragma unroll
            for (int ms=0;ms<4;ms++){
                bf16x8 af = *(const bf16x8*)(AT + swzV(w*16+ln, ms*64 + g*16));
                #pragma unroll
                for (int cf=0;cf<4;cf++){
                    bf16x8 vf = *(const bf16x8*)(VT + swzV(cf*16+ln, ms*64 + g*16));
                    oacc[cf] = MFMA(af, vf, oacc[cf]);
                }
            }
        }
        // attn-LIF (v_th = 0.5) + spike store
        #pragma unroll
        for (int cf=0;cf<4;cf++)
            #pragma unroll
            for (int r=0;r<4;r++){
                float v = vmem[cf][r];
                float o = oacc[cf][r];
                v = v + (o - v) * 0.5f;
                float s = ((v - 0.5f) >= 0.f) ? 1.f : 0.f;
                const int n = n0 + g*4 + r;
                os[tb + (i64)n*512 + cf*16 + ln] = (u8)s;
                vmem[cf][r] = v * (1.f - s);
            }
    }
}

// ---------------- out = (x + o2) + m
__global__ __launch_bounds__(256)
void final_add4(const float4* __restrict__ x, const u32* __restrict__ o2,
                const u32* __restrict__ m, float4* __restrict__ outp, int n4)
{
    int i = blockIdx.x * blockDim.x + threadIdx.x;
    if (i < n4){
        float4 xv = x[i]; u32 a = o2[i], c = m[i];
        float4 r;
        r.x = (xv.x + (float)( a      & 255u)) + (float)( c      & 255u);
        r.y = (xv.y + (float)((a>> 8) & 255u)) + (float)((c>> 8) & 255u);
        r.z = (xv.z + (float)((a>>16) & 255u)) + (float)((c>>16) & 255u);
        r.w = (xv.w + (float)((a>>24) & 255u)) + (float)((c>>24) & 255u);
        outp[i] = r;
    }
}

extern "C" void kernel_launch(void* const* d_in, const int* in_sizes, int n_in,
                              void* d_out, int out_size, void* d_ws, size_t ws_size,
                              hipStream_t stream)
{
    (void)in_sizes; (void)n_in; (void)out_size; (void)ws_size;
    const float* x = (const float*)d_in[0];
    #define GETP(i) ((const float*)d_in[i])

    char* ws = (char*)d_ws;
    const i64 SZ = 16777216;
    // W^T split planes (bf16 u16): q,k,v,p: 512*512*2*3 = 1572864 B each; f1,f2: 6291456 B
    u16* WTq  = (u16*)(ws + 0);
    u16* WTk  = (u16*)(ws + 1572864);
    u16* WTv  = (u16*)(ws + 3145728);
    u16* WTp  = (u16*)(ws + 4718592);
    u16* WTf1 = (u16*)(ws + 6291456);
    u16* WTf2 = (u16*)(ws + 12582912);
    u8* qs  = (u8*)(ws + 18874368);
    u8* ks_ = qs + SZ;
    u8* vs_ = ks_ + SZ;
    u8* os_ = (u8*)(ws + 18874368 + 3*SZ);        // separate: alive while p runs
    u8* o2  = qs;                                  // reuse (qs dead after attn)
    u8* hhb = ks_;                                 // bitpacked 8.4 MB (ks dead)
    u8* mm  = vs_;                                 // (vs dead)

    dim3 blk(256,1,1);
    // W prep: split + transpose
    wsplit_kernel<<<dim3(8,8),  blk,0,stream>>>(GETP(1),  WTq, 512, 512);
    wsplit_kernel<<<dim3(8,8),  blk,0,stream>>>(GETP(7),  WTk, 512, 512);
    wsplit_kernel<<<dim3(8,8),  blk,0,stream>>>(GETP(13), WTv, 512, 512);
    wsplit_kernel<<<dim3(8,8),  blk,0,stream>>>(GETP(19), WTp, 512, 512);
    wsplit_kernel<<<dim3(8,32), blk,0,stream>>>(GETP(25), WTf1, 512, 2048);
    wsplit_kernel<<<dim3(32,8), blk,0,stream>>>(GETP(31), WTf2, 2048, 512);

    // q, k, v stages (A = x f32, split on the fly)
    gemm_bn_lif<0,false><<<dim3(8,256),blk,0,stream>>>(x, nullptr, nullptr, WTq,
        GETP(2),GETP(3),GETP(4),GETP(5),GETP(6),  qs, 512, 512, 1.0f);
    gemm_bn_lif<0,false><<<dim3(8,256),blk,0,stream>>>(x, nullptr, nullptr, WTk,
        GETP(8),GETP(9),GETP(10),GETP(11),GETP(12), ks_, 512, 512, 1.0f);
    gemm_bn_lif<0,false><<<dim3(8,256),blk,0,stream>>>(x, nullptr, nullptr, WTv,
        GETP(14),GETP(15),GETP(16),GETP(17),GETP(18), vs_, 512, 512, 1.0f);
    // attention (exact)
    attn_lif_kernel<<<dim3(4,8,32),blk,0,stream>>>(qs, ks_, vs_, os_);
    // p stage (A = os spikes u8)
    gemm_bn_lif<1,false><<<dim3(8,256),blk,0,stream>>>(nullptr, os_, nullptr, WTp,
        GETP(20),GETP(21),GETP(22),GETP(23),GETP(24), o2, 512, 512, 1.0f);
    // f1 stage (A = fl(x + o2), split on the fly; bitpacked output)
    gemm_bn_lif<2,true><<<dim3(32,256),blk,0,stream>>>(x, o2, nullptr, WTf1,
        GETP(26),GETP(27),GETP(28),GETP(29),GETP(30), hhb, 512, 2048, 1.0f);
    // f2 stage (A = hh bits, K = 2048)
    gemm_bn_lif<3,false><<<dim3(8,256),blk,0,stream>>>(nullptr, nullptr, hhb, WTf2,
        GETP(32),GETP(33),GETP(34),GETP(35),GETP(36), mm, 2048, 512, 1.0f);
    // out = (x + o2) + m
    final_add4<<<dim3(16384),blk,0,stream>>>((const float4*)x, (const u32*)o2,
        (const u32*)mm, (float4*)d_out, (int)(SZ/4));
}

// Round 4
// 1125.705 us; speedup vs baseline: 2.6419x; 1.0543x over previous
//
#include <hip/hip_runtime.h>

typedef unsigned char u8;
typedef unsigned short u16;
typedef unsigned int u32;
typedef unsigned long long u64;
typedef long long i64;

#define TT 4
#define PAIRS 8192          // global pairs (B*N)
#define PH 4096             // pairs per half
#define BNEPS 1e-5f

typedef __attribute__((ext_vector_type(8))) __bf16 bf16x8;
typedef __attribute__((ext_vector_type(4))) float f32x4;

__device__ __forceinline__ float bf2f(u16 b){ return __uint_as_float(((u32)b)<<16); }
__device__ __forceinline__ u16 f2bf_rne(float f){ u32 u = __float_as_uint(f); return (u16)((u + 0x7FFFu + ((u>>16)&1u))>>16); }
__device__ __forceinline__ u16 f2bf_tr(float f){ return (u16)(__float_as_uint(f)>>16); }

// w = h + m + l + eps, |eps| <= 2^-23 |w|
__device__ __forceinline__ void split3(float v, u16& h, u16& m, u16& l){
    h = f2bf_tr(v); float r  = v - bf2f(h);
    m = f2bf_tr(r); float r2 = r - bf2f(m);
    l = f2bf_tr(r2);
}

__device__ __forceinline__ f32x4 MFMA(bf16x8 a, bf16x8 b, f32x4 c){
    return __builtin_amdgcn_mfma_f32_16x16x32_bf16(a, b, c, 0, 0, 0);
}

union BF8 { u16 u[8]; bf16x8 v; };

// conflict-free swizzle for 64B-row tiles: 8-lane beats cover all 32 banks
__device__ __forceinline__ int swz(int row, int off){ return row*64 + (off ^ (((row>>1)&3)<<4)); }
// attn swizzles (row strides 128 / 256 bytes) — validated in round 3
__device__ __forceinline__ int swzK(int row, int off){ return row*128 + (off ^ ((row&7)<<4)); }
__device__ __forceinline__ int swzV(int row, int off){ return row*256 + (off ^ ((row&7)<<4)); }

__device__ __forceinline__ uint4 expand8(const u8* pb){
    u32 w0 = (pb[0]?0x3F80u:0u) | ((pb[1]?0x3F80u:0u)<<16);
    u32 w1 = (pb[2]?0x3F80u:0u) | ((pb[3]?0x3F80u:0u)<<16);
    u32 w2 = (pb[4]?0x3F80u:0u) | ((pb[5]?0x3F80u:0u)<<16);
    u32 w3 = (pb[6]?0x3F80u:0u) | ((pb[7]?0x3F80u:0u)<<16);
    return make_uint4(w0,w1,w2,w3);
}
__device__ __forceinline__ uint4 expandbits(u32 bits){
    u32 w0 = ((bits>>0)&1?0x3F80u:0u) | ((bits>>1)&1?0x3F800000u:0u);
    u32 w1 = ((bits>>2)&1?0x3F80u:0u) | ((bits>>3)&1?0x3F800000u:0u);
    u32 w2 = ((bits>>4)&1?0x3F80u:0u) | ((bits>>5)&1?0x3F800000u:0u);
    u32 w3 = ((bits>>6)&1?0x3F80u:0u) | ((bits>>7)&1?0x3F800000u:0u);
    return make_uint4(w0,w1,w2,w3);
}

// ---------------- W split+transpose prep: W [K][NC] f32 -> 3 planes WT [NC][K] bf16
__global__ __launch_bounds__(256)
void wsplit_kernel(const float* __restrict__ W, u16* __restrict__ out, int K, int NC)
{
    __shared__ float tile[64][65];
    const int k0 = blockIdx.x*64, c0 = blockIdx.y*64;
    const int tid = threadIdx.x;
    #pragma unroll
    for (int j=0;j<16;j++){
        int el = tid + j*256; int r = el>>6, c = el&63;
        tile[r][c] = W[(i64)(k0+r)*NC + c0 + c];
    }
    __syncthreads();
    const i64 NCK = (i64)NC*K;
    #pragma unroll
    for (int j=0;j<16;j++){
        int el = tid + j*256; int c = el>>6, k = el&63;
        float v = tile[k][c];
        u16 h,m,l; split3(v,h,m,l);
        i64 idx = (i64)(c0+c)*K + k0 + k;
        out[idx] = h; out[NCK+idx] = m; out[2*NCK+idx] = l;
    }
}

// ---------------- A split prep: local half (4t x PH pairs x 512) -> 3 bf16 planes
template<bool WITH_O2>
__global__ __launch_bounds__(256)
void asplit_kernel(const float* __restrict__ x, const u8* __restrict__ o2,
                   u16* __restrict__ out, int pairBase)
{
    const i64 PLANE = (i64)TT*PH*512;
    i64 i = ((i64)blockIdx.x*256 + threadIdx.x)*8;    // local elem idx
    int t = (int)(i >> 21);
    i64 gi = i + ((i64)t*PH + pairBase)*512;          // global elem idx
    float4 f0 = *(const float4*)(x+gi), f1v = *(const float4*)(x+gi+4);
    float vv[8] = {f0.x,f0.y,f0.z,f0.w,f1v.x,f1v.y,f1v.z,f1v.w};
    if (WITH_O2){
        uint2 ob = *(const uint2*)(o2 + i);
        const u8* pb = (const u8*)&ob;
        #pragma unroll
        for (int j=0;j<8;j++) vv[j] = vv[j] + (float)pb[j];
    }
    u16 h[8],m[8],l[8];
    #pragma unroll
    for (int j=0;j<8;j++) split3(vv[j], h[j], m[j], l[j]);
    u32 wh[4], wm[4], wl[4];
    #pragma unroll
    for (int q=0;q<4;q++){
        wh[q] = (u32)h[2*q] | ((u32)h[2*q+1]<<16);
        wm[q] = (u32)m[2*q] | ((u32)m[2*q+1]<<16);
        wl[q] = (u32)l[2*q] | ((u32)l[2*q+1]<<16);
    }
    *(uint4*)&out[i]           = make_uint4(wh[0],wh[1],wh[2],wh[3]);
    *(uint4*)&out[PLANE+i]     = make_uint4(wm[0],wm[1],wm[2],wm[3]);
    *(uint4*)&out[2*PLANE+i]   = make_uint4(wl[0],wl[1],wl[2],wl[3]);
}

// ---------------- Fused GEMM + bias + BN + LIF -> spikes
// ASRC: 0 = pre-split bf16 planes (3, exact-split path), 1 = u8 spikes, 3 = bitpacked spikes
// Block: 128 rows (4t x 32 pairs) x 128 cols, 4 waves (2M x 2N), wave = 64x64.
template<int ASRC, bool BITOUT>
__global__ __launch_bounds__(256)
void gemm_bn_lif(const u16* __restrict__ Ap, const u8* __restrict__ Au8,
                 const u8* __restrict__ Abits,
                 const u16* __restrict__ WT,
                 const float* __restrict__ bias, const float* __restrict__ gw,
                 const float* __restrict__ bew,  const float* __restrict__ muw,
                 const float* __restrict__ varw,
                 u8* __restrict__ outp, int K, int NC, float vth)
{
    constexpr int NSPL = (ASRC==0) ? 3 : 1;
    __shared__ __align__(16) char smem[NSPL*16384];
    char* smA = smem;
    char* smB = smem + NSPL*8192;

    const int tid = threadIdx.x;
    const int c0    = blockIdx.x * 128;
    const int pair0 = blockIdx.y * 32;
    const int w  = tid>>6, l = tid&63, g = l>>4, ln = l&15;
    const int wm = w>>1, wn = w&1;
    const i64 NCK = (i64)NC*K;
    const i64 APLANE = (i64)TT*PH*K;

    f32x4 acc[TT][4];
    #pragma unroll
    for (int t=0;t<TT;t++)
        #pragma unroll
        for (int cf=0;cf<4;cf++) acc[t][cf] = (f32x4)0.f;

    for (int k0 = 0; k0 < K; k0 += 32){
        __syncthreads();
        // ---- stage A: 128 rows x 32 k (bf16)
        if (ASRC==0){
            #pragma unroll
            for (int j=0;j<6;j++){
                int cid = tid + j*256;            // 0..1535 = 3 planes x 128 rows x 4 chunks
                int s = cid>>9, rem = cid&511, row = rem>>2, c = rem&3;
                int t = row>>5, pp = row&31;
                i64 grow = (i64)t*PH + pair0 + pp;
                uint4 d = *(const uint4*)(Ap + s*APLANE + grow*K + k0 + c*8);
                *(uint4*)(smA + s*8192 + swz(row, c*16)) = d;
            }
        } else if (ASRC==1){
            const int row = tid>>1, half = tid&1;
            const int t = row>>5, pp = row&31;
            const i64 grow = (i64)t*PH + pair0 + pp;
            uint4 ob = *(const uint4*)(Au8 + grow*K + k0 + half*16);
            const u8* pb = (const u8*)&ob;
            *(uint4*)(smA + swz(row, half*32))      = expand8(pb);
            *(uint4*)(smA + swz(row, half*32+16))   = expand8(pb+8);
        } else {
            const int row = tid>>1, half = tid&1;
            const int t = row>>5, pp = row&31;
            const i64 grow = (i64)t*PH + pair0 + pp;
            u32 bits = *(const u16*)(Abits + grow*(K>>3) + (k0>>3) + half*2);
            *(uint4*)(smA + swz(row, half*32))      = expandbits(bits);
            *(uint4*)(smA + swz(row, half*32+16))   = expandbits(bits>>8);
        }
        // ---- stage B: NSPL planes x 128 cols x 32 k from WT
        #pragma unroll
        for (int j=0;j<NSPL*2;j++){
            int cid = tid + j*256;                // 0..NSPL*512-1
            int s = cid>>9, rem = cid&511, col = rem>>2, c = rem&3;
            uint4 d = *(const uint4*)(WT + (i64)s*NCK + (i64)(c0+col)*K + k0 + c*8);
            *(uint4*)(smB + s*8192 + swz(col, c*16)) = d;
        }
        __syncthreads();

        bf16x8 bfr[NSPL][4];
        #pragma unroll
        for (int s=0;s<NSPL;s++)
            #pragma unroll
            for (int cf=0;cf<4;cf++)
                bfr[s][cf] = *(const bf16x8*)(smB + s*8192 + swz(wn*64 + cf*16 + ln, g*16));

        #pragma unroll
        for (int t=0;t<TT;t++){
            bf16x8 afr[NSPL];
            #pragma unroll
            for (int s=0;s<NSPL;s++)
                afr[s] = *(const bf16x8*)(smA + s*8192 + swz(t*32 + wm*16 + ln, g*16));
            #pragma unroll
            for (int cf=0;cf<4;cf++){
                f32x4 a = acc[t][cf];
                a = MFMA(afr[0], bfr[0][cf], a);
                if (NSPL==3){
                    a = MFMA(afr[0], bfr[1][cf], a);
                    a = MFMA(afr[1], bfr[0][cf], a);
                    a = MFMA(afr[1], bfr[1][cf], a);
                    a = MFMA(afr[0], bfr[2][cf], a);
                    a = MFMA(afr[2], bfr[0][cf], a);
                }
                acc[t][cf] = a;
            }
        }
    }

    // ---- epilogue: bias + BN + LIF over t (local-pair output)
    #pragma unroll
    for (int cf=0;cf<4;cf++){
        const int c = c0 + wn*64 + cf*16 + ln;
        const float gs  = gw[c] / sqrtf(varw[c] + BNEPS);
        const float bf_ = bias[c], muf = muw[c], bef = bew[c];
        #pragma unroll
        for (int r=0;r<4;r++){
            const int prow = pair0 + wm*16 + g*4 + r;
            float v = 0.f;
            #pragma unroll
            for (int t=0;t<TT;t++){
                float y = acc[t][cf][r] + bf_;
                float z = (y - muf) * gs + bef;
                v = v + (z - v) * 0.5f;
                float s = ((v - vth) >= 0.f) ? 1.f : 0.f;
                if (BITOUT){
                    u64 bal = __ballot(s != 0.f);
                    if (ln == 0){
                        i64 rowG = (i64)t*PH + prow;
                        *(u16*)(outp + rowG*(NC>>3) + ((c0 + wn*64 + cf*16)>>3)) = (u16)(bal >> (g*16));
                    }
                } else {
                    outp[((i64)t*PH + prow)*NC + c] = (u8)s;
                }
                v = v * (1.f - s);
            }
        }
    }
}

// ---------------- Spiking attention + attn-LIF (v_th=0.5), exact bf16-MFMA, local half (16 b)
__global__ __launch_bounds__(256)
void attn_lif_kernel(const u8* __restrict__ qs, const u8* __restrict__ ks,
                     const u8* __restrict__ vs, u8* __restrict__ os)
{
    __shared__ __align__(16) char smem[49152];
    char* Kl = smem;            // [128 m][64 d] bf16, swzK
    char* VT = smem + 16384;    // [64 d][128 m] bf16, swzV
    char* AT = smem + 32768;    // [64 n][128 m] bf16, swzV

    const int tid = threadIdx.x;
    const int w = tid>>6, l = tid&63, g = l>>4, ln = l&15;
    const int h = blockIdx.y, b = blockIdx.z;
    const int n0 = blockIdx.x*64 + w*16;

    f32x4 vmem[4];
    #pragma unroll
    for (int cf=0;cf<4;cf++) vmem[cf] = (f32x4)0.f;

    for (int t=0;t<TT;t++){
        const i64 tb = ((i64)(t*16 + b)*256)*512 + h*64;
        bf16x8 qf[2];
        #pragma unroll
        for (int ksl=0;ksl<2;ksl++){
            uint2 qv = *(const uint2*)(qs + tb + (i64)(n0+ln)*512 + ksl*32 + g*8);
            const u8* pb = (const u8*)&qv;
            BF8 f;
            #pragma unroll
            for (int j=0;j<8;j++) f.u[j] = pb[j] ? 0x3F80 : 0;
            qf[ksl] = f.v;
        }
        f32x4 oacc[4];
        #pragma unroll
        for (int cf=0;cf<4;cf++) oacc[cf] = (f32x4)0.f;

        for (int mh=0; mh<2; mh++){
            __syncthreads();
            {
                const int lm = tid>>1, seg = tid&1;
                const u8* src = ks + tb + (i64)(mh*128+lm)*512 + seg*32;
                uint4 a = *(const uint4*)(src), c = *(const uint4*)(src+16);
                const u8* pa = (const u8*)&a; const u8* pc = (const u8*)&c;
                #pragma unroll
                for (int q=0;q<4;q++){
                    *(ushort4*)(Kl + swzK(lm, seg*64 + q*8)) =
                        make_ushort4(pa[q*4]?0x3F80:0, pa[q*4+1]?0x3F80:0, pa[q*4+2]?0x3F80:0, pa[q*4+3]?0x3F80:0);
                    *(ushort4*)(Kl + swzK(lm, seg*64 + 32 + q*8)) =
                        make_ushort4(pc[q*4]?0x3F80:0, pc[q*4+1]?0x3F80:0, pc[q*4+2]?0x3F80:0, pc[q*4+3]?0x3F80:0);
                }
            }
            {
                const int lm = tid>>1, seg = tid&1;
                const u8* src = vs + tb + (i64)(mh*128+lm)*512 + seg*32;
                uint4 a = *(const uint4*)(src), c = *(const uint4*)(src+16);
                const u8* pa = (const u8*)&a; const u8* pc = (const u8*)&c;
                #pragma unroll
                for (int j=0;j<16;j++){
                    *(u16*)(VT + swzV(seg*32 + j,      lm*2)) = pa[j] ? 0x3F80 : 0;
                    *(u16*)(VT + swzV(seg*32 + 16 + j, lm*2)) = pc[j] ? 0x3F80 : 0;
                }
            }
            __syncthreads();
            #pragma unroll
            for (int rf=0;rf<8;rf++){
                f32x4 s = (f32x4)0.f;
                #pragma unroll
                for (int ksl=0;ksl<2;ksl++){
                    bf16x8 kf = *(const bf16x8*)(Kl + swzK(rf*16+ln, ksl*64 + g*16));
                    s = MFMA(kf, qf[ksl], s);
                }
                ushort4 pk = make_ushort4(f2bf_rne(s[0]*0.125f), f2bf_rne(s[1]*0.125f),
                                          f2bf_rne(s[2]*0.125f), f2bf_rne(s[3]*0.125f));
                *(ushort4*)(AT + swzV(w*16+ln, rf*32 + g*8)) = pk;
            }
            #pragma unroll
            for (int ms=0;ms<4;ms++){
                bf16x8 af = *(const bf16x8*)(AT + swzV(w*16+ln, ms*64 + g*16));
                #pragma unroll
                for (int cf=0;cf<4;cf++){
                    bf16x8 vf = *(const bf16x8*)(VT + swzV(cf*16+ln, ms*64 + g*16));
                    oacc[cf] = MFMA(af, vf, oacc[cf]);
                }
            }
        }
        #pragma unroll
        for (int cf=0;cf<4;cf++)
            #pragma unroll
            for (int r=0;r<4;r++){
                float v = vmem[cf][r];
                float o = oacc[cf][r];
                v = v + (o - v) * 0.5f;
                float s = ((v - 0.5f) >= 0.f) ? 1.f : 0.f;
                const int n = n0 + g*4 + r;
                os[tb + (i64)n*512 + cf*16 + ln] = (u8)s;
                vmem[cf][r] = v * (1.f - s);
            }
    }
}

// ---------------- out = (x + o2) + m  (local half -> global)
__global__ __launch_bounds__(256)
void final_add4(const float4* __restrict__ x, const u32* __restrict__ o2,
                const u32* __restrict__ m, float4* __restrict__ outp, int pairBase)
{
    i64 i4 = (i64)blockIdx.x*256 + threadIdx.x;       // local float4 idx < 2097152
    int t = (int)(i4 >> 19);
    i64 gi4 = i4 + ((i64)t*PH + pairBase)*128;
    float4 xv = x[gi4]; u32 a = o2[i4], c = m[i4];
    float4 r;
    r.x = (xv.x + (float)( a      & 255u)) + (float)( c      & 255u);
    r.y = (xv.y + (float)((a>> 8) & 255u)) + (float)((c>> 8) & 255u);
    r.z = (xv.z + (float)((a>>16) & 255u)) + (float)((c>>16) & 255u);
    r.w = (xv.w + (float)((a>>24) & 255u)) + (float)((c>>24) & 255u);
    outp[gi4] = r;
}

extern "C" void kernel_launch(void* const* d_in, const int* in_sizes, int n_in,
                              void* d_out, int out_size, void* d_ws, size_t ws_size,
                              hipStream_t stream)
{
    (void)in_sizes; (void)n_in; (void)out_size; (void)ws_size;
    const float* x = (const float*)d_in[0];
    #define GETP(i) ((const float*)d_in[i])

    char* ws = (char*)d_ws;
    u16* WTq  = (u16*)(ws + 0);
    u16* WTk  = (u16*)(ws + 1572864);
    u16* WTv  = (u16*)(ws + 3145728);
    u16* WTp  = (u16*)(ws + 4718592);
    u16* WTf1 = (u16*)(ws + 6291456);
    u16* WTf2 = (u16*)(ws + 12582912);
    u16* Ax   = (u16*)(ws + 18874368);            // 3 planes x 8388608 bf16 = 50331648 B
    u8* qs  = (u8*)(ws + 69206016);               // 8388608 each
    u8* ks_ = (u8*)(ws + 77594624);
    u8* vs_ = (u8*)(ws + 85983232);
    u8* os_ = (u8*)(ws + 94371840);
    u8* o2  = qs;                                 // reuse
    u8* hhb = ks_;                                // bitpacked 4 MB
    u8* mm  = vs_;

    dim3 blk(256,1,1);
    wsplit_kernel<<<dim3(8,8),  blk,0,stream>>>(GETP(1),  WTq, 512, 512);
    wsplit_kernel<<<dim3(8,8),  blk,0,stream>>>(GETP(7),  WTk, 512, 512);
    wsplit_kernel<<<dim3(8,8),  blk,0,stream>>>(GETP(13), WTv, 512, 512);
    wsplit_kernel<<<dim3(8,8),  blk,0,stream>>>(GETP(19), WTp, 512, 512);
    wsplit_kernel<<<dim3(8,32), blk,0,stream>>>(GETP(25), WTf1, 512, 2048);
    wsplit_kernel<<<dim3(32,8), blk,0,stream>>>(GETP(31), WTf2, 2048, 512);

    for (int hb = 0; hb < 2; hb++){
        const int pb = hb * PH;
        asplit_kernel<false><<<dim3(4096),blk,0,stream>>>(x, nullptr, Ax, pb);
        gemm_bn_lif<0,false><<<dim3(4,128),blk,0,stream>>>(Ax, nullptr, nullptr, WTq,
            GETP(2),GETP(3),GETP(4),GETP(5),GETP(6),  qs, 512, 512, 1.0f);
        gemm_bn_lif<0,false><<<dim3(4,128),blk,0,stream>>>(Ax, nullptr, nullptr, WTk,
            GETP(8),GETP(9),GETP(10),GETP(11),GETP(12), ks_, 512, 512, 1.0f);
        gemm_bn_lif<0,false><<<dim3(4,128),blk,0,stream>>>(Ax, nullptr, nullptr, WTv,
            GETP(14),GETP(15),GETP(16),GETP(17),GETP(18), vs_, 512, 512, 1.0f);
        attn_lif_kernel<<<dim3(4,8,16),blk,0,stream>>>(qs, ks_, vs_, os_);
        gemm_bn_lif<1,false><<<dim3(4,128),blk,0,stream>>>(nullptr, os_, nullptr, WTp,
            GETP(20),GETP(21),GETP(22),GETP(23),GETP(24), o2, 512, 512, 1.0f);
        asplit_kernel<true><<<dim3(4096),blk,0,stream>>>(x, o2, Ax, pb);
        gemm_bn_lif<0,true><<<dim3(16,128),blk,0,stream>>>(Ax, nullptr, nullptr, WTf1,
            GETP(26),GETP(27),GETP(28),GETP(29),GETP(30), hhb, 512, 2048, 1.0f);
        gemm_bn_lif<3,false><<<dim3(4,128),blk,0,stream>>>(nullptr, nullptr, hhb, WTf2,
            GETP(32),GETP(33),GETP(34),GETP(35),GETP(36), mm, 2048, 512, 1.0f);
        final_add4<<<dim3(8192),blk,0,stream>>>((const float4*)x, (const u32*)o2,
            (const u32*)mm, (float4*)d_out, pb);
    }
}

// Round 5
// 709.394 us; speedup vs baseline: 4.1924x; 1.5869x over previous
//
#include <hip/hip_runtime.h>

typedef unsigned char u8;
typedef unsigned short u16;
typedef unsigned int u32;
typedef unsigned long long u64;
typedef long long i64;

#define TT 4
#define PH 4096             // pairs per half
#define KSW 16              // K/32 for tiled-image GEMMs (K=512)
#define BNEPS 1e-5f

typedef __attribute__((ext_vector_type(8))) __bf16 bf16x8;
typedef __attribute__((ext_vector_type(4))) float f32x4;

__device__ __forceinline__ float bf2f(u16 b){ return __uint_as_float(((u32)b)<<16); }
__device__ __forceinline__ u16 f2bf_rne(float f){ u32 u = __float_as_uint(f); return (u16)((u + 0x7FFFu + ((u>>16)&1u))>>16); }
__device__ __forceinline__ u16 f2bf_tr(float f){ return (u16)(__float_as_uint(f)>>16); }

__device__ __forceinline__ void split2(float v, u16& h, u16& m){
    h = f2bf_tr(v); m = f2bf_tr(v - bf2f(h));
}
__device__ __forceinline__ void split3(float v, u16& h, u16& m, u16& l){
    h = f2bf_tr(v); float r  = v - bf2f(h);
    m = f2bf_tr(r); float r2 = r - bf2f(m);
    l = f2bf_tr(r2);
}

__device__ __forceinline__ f32x4 MFMA(bf16x8 a, bf16x8 b, f32x4 c){
    return __builtin_amdgcn_mfma_f32_16x16x32_bf16(a, b, c, 0, 0, 0);
}

union BF8 { u16 u[8]; bf16x8 v; };

// async global->LDS, 16B per lane
__device__ __forceinline__ void gload16(const void* g, void* l){
    __builtin_amdgcn_global_load_lds(
        (const __attribute__((address_space(1))) unsigned int*)g,
        (__attribute__((address_space(3))) unsigned int*)l, 16, 0, 0);
}

// swizzles used by the reg-staged kernels (validated rounds 3-4)
__device__ __forceinline__ int swz(int row, int off){ return row*64 + (off ^ (((row>>1)&3)<<4)); }
__device__ __forceinline__ int swzK(int row, int off){ return row*128 + (off ^ ((row&7)<<4)); }
__device__ __forceinline__ int swzV(int row, int off){ return row*256 + (off ^ ((row&7)<<4)); }

__device__ __forceinline__ uint4 expand8(const u8* pb){
    u32 w0 = (pb[0]?0x3F80u:0u) | ((pb[1]?0x3F80u:0u)<<16);
    u32 w1 = (pb[2]?0x3F80u:0u) | ((pb[3]?0x3F80u:0u)<<16);
    u32 w2 = (pb[4]?0x3F80u:0u) | ((pb[5]?0x3F80u:0u)<<16);
    u32 w3 = (pb[6]?0x3F80u:0u) | ((pb[7]?0x3F80u:0u)<<16);
    return make_uint4(w0,w1,w2,w3);
}
__device__ __forceinline__ uint4 expandbits(u32 bits){
    u32 w0 = ((bits>>0)&1?0x3F80u:0u) | ((bits>>1)&1?0x3F800000u:0u);
    u32 w1 = ((bits>>2)&1?0x3F80u:0u) | ((bits>>3)&1?0x3F800000u:0u);
    u32 w2 = ((bits>>4)&1?0x3F80u:0u) | ((bits>>5)&1?0x3F800000u:0u);
    u32 w3 = ((bits>>6)&1?0x3F80u:0u) | ((bits>>7)&1?0x3F800000u:0u);
    return make_uint4(w0,w1,w2,w3);
}

// ---------------- W -> tiled LDS images: [nb][ks][plane(h,m)][g][col 0..127][16B]
__global__ __launch_bounds__(256)
void wsplit2(const float* __restrict__ W, u8* __restrict__ out, int NC, int nbOff)
{
    const int ks = blockIdx.x, nbl = blockIdx.y;
    const int c0 = nbl*128;
    u8* img = out + ((i64)(nbOff+nbl)*KSW + ks)*16384;
    #pragma unroll
    for (int it=0; it<2; it++){
        int chunk = threadIdx.x + it*256;        // 0..511 = 4g x 128col
        int gq = chunk>>7, col = chunk&127;
        float v[8];
        #pragma unroll
        for (int j=0;j<8;j++) v[j] = W[(i64)(ks*32 + gq*8 + j)*NC + c0 + col];
        u16 h[8], m[8];
        #pragma unroll
        for (int j=0;j<8;j++) split2(v[j], h[j], m[j]);
        int off = gq*2048 + col*16;
        *(ushort4*)(img + off)          = make_ushort4(h[0],h[1],h[2],h[3]);
        *(ushort4*)(img + off + 8)      = make_ushort4(h[4],h[5],h[6],h[7]);
        *(ushort4*)(img + 8192 + off)   = make_ushort4(m[0],m[1],m[2],m[3]);
        *(ushort4*)(img + 8192 + off+8) = make_ushort4(m[4],m[5],m[6],m[7]);
    }
}

// ---------------- old-style W split (for reg-staged p/f2 kernels): [NC][K] planes
__global__ __launch_bounds__(256)
void wsplit_old(const float* __restrict__ W, u16* __restrict__ out, int K, int NC)
{
    __shared__ float tile[64][65];
    const int k0 = blockIdx.x*64, c0 = blockIdx.y*64;
    const int tid = threadIdx.x;
    #pragma unroll
    for (int j=0;j<16;j++){
        int el = tid + j*256; int r = el>>6, c = el&63;
        tile[r][c] = W[(i64)(k0+r)*NC + c0 + c];
    }
    __syncthreads();
    #pragma unroll
    for (int j=0;j<16;j++){
        int el = tid + j*256; int c = el>>6, k = el&63;
        u16 h,m,l; split3(tile[k][c],h,m,l);
        out[(i64)(c0+c)*K + k0 + k] = h;    // only h-plane consumed (proven safe r3/r4)
    }
}

// ---------------- A -> tiled images: [pb][ks][plane(h,m)][g][row 0..127][16B], row = t*32+pl
template<bool WITH_O2>
__global__ __launch_bounds__(256)
void asplitT(const float* __restrict__ x, const u8* __restrict__ o2,
             u8* __restrict__ At, int pairBase)
{
    const int pb = blockIdx.x, ks = blockIdx.y;
    u8* img = At + ((i64)pb*KSW + ks)*16384;
    #pragma unroll
    for (int it=0; it<2; it++){
        int chunk = threadIdx.x + it*256;        // 0..511 = 4g x 128row
        int gq = chunk>>7, row = chunk&127;
        int t = row>>5, pl = row&31;
        i64 grow = (i64)t*8192 + pairBase + pb*32 + pl;
        const float* src = x + grow*512 + ks*32 + gq*8;
        float4 f0 = *(const float4*)src, f1v = *(const float4*)(src+4);
        float vv[8] = {f0.x,f0.y,f0.z,f0.w,f1v.x,f1v.y,f1v.z,f1v.w};
        if (WITH_O2){
            i64 lrow = (i64)t*PH + pb*32 + pl;
            uint2 ob = *(const uint2*)(o2 + lrow*512 + ks*32 + gq*8);
            const u8* pbб = (const u8*)&ob;
            #pragma unroll
            for (int j=0;j<8;j++) vv[j] = vv[j] + (float)pbб[j];
        }
        u16 h[8], m[8];
        #pragma unroll
        for (int j=0;j<8;j++) split2(vv[j], h[j], m[j]);
        int off = gq*2048 + row*16;
        *(ushort4*)(img + off)          = make_ushort4(h[0],h[1],h[2],h[3]);
        *(ushort4*)(img + off + 8)      = make_ushort4(h[4],h[5],h[6],h[7]);
        *(ushort4*)(img + 8192 + off)   = make_ushort4(m[0],m[1],m[2],m[3]);
        *(ushort4*)(img + 8192 + off+8) = make_ushort4(m[4],m[5],m[6],m[7]);
    }
}

// ---------------- main GEMM: tiled images, gload_lds, dbuf, 3-product split, +BN+LIF
// block 256 (4 waves 2Mx2N), tile 128 rows (4t x 32 pairs) x 128 cols, K_STEP 32
template<bool BITOUT>
__global__ __launch_bounds__(256)
void gemm3(const u8* __restrict__ At, const u8* __restrict__ Bt,
           const float* __restrict__ b0, const float* __restrict__ b1, const float* __restrict__ b2,
           const float* __restrict__ g0, const float* __restrict__ g1, const float* __restrict__ g2,
           const float* __restrict__ e0, const float* __restrict__ e1, const float* __restrict__ e2,
           const float* __restrict__ u0, const float* __restrict__ u1, const float* __restrict__ u2,
           const float* __restrict__ v0, const float* __restrict__ v1, const float* __restrict__ v2,
           u8* __restrict__ outp, int NCT, int cmask)
{
    __shared__ __align__(16) char smem[65536];       // 2 x (A 16K + B 16K)
    const int tid = threadIdx.x;
    const int nb = blockIdx.x, pb = blockIdx.y;
    const int w = tid>>6, lane = tid&63, g = lane>>4, ln = lane&15;
    const int wm = w>>1, wn = w&1;

    f32x4 acc[TT][4];
    #pragma unroll
    for (int t=0;t<TT;t++)
        #pragma unroll
        for (int cf=0;cf<4;cf++) acc[t][cf] = (f32x4)0.f;

    const u8* Abase = At + ((i64)pb*KSW)*16384;
    const u8* Bbase = Bt + ((i64)nb*KSW)*16384;

    // prologue: stage ks=0 into buf0
    #pragma unroll
    for (int i=0;i<4;i++){
        int c = i*4 + w;
        gload16(Abase + c*1024 + lane*16, smem + c*1024);
        gload16(Bbase + c*1024 + lane*16, smem + 16384 + c*1024);
    }
    __syncthreads();

    for (int ks=0; ks<KSW; ks++){
        char* cur = smem + (ks&1)*32768;
        if (ks+1 < KSW){
            char* nxt = smem + ((ks+1)&1)*32768;
            const u8* Ai = Abase + (i64)(ks+1)*16384;
            const u8* Bi = Bbase + (i64)(ks+1)*16384;
            #pragma unroll
            for (int i=0;i<4;i++){
                int c = i*4 + w;
                gload16(Ai + c*1024 + lane*16, nxt + c*1024);
                gload16(Bi + c*1024 + lane*16, nxt + 16384 + c*1024);
            }
        }
        bf16x8 bfr[2][4];
        #pragma unroll
        for (int s=0;s<2;s++)
            #pragma unroll
            for (int cf=0;cf<4;cf++)
                bfr[s][cf] = *(const bf16x8*)(cur + 16384 + s*8192 + g*2048 + (wn*64 + cf*16 + ln)*16);
        #pragma unroll
        for (int t=0;t<TT;t++){
            int arow = t*32 + wm*16 + ln;
            bf16x8 a0 = *(const bf16x8*)(cur + g*2048 + arow*16);
            bf16x8 a1 = *(const bf16x8*)(cur + 8192 + g*2048 + arow*16);
            #pragma unroll
            for (int cf=0;cf<4;cf++){
                f32x4 a = acc[t][cf];
                a = MFMA(a0, bfr[0][cf], a);
                a = MFMA(a0, bfr[1][cf], a);
                a = MFMA(a1, bfr[0][cf], a);
                acc[t][cf] = a;
            }
        }
        __syncthreads();
    }

    // epilogue: bias + BN + LIF over t
    const int cbase = nb*128 + wn*64;
    #pragma unroll
    for (int cf=0;cf<4;cf++){
        const int c = cbase + cf*16 + ln;
        int which = c >> 9; if (which > 2) which = 2;
        const float* bp = which==0?b0:(which==1?b1:b2);
        const float* gp = which==0?g0:(which==1?g1:g2);
        const float* ep = which==0?e0:(which==1?e1:e2);
        const float* up = which==0?u0:(which==1?u1:u2);
        const float* vp = which==0?v0:(which==1?v1:v2);
        const int ci = c & cmask;
        const float gs  = gp[ci] / sqrtf(vp[ci] + BNEPS);
        const float bf_ = bp[ci], muf = up[ci], bef = ep[ci];
        #pragma unroll
        for (int r=0;r<4;r++){
            const int prow = pb*32 + wm*16 + g*4 + r;
            float v = 0.f;
            #pragma unroll
            for (int t=0;t<TT;t++){
                float y = acc[t][cf][r] + bf_;
                float z = (y - muf) * gs + bef;
                v = v + (z - v) * 0.5f;
                float s = ((v - 1.0f) >= 0.f) ? 1.f : 0.f;
                if (BITOUT){
                    u64 bal = __ballot(s != 0.f);
                    if (ln == 0){
                        i64 rowG = (i64)t*PH + prow;
                        *(u16*)(outp + rowG*(NCT>>3) + ((cbase + cf*16)>>3)) = (u16)(bal >> (g*16));
                    }
                } else {
                    outp[((i64)t*PH + prow)*NCT + c] = (u8)s;
                }
                v = v * (1.f - s);
            }
        }
    }
}

// ---------------- spike-input GEMM (p: u8 spikes / f2: bitpacked), reg-staged, h-plane W
template<bool BITS>
__global__ __launch_bounds__(256)
void gemm_sp(const u8* __restrict__ Au8, const u16* __restrict__ WT,
             const float* __restrict__ bias, const float* __restrict__ gw,
             const float* __restrict__ bew,  const float* __restrict__ muw,
             const float* __restrict__ varw,
             u8* __restrict__ outp, int K, int NC)
{
    __shared__ __align__(16) char smem[16384];
    char* smA = smem;
    char* smB = smem + 8192;
    const int tid = threadIdx.x;
    const int c0    = blockIdx.x * 128;
    const int pair0 = blockIdx.y * 32;
    const int w  = tid>>6, l = tid&63, g = l>>4, ln = l&15;
    const int wm = w>>1, wn = w&1;

    f32x4 acc[TT][4];
    #pragma unroll
    for (int t=0;t<TT;t++)
        #pragma unroll
        for (int cf=0;cf<4;cf++) acc[t][cf] = (f32x4)0.f;

    for (int k0 = 0; k0 < K; k0 += 32){
        __syncthreads();
        {
            const int row = tid>>1, half = tid&1;
            const int t = row>>5, pp = row&31;
            const i64 grow = (i64)t*PH + pair0 + pp;
            if (!BITS){
                uint4 ob = *(const uint4*)(Au8 + grow*K + k0 + half*16);
                const u8* pb = (const u8*)&ob;
                *(uint4*)(smA + swz(row, half*32))    = expand8(pb);
                *(uint4*)(smA + swz(row, half*32+16)) = expand8(pb+8);
            } else {
                u32 bits = *(const u16*)(Au8 + grow*(K>>3) + (k0>>3) + half*2);
                *(uint4*)(smA + swz(row, half*32))    = expandbits(bits);
                *(uint4*)(smA + swz(row, half*32+16)) = expandbits(bits>>8);
            }
        }
        #pragma unroll
        for (int j=0;j<2;j++){
            int cid = tid + j*256;
            int col = cid>>2, c = cid&3;
            uint4 d = *(const uint4*)(WT + (i64)(c0+col)*K + k0 + c*8);
            *(uint4*)(smB + swz(col, c*16)) = d;
        }
        __syncthreads();

        bf16x8 bfr[4];
        #pragma unroll
        for (int cf=0;cf<4;cf++)
            bfr[cf] = *(const bf16x8*)(smB + swz(wn*64 + cf*16 + ln, g*16));
        #pragma unroll
        for (int t=0;t<TT;t++){
            bf16x8 afr = *(const bf16x8*)(smA + swz(t*32 + wm*16 + ln, g*16));
            #pragma unroll
            for (int cf=0;cf<4;cf++)
                acc[t][cf] = MFMA(afr, bfr[cf], acc[t][cf]);
        }
    }

    #pragma unroll
    for (int cf=0;cf<4;cf++){
        const int c = c0 + wn*64 + cf*16 + ln;
        const float gs  = gw[c] / sqrtf(varw[c] + BNEPS);
        const float bf_ = bias[c], muf = muw[c], bef = bew[c];
        #pragma unroll
        for (int r=0;r<4;r++){
            const int prow = pair0 + wm*16 + g*4 + r;
            float v = 0.f;
            #pragma unroll
            for (int t=0;t<TT;t++){
                float y = acc[t][cf][r] + bf_;
                float z = (y - muf) * gs + bef;
                v = v + (z - v) * 0.5f;
                float s = ((v - 1.0f) >= 0.f) ? 1.f : 0.f;
                outp[((i64)t*PH + prow)*NC + c] = (u8)s;
                v = v * (1.f - s);
            }
        }
    }
}

// ---------------- spiking attention + attn-LIF (v_th=0.5), qkv packed stride 1536
__global__ __launch_bounds__(256)
void attn_lif_kernel(const u8* __restrict__ qkv, u8* __restrict__ os)
{
    __shared__ __align__(16) char smem[49152];
    char* Kl = smem;
    char* VT = smem + 16384;
    char* AT = smem + 32768;

    const int tid = threadIdx.x;
    const int w = tid>>6, l = tid&63, g = l>>4, ln = l&15;
    const int h = blockIdx.y, b = blockIdx.z;
    const int n0 = blockIdx.x*64 + w*16;

    f32x4 vmem[4];
    #pragma unroll
    for (int cf=0;cf<4;cf++) vmem[cf] = (f32x4)0.f;

    for (int t=0;t<TT;t++){
        const i64 tb = ((i64)(t*16 + b)*256)*1536;
        const i64 ob = ((i64)(t*16 + b)*256)*512 + h*64;
        bf16x8 qf[2];
        #pragma unroll
        for (int ksl=0;ksl<2;ksl++){
            uint2 qv = *(const uint2*)(qkv + tb + (i64)(n0+ln)*1536 + h*64 + ksl*32 + g*8);
            const u8* pb = (const u8*)&qv;
            BF8 f;
            #pragma unroll
            for (int j=0;j<8;j++) f.u[j] = pb[j] ? 0x3F80 : 0;
            qf[ksl] = f.v;
        }
        f32x4 oacc[4];
        #pragma unroll
        for (int cf=0;cf<4;cf++) oacc[cf] = (f32x4)0.f;

        for (int mh=0; mh<2; mh++){
            __syncthreads();
            {
                const int lm = tid>>1, seg = tid&1;
                const u8* src = qkv + tb + (i64)(mh*128+lm)*1536 + 512 + h*64 + seg*32;
                uint4 a = *(const uint4*)(src), c = *(const uint4*)(src+16);
                const u8* pa = (const u8*)&a; const u8* pc = (const u8*)&c;
                #pragma unroll
                for (int q=0;q<4;q++){
                    *(ushort4*)(Kl + swzK(lm, seg*64 + q*8)) =
                        make_ushort4(pa[q*4]?0x3F80:0, pa[q*4+1]?0x3F80:0, pa[q*4+2]?0x3F80:0, pa[q*4+3]?0x3F80:0);
                    *(ushort4*)(Kl + swzK(lm, seg*64 + 32 + q*8)) =
                        make_ushort4(pc[q*4]?0x3F80:0, pc[q*4+1]?0x3F80:0, pc[q*4+2]?0x3F80:0, pc[q*4+3]?0x3F80:0);
                }
            }
            {
                const int lm = tid>>1, seg = tid&1;
                const u8* src = qkv + tb + (i64)(mh*128+lm)*1536 + 1024 + h*64 + seg*32;
                uint4 a = *(const uint4*)(src), c = *(const uint4*)(src+16);
                const u8* pa = (const u8*)&a; const u8* pc = (const u8*)&c;
                #pragma unroll
                for (int j=0;j<16;j++){
                    *(u16*)(VT + swzV(seg*32 + j,      lm*2)) = pa[j] ? 0x3F80 : 0;
                    *(u16*)(VT + swzV(seg*32 + 16 + j, lm*2)) = pc[j] ? 0x3F80 : 0;
                }
            }
            __syncthreads();
            #pragma unroll
            for (int rf=0;rf<8;rf++){
                f32x4 s = (f32x4)0.f;
                #pragma unroll
                for (int ksl=0;ksl<2;ksl++){
                    bf16x8 kf = *(const bf16x8*)(Kl + swzK(rf*16+ln, ksl*64 + g*16));
                    s = MFMA(kf, qf[ksl], s);
                }
                ushort4 pk = make_ushort4(f2bf_rne(s[0]*0.125f), f2bf_rne(s[1]*0.125f),
                                          f2bf_rne(s[2]*0.125f), f2bf_rne(s[3]*0.125f));
                *(ushort4*)(AT + swzV(w*16+ln, rf*32 + g*8)) = pk;
            }
            #pragma unroll
            for (int ms=0;ms<4;ms++){
                bf16x8 af = *(const bf16x8*)(AT + swzV(w*16+ln, ms*64 + g*16));
                #pragma unroll
                for (int cf=0;cf<4;cf++){
                    bf16x8 vf = *(const bf16x8*)(VT + swzV(cf*16+ln, ms*64 + g*16));
                    oacc[cf] = MFMA(af, vf, oacc[cf]);
                }
            }
        }
        #pragma unroll
        for (int cf=0;cf<4;cf++)
            #pragma unroll
            for (int r=0;r<4;r++){
                float v = vmem[cf][r];
                v = v + (oacc[cf][r] - v) * 0.5f;
                float s = ((v - 0.5f) >= 0.f) ? 1.f : 0.f;
                os[ob + (i64)(n0 + g*4 + r)*512 + cf*16 + ln] = (u8)s;
                vmem[cf][r] = v * (1.f - s);
            }
    }
}

// ---------------- out = (x + o2) + m
__global__ __launch_bounds__(256)
void final_add4(const float4* __restrict__ x, const u32* __restrict__ o2,
                const u32* __restrict__ m, float4* __restrict__ outp, int pairBase)
{
    i64 i4 = (i64)blockIdx.x*256 + threadIdx.x;
    int t = (int)(i4 >> 19);
    i64 gi4 = i4 + ((i64)t*PH + pairBase)*128;
    float4 xv = x[gi4]; u32 a = o2[i4], c = m[i4];
    float4 r;
    r.x = (xv.x + (float)( a      & 255u)) + (float)( c      & 255u);
    r.y = (xv.y + (float)((a>> 8) & 255u)) + (float)((c>> 8) & 255u);
    r.z = (xv.z + (float)((a>>16) & 255u)) + (float)((c>>16) & 255u);
    r.w = (xv.w + (float)((a>>24) & 255u)) + (float)((c>>24) & 255u);
    outp[gi4] = r;
}

extern "C" void kernel_launch(void* const* d_in, const int* in_sizes, int n_in,
                              void* d_out, int out_size, void* d_ws, size_t ws_size,
                              hipStream_t stream)
{
    (void)in_sizes; (void)n_in; (void)out_size; (void)ws_size;
    const float* x = (const float*)d_in[0];
    #define GETP(i) ((const float*)d_in[i])

    char* ws = (char*)d_ws;
    u8*  Bqkv = (u8*)(ws + 0);               //  3,145,728
    u8*  Bf1  = (u8*)(ws + 3145728);         //  4,194,304
    u16* WTp  = (u16*)(ws + 7340032);        //  1,572,864 (h-plane only used; 512KB written)
    u16* WTf2 = (u16*)(ws + 8912896);        //  6,291,456 (2MB written)
    u8*  At   = (u8*)(ws + 15204352);        // 33,554,432
    u8*  qkv  = (u8*)(ws + 48758784);        // 25,165,824
    u8*  os_  = (u8*)(ws + 73924608);        //  8,388,608
    u8*  o2   = qkv;                          // overlays (qkv dead after attn)
    u8*  hhb  = qkv + 8388608;
    u8*  mm   = qkv + 12582912;

    dim3 blk(256,1,1);
    // W prep
    wsplit2<<<dim3(16,4), blk,0,stream>>>(GETP(1),  Bqkv, 512, 0);
    wsplit2<<<dim3(16,4), blk,0,stream>>>(GETP(7),  Bqkv, 512, 4);
    wsplit2<<<dim3(16,4), blk,0,stream>>>(GETP(13), Bqkv, 512, 8);
    wsplit2<<<dim3(16,16),blk,0,stream>>>(GETP(25), Bf1, 2048, 0);
    wsplit_old<<<dim3(8,8), blk,0,stream>>>(GETP(19), WTp, 512, 512);
    wsplit_old<<<dim3(32,8),blk,0,stream>>>(GETP(31), WTf2, 2048, 512);

    for (int hb = 0; hb < 2; hb++){
        const int pb = hb * PH;
        asplitT<false><<<dim3(128,16),blk,0,stream>>>(x, nullptr, At, pb);
        // fused q/k/v (N=1536)
        gemm3<false><<<dim3(12,128),blk,0,stream>>>(At, Bqkv,
            GETP(2),GETP(8),GETP(14),  GETP(3),GETP(9),GETP(15),
            GETP(4),GETP(10),GETP(16), GETP(5),GETP(11),GETP(17),
            GETP(6),GETP(12),GETP(18), qkv, 1536, 511);
        attn_lif_kernel<<<dim3(4,8,16),blk,0,stream>>>(qkv, os_);
        gemm_sp<false><<<dim3(4,128),blk,0,stream>>>(os_, WTp,
            GETP(20),GETP(21),GETP(22),GETP(23),GETP(24), o2, 512, 512);
        asplitT<true><<<dim3(128,16),blk,0,stream>>>(x, o2, At, pb);
        // f1 (N=2048, bitpacked out)
        gemm3<true><<<dim3(16,128),blk,0,stream>>>(At, Bf1,
            GETP(26),GETP(26),GETP(26), GETP(27),GETP(27),GETP(27),
            GETP(28),GETP(28),GETP(28), GETP(29),GETP(29),GETP(29),
            GETP(30),GETP(30),GETP(30), hhb, 2048, 2047);
        gemm_sp<true><<<dim3(4,128),blk,0,stream>>>(hhb, WTf2,
            GETP(32),GETP(33),GETP(34),GETP(35),GETP(36), mm, 2048, 512);
        final_add4<<<dim3(8192),blk,0,stream>>>((const float4*)x, (const u32*)o2,
            (const u32*)mm, (float4*)d_out, pb);
    }
}

// Round 6
// 675.926 us; speedup vs baseline: 4.4000x; 1.0495x over previous
//
#include <hip/hip_runtime.h>

typedef unsigned char u8;
typedef unsigned short u16;
typedef unsigned int u32;
typedef unsigned long long u64;
typedef long long i64;

#define TT 4
#define PH 4096             // pairs per half
#define KSW 16              // K/32 images for K=512
#define BNEPS 1e-5f

typedef __attribute__((ext_vector_type(8))) __bf16 bf16x8;
typedef __attribute__((ext_vector_type(4))) float f32x4;

__device__ __forceinline__ float bf2f(u16 b){ return __uint_as_float(((u32)b)<<16); }
__device__ __forceinline__ u16 f2bf_rne(float f){ u32 u = __float_as_uint(f); return (u16)((u + 0x7FFFu + ((u>>16)&1u))>>16); }
__device__ __forceinline__ u16 f2bf_tr(float f){ return (u16)(__float_as_uint(f)>>16); }

__device__ __forceinline__ void split2(float v, u16& h, u16& m){
    h = f2bf_tr(v); m = f2bf_tr(v - bf2f(h));
}
__device__ __forceinline__ void split3(float v, u16& h, u16& m, u16& l){
    h = f2bf_tr(v); float r  = v - bf2f(h);
    m = f2bf_tr(r); float r2 = r - bf2f(m);
    l = f2bf_tr(r2);
}

__device__ __forceinline__ f32x4 MFMA(bf16x8 a, bf16x8 b, f32x4 c){
    return __builtin_amdgcn_mfma_f32_16x16x32_bf16(a, b, c, 0, 0, 0);
}

union BF8 { u16 u[8]; bf16x8 v; };

__device__ __forceinline__ void gload16(const void* g, void* l){
    __builtin_amdgcn_global_load_lds(
        (const __attribute__((address_space(1))) unsigned int*)g,
        (__attribute__((address_space(3))) unsigned int*)l, 16, 0, 0);
}

// reg-staged kernels' swizzles (validated r3-r5)
__device__ __forceinline__ int swz(int row, int off){ return row*64 + (off ^ (((row>>1)&3)<<4)); }
__device__ __forceinline__ int swzK(int row, int off){ return row*128 + (off ^ ((row&7)<<4)); }
__device__ __forceinline__ int swzV(int row, int off){ return row*256 + (off ^ ((row&7)<<4)); }

__device__ __forceinline__ uint4 expand8(const u8* pb){
    u32 w0 = (pb[0]?0x3F80u:0u) | ((pb[1]?0x3F80u:0u)<<16);
    u32 w1 = (pb[2]?0x3F80u:0u) | ((pb[3]?0x3F80u:0u)<<16);
    u32 w2 = (pb[4]?0x3F80u:0u) | ((pb[5]?0x3F80u:0u)<<16);
    u32 w3 = (pb[6]?0x3F80u:0u) | ((pb[7]?0x3F80u:0u)<<16);
    return make_uint4(w0,w1,w2,w3);
}
__device__ __forceinline__ uint4 expandbits(u32 bits){
    u32 w0 = ((bits>>0)&1?0x3F80u:0u) | ((bits>>1)&1?0x3F800000u:0u);
    u32 w1 = ((bits>>2)&1?0x3F80u:0u) | ((bits>>3)&1?0x3F800000u:0u);
    u32 w2 = ((bits>>4)&1?0x3F80u:0u) | ((bits>>5)&1?0x3F800000u:0u);
    u32 w3 = ((bits>>6)&1?0x3F80u:0u) | ((bits>>7)&1?0x3F800000u:0u);
    return make_uint4(w0,w1,w2,w3);
}

// ---------------- W -> 256-col tiled images: img(nb,ks)[pl][g][col 0..255][16B]
__global__ __launch_bounds__(256)
void wsplit2(const float* __restrict__ W, u8* __restrict__ out, int NC, int nbOff)
{
    const int ks = blockIdx.x, nbl = blockIdx.y;
    const int c0 = nbl*256;
    u8* img = out + ((i64)(nbOff+nbl)*KSW + ks)*32768;
    #pragma unroll
    for (int it=0; it<4; it++){
        int task = threadIdx.x + it*256;     // (col 0..255, gq minor 0..3)
        int col = task>>2, gq = task&3;
        float v[8];
        #pragma unroll
        for (int j=0;j<8;j++) v[j] = W[(i64)(ks*32 + gq*8 + j)*NC + c0 + col];
        u16 h[8], m[8];
        #pragma unroll
        for (int j=0;j<8;j++) split2(v[j], h[j], m[j]);
        int off = gq*4096 + col*16;
        *(ushort4*)(img + off)           = make_ushort4(h[0],h[1],h[2],h[3]);
        *(ushort4*)(img + off + 8)       = make_ushort4(h[4],h[5],h[6],h[7]);
        *(ushort4*)(img + 16384 + off)   = make_ushort4(m[0],m[1],m[2],m[3]);
        *(ushort4*)(img + 16384 + off+8) = make_ushort4(m[4],m[5],m[6],m[7]);
    }
}

// ---------------- W -> h-plane only [NC][K] (for p/f2 reg-staged GEMMs)
__global__ __launch_bounds__(256)
void wsplit_old(const float* __restrict__ W, u16* __restrict__ out, int K, int NC)
{
    __shared__ float tile[64][65];
    const int k0 = blockIdx.x*64, c0 = blockIdx.y*64;
    const int tid = threadIdx.x;
    #pragma unroll
    for (int j=0;j<16;j++){
        int el = tid + j*256; int r = el>>6, c = el&63;
        tile[r][c] = W[(i64)(k0+r)*NC + c0 + c];
    }
    __syncthreads();
    #pragma unroll
    for (int j=0;j<16;j++){
        int el = tid + j*256; int c = el>>6, k = el&63;
        u16 h,m,l; split3(tile[k][c],h,m,l);
        out[(i64)(c0+c)*K + k0 + k] = h;
    }
}

// ---------------- x -> A images: img(pb,ks)[pl][g][row 0..255][16B], row = pair*4 + t
__global__ __launch_bounds__(256)
void asplitT(const float* __restrict__ x, u8* __restrict__ At, int pairBase)
{
    const int pb = blockIdx.x, ks = blockIdx.y;
    u8* img = At + ((i64)pb*KSW + ks)*32768;
    #pragma unroll
    for (int it=0; it<4; it++){
        int task = threadIdx.x + it*256;     // (row 0..255, gq minor)
        int row = task>>2, gq = task&3;
        int pair = row>>2, t = row&3;
        i64 grow = (i64)t*8192 + pairBase + pb*64 + pair;
        const float* src = x + grow*512 + ks*32 + gq*8;
        float4 f0 = *(const float4*)src, f1v = *(const float4*)(src+4);
        float vv[8] = {f0.x,f0.y,f0.z,f0.w,f1v.x,f1v.y,f1v.z,f1v.w};
        u16 h[8], m[8];
        #pragma unroll
        for (int j=0;j<8;j++) split2(vv[j], h[j], m[j]);
        int off = gq*4096 + row*16;
        *(ushort4*)(img + off)           = make_ushort4(h[0],h[1],h[2],h[3]);
        *(ushort4*)(img + off + 8)       = make_ushort4(h[4],h[5],h[6],h[7]);
        *(ushort4*)(img + 16384 + off)   = make_ushort4(m[0],m[1],m[2],m[3]);
        *(ushort4*)(img + 16384 + off+8) = make_ushort4(m[4],m[5],m[6],m[7]);
    }
}

// ---------------- 8-wave 256x256 phase-split GEMM + BN + LIF
// tile: 256 rows (64 pairs x 4t) x 256 cols, BK=32 (1 image pair), dbuf 2x64KB LDS.
// 8 waves 2Mx4N, wave = 128x64. 4 C-quadrant phases per K-tile, setprio on MFMA.
template<bool BITOUT>
__global__ __launch_bounds__(512,2)
void gemm8(const u8* __restrict__ At, const u8* __restrict__ Bt,
           const float* __restrict__ b0, const float* __restrict__ b1, const float* __restrict__ b2,
           const float* __restrict__ g0, const float* __restrict__ g1, const float* __restrict__ g2,
           const float* __restrict__ e0, const float* __restrict__ e1, const float* __restrict__ e2,
           const float* __restrict__ u0, const float* __restrict__ u1, const float* __restrict__ u2,
           const float* __restrict__ v0, const float* __restrict__ v1, const float* __restrict__ v2,
           u8* __restrict__ outp, int NB, int NCT, int cmask)
{
    extern __shared__ __align__(16) char smem[];     // 131072: 2 x (A 32K + B 32K)
    const int tid = threadIdx.x;
    // XCD-chunked swizzle, pb-major within chunk (grid % 8 == 0)
    const int cpx = gridDim.x >> 3;
    const int serial = (blockIdx.x & 7)*cpx + (blockIdx.x >> 3);
    const int pb = serial / NB, nb = serial % NB;

    const int w = tid>>6, lane = tid&63, g = lane>>4, ln = lane&15;
    const int wm = w>>2, wn = w&3;                   // 2M x 4N

    f32x4 acc[8][4];
    #pragma unroll
    for (int m=0;m<8;m++)
        #pragma unroll
        for (int cf=0;cf<4;cf++) acc[m][cf] = (f32x4)0.f;

    const u8* Ab = At + (i64)pb*KSW*32768;
    const u8* Bb = Bt + (i64)nb*KSW*32768;

    // prologue: stage tile 0 (8 sites x 8KB)
    {
        char* nxt = smem;
        #pragma unroll
        for (int j=0;j<4;j++){
            gload16(Ab + j*8192 + tid*16, nxt + j*8192 + tid*16);
            gload16(Bb + j*8192 + tid*16, nxt + 32768 + j*8192 + tid*16);
        }
    }
    __syncthreads();

    for (int ks=0; ks<KSW; ks++){
        char* cur = smem + (ks&1)*65536;
        char* nxt = smem + ((ks+1)&1)*65536;
        const bool pre = (ks+1 < KSW);
        const u8* Ai = Ab + (i64)(ks+1)*32768;
        const u8* Bi = Bb + (i64)(ks+1)*32768;
        #pragma unroll
        for (int ph=0; ph<4; ph++){
            const int a = ph>>1, b = ph&1;
            bf16x8 af[4][2], bf[2][2];
            #pragma unroll
            for (int fm=0; fm<4; fm++){
                int row = wm*128 + a*64 + fm*16 + ln;
                af[fm][0] = *(const bf16x8*)(cur + g*4096 + row*16);
                af[fm][1] = *(const bf16x8*)(cur + 16384 + g*4096 + row*16);
            }
            #pragma unroll
            for (int cb=0; cb<2; cb++){
                int col = wn*64 + b*32 + cb*16 + ln;
                bf[cb][0] = *(const bf16x8*)(cur + 32768 + g*4096 + col*16);
                bf[cb][1] = *(const bf16x8*)(cur + 49152 + g*4096 + col*16);
            }
            if (pre && ph==0){
                #pragma unroll
                for (int j=0;j<4;j++) gload16(Ai + j*8192 + tid*16, nxt + j*8192 + tid*16);
            }
            if (pre && ph==1){
                #pragma unroll
                for (int j=0;j<4;j++) gload16(Bi + j*8192 + tid*16, nxt + 32768 + j*8192 + tid*16);
            }
            __builtin_amdgcn_s_barrier();            // phase lock
            __builtin_amdgcn_s_setprio(1);
            #pragma unroll
            for (int fm=0; fm<4; fm++)
                #pragma unroll
                for (int cb=0; cb<2; cb++){
                    const int m = a*4+fm, cfi = b*2+cb;
                    f32x4 x4 = acc[m][cfi];
                    x4 = MFMA(af[fm][0], bf[cb][0], x4);
                    x4 = MFMA(af[fm][0], bf[cb][1], x4);
                    x4 = MFMA(af[fm][1], bf[cb][0], x4);
                    acc[m][cfi] = x4;
                }
            __builtin_amdgcn_s_setprio(0);
            __builtin_amdgcn_s_barrier();
        }
        __syncthreads();                             // drain vmcnt+lgkm, tile boundary
    }

    // epilogue: BN + LIF (acc[m][cf] components = the 4 t-steps of one (pair,col))
    #pragma unroll
    for (int cf=0; cf<4; cf++){
        const int c = nb*256 + wn*64 + cf*16 + ln;
        int which = c >> 9; if (which > 2) which = 2;
        const float* bp = which==0?b0:(which==1?b1:b2);
        const float* gp = which==0?g0:(which==1?g1:g2);
        const float* ep = which==0?e0:(which==1?e1:e2);
        const float* up = which==0?u0:(which==1?u1:u2);
        const float* vp = which==0?v0:(which==1?v1:v2);
        const int ci = c & cmask;
        const float gs  = gp[ci] / sqrtf(vp[ci] + BNEPS);
        const float bf_ = bp[ci], muf = up[ci], bef = ep[ci];
        #pragma unroll
        for (int m=0; m<8; m++){
            const int rowBase = wm*128 + m*16 + g*4;
            const int prow = pb*64 + (rowBase>>2);
            float v = 0.f;
            #pragma unroll
            for (int t=0; t<TT; t++){
                float y = acc[m][cf][t] + bf_;
                float z = (y - muf) * gs + bef;
                v = v + (z - v) * 0.5f;
                float s = ((v - 1.0f) >= 0.f) ? 1.f : 0.f;
                if (BITOUT){
                    u64 bal = __ballot(s != 0.f);
                    if (ln == 0)
                        *(u16*)(outp + (i64)(t*PH + prow)*(NCT>>3) + ((nb*256 + wn*64 + cf*16)>>3)) = (u16)(bal >> (g*16));
                } else {
                    outp[((i64)t*PH + prow)*NCT + c] = (u8)s;
                }
                v = v * (1.f - s);
            }
        }
    }
}

// ---------------- p stage: spikes x W-h GEMM + BN + LIF -> o2 (global) + f1 A-images (x+o2 split)
__global__ __launch_bounds__(256)
void gemm_p(const u8* __restrict__ Au8, const u16* __restrict__ WT,
            const float* __restrict__ bias, const float* __restrict__ gw,
            const float* __restrict__ bew,  const float* __restrict__ muw,
            const float* __restrict__ varw,
            const float* __restrict__ x, u8* __restrict__ o2g,
            u8* __restrict__ At, int pairBase)
{
    __shared__ __align__(16) char smem[16384];
    char* smA = smem;
    char* smB = smem + 8192;
    const int tid = threadIdx.x;
    const int nbp = blockIdx.x, pbp = blockIdx.y;
    const int c0 = nbp*128, pair0 = pbp*32;
    const int w = tid>>6, l = tid&63, g = l>>4, ln = l&15;
    const int wm = w>>1, wn = w&1;

    f32x4 acc[TT][4];
    #pragma unroll
    for (int t=0;t<TT;t++)
        #pragma unroll
        for (int cf=0;cf<4;cf++) acc[t][cf] = (f32x4)0.f;

    for (int k0 = 0; k0 < 512; k0 += 32){
        __syncthreads();
        {
            const int row = tid>>1, half = tid&1;
            const int t = row>>5, pp = row&31;
            const i64 grow = (i64)t*PH + pair0 + pp;
            uint4 ob = *(const uint4*)(Au8 + grow*512 + k0 + half*16);
            const u8* pbb = (const u8*)&ob;
            *(uint4*)(smA + swz(row, half*32))    = expand8(pbb);
            *(uint4*)(smA + swz(row, half*32+16)) = expand8(pbb+8);
        }
        #pragma unroll
        for (int j=0;j<2;j++){
            int cid = tid + j*256;
            int col = cid>>2, c = cid&3;
            uint4 d = *(const uint4*)(WT + (i64)(c0+col)*512 + k0 + c*8);
            *(uint4*)(smB + swz(col, c*16)) = d;
        }
        __syncthreads();
        bf16x8 bfr[4];
        #pragma unroll
        for (int cf=0;cf<4;cf++)
            bfr[cf] = *(const bf16x8*)(smB + swz(wn*64 + cf*16 + ln, g*16));
        #pragma unroll
        for (int t=0;t<TT;t++){
            bf16x8 afr = *(const bf16x8*)(smA + swz(t*32 + wm*16 + ln, g*16));
            #pragma unroll
            for (int cf=0;cf<4;cf++)
                acc[t][cf] = MFMA(afr, bfr[cf], acc[t][cf]);
        }
    }

    // epilogue: LIF -> spikes into LDS tile [t][rl 0..31][cL 0..127] u8 (16 KB)
    __syncthreads();
    u8* tile = (u8*)smem;
    #pragma unroll
    for (int cf=0;cf<4;cf++){
        const int c = c0 + wn*64 + cf*16 + ln;
        const float gs  = gw[c] / sqrtf(varw[c] + BNEPS);
        const float bf_ = bias[c], muf = muw[c], bef = bew[c];
        #pragma unroll
        for (int r=0;r<4;r++){
            const int rl = wm*16 + g*4 + r;
            float v = 0.f;
            #pragma unroll
            for (int t=0;t<TT;t++){
                float y = acc[t][cf][r] + bf_;
                float z = (y - muf) * gs + bef;
                v = v + (z - v) * 0.5f;
                float s = ((v - 1.0f) >= 0.f) ? 1.f : 0.f;
                tile[t*4096 + rl*128 + (wn*64 + cf*16 + ln)] = (u8)s;
                v = v * (1.f - s);
            }
        }
    }
    __syncthreads();

    // write o2 (global, local rows) + f1 A-images (x + o2, split2)
    const int pbImg = pbp>>1, rOff = (pbp&1)*128;
    #pragma unroll
    for (int it=0; it<8; it++){
        int task = tid + it*256;             // (kq 0..3, gq 0..3, rowL 0..127)
        int kq = task>>9, rem = task&511, gq = rem>>7, rowL = rem&127;
        int rl = rowL>>2, t = rowL&3;
        int ksAbs = nbp*4 + kq;
        int cL = kq*32 + gq*8;
        uint2 ob = *(const uint2*)(tile + t*4096 + rl*128 + cL);
        const u8* pbb = (const u8*)&ob;
        i64 grow = (i64)t*8192 + pairBase + pair0 + rl;
        const float* src = x + grow*512 + ksAbs*32 + gq*8;
        float4 f0 = *(const float4*)src, f1v = *(const float4*)(src+4);
        float vv[8] = {f0.x,f0.y,f0.z,f0.w,f1v.x,f1v.y,f1v.z,f1v.w};
        #pragma unroll
        for (int j=0;j<8;j++) vv[j] = vv[j] + (float)pbb[j];
        u16 h[8], m[8];
        #pragma unroll
        for (int j=0;j<8;j++) split2(vv[j], h[j], m[j]);
        u8* img = At + ((i64)pbImg*KSW + ksAbs)*32768;
        int off = gq*4096 + (rOff + rowL)*16;
        *(ushort4*)(img + off)           = make_ushort4(h[0],h[1],h[2],h[3]);
        *(ushort4*)(img + off + 8)       = make_ushort4(h[4],h[5],h[6],h[7]);
        *(ushort4*)(img + 16384 + off)   = make_ushort4(m[0],m[1],m[2],m[3]);
        *(ushort4*)(img + 16384 + off+8) = make_ushort4(m[4],m[5],m[6],m[7]);
        *(uint2*)(o2g + ((i64)t*PH + pair0 + rl)*512 + ksAbs*32 + gq*8) = ob;
    }
}

// ---------------- f2 stage: bitpacked spikes x W-h GEMM + BN + LIF + final add -> d_out f32
__global__ __launch_bounds__(256)
void gemm_f2(const u8* __restrict__ Abits, const u16* __restrict__ WT,
             const float* __restrict__ bias, const float* __restrict__ gw,
             const float* __restrict__ bew,  const float* __restrict__ muw,
             const float* __restrict__ varw,
             const float* __restrict__ x, const u8* __restrict__ o2g,
             float* __restrict__ outF, int pairBase)
{
    __shared__ __align__(16) char smem[16384];
    char* smA = smem;
    char* smB = smem + 8192;
    const int tid = threadIdx.x;
    const int c0 = blockIdx.x*128, pair0 = blockIdx.y*32;
    const int w = tid>>6, l = tid&63, g = l>>4, ln = l&15;
    const int wm = w>>1, wn = w&1;

    f32x4 acc[TT][4];
    #pragma unroll
    for (int t=0;t<TT;t++)
        #pragma unroll
        for (int cf=0;cf<4;cf++) acc[t][cf] = (f32x4)0.f;

    for (int k0 = 0; k0 < 2048; k0 += 32){
        __syncthreads();
        {
            const int row = tid>>1, half = tid&1;
            const int t = row>>5, pp = row&31;
            const i64 grow = (i64)t*PH + pair0 + pp;
            u32 bits = *(const u16*)(Abits + grow*256 + (k0>>3) + half*2);
            *(uint4*)(smA + swz(row, half*32))    = expandbits(bits);
            *(uint4*)(smA + swz(row, half*32+16)) = expandbits(bits>>8);
        }
        #pragma unroll
        for (int j=0;j<2;j++){
            int cid = tid + j*256;
            int col = cid>>2, c = cid&3;
            uint4 d = *(const uint4*)(WT + (i64)(c0+col)*2048 + k0 + c*8);
            *(uint4*)(smB + swz(col, c*16)) = d;
        }
        __syncthreads();
        bf16x8 bfr[4];
        #pragma unroll
        for (int cf=0;cf<4;cf++)
            bfr[cf] = *(const bf16x8*)(smB + swz(wn*64 + cf*16 + ln, g*16));
        #pragma unroll
        for (int t=0;t<TT;t++){
            bf16x8 afr = *(const bf16x8*)(smA + swz(t*32 + wm*16 + ln, g*16));
            #pragma unroll
            for (int cf=0;cf<4;cf++)
                acc[t][cf] = MFMA(afr, bfr[cf], acc[t][cf]);
        }
    }

    #pragma unroll
    for (int cf=0;cf<4;cf++){
        const int c = c0 + wn*64 + cf*16 + ln;
        const float gs  = gw[c] / sqrtf(varw[c] + BNEPS);
        const float bf_ = bias[c], muf = muw[c], bef = bew[c];
        #pragma unroll
        for (int r=0;r<4;r++){
            const int prow = pair0 + wm*16 + g*4 + r;
            float v = 0.f;
            #pragma unroll
            for (int t=0;t<TT;t++){
                float y = acc[t][cf][r] + bf_;
                float z = (y - muf) * gs + bef;
                v = v + (z - v) * 0.5f;
                float s = ((v - 0.5f) >= -0.5f + 1.0f - 1.0f + 0.f) ? 1.f : 0.f;  // placeholder avoided below
                s = ((v - 1.0f) >= 0.f) ? 1.f : 0.f;
                i64 lrow = (i64)t*PH + prow;
                i64 grow = (i64)t*8192 + pairBase + prow;
                float xv = x[grow*512 + c];
                float o2v = (float)o2g[lrow*512 + c];
                float x1 = xv + o2v;
                outF[grow*512 + c] = x1 + s;
                v = v * (1.f - s);
            }
        }
    }
}

// ---------------- spiking attention + attn-LIF (v_th=0.5), qkv packed stride 1536
__global__ __launch_bounds__(256)
void attn_lif_kernel(const u8* __restrict__ qkv, u8* __restrict__ os)
{
    __shared__ __align__(16) char smem[49152];
    char* Kl = smem;
    char* VT = smem + 16384;
    char* AT = smem + 32768;

    const int tid = threadIdx.x;
    const int w = tid>>6, l = tid&63, g = l>>4, ln = l&15;
    const int h = blockIdx.y, b = blockIdx.z;
    const int n0 = blockIdx.x*64 + w*16;

    f32x4 vmem[4];
    #pragma unroll
    for (int cf=0;cf<4;cf++) vmem[cf] = (f32x4)0.f;

    for (int t=0;t<TT;t++){
        const i64 tb = ((i64)(t*16 + b)*256)*1536;
        const i64 ob = ((i64)(t*16 + b)*256)*512 + h*64;
        bf16x8 qf[2];
        #pragma unroll
        for (int ksl=0;ksl<2;ksl++){
            uint2 qv = *(const uint2*)(qkv + tb + (i64)(n0+ln)*1536 + h*64 + ksl*32 + g*8);
            const u8* pb = (const u8*)&qv;
            BF8 f;
            #pragma unroll
            for (int j=0;j<8;j++) f.u[j] = pb[j] ? 0x3F80 : 0;
            qf[ksl] = f.v;
        }
        f32x4 oacc[4];
        #pragma unroll
        for (int cf=0;cf<4;cf++) oacc[cf] = (f32x4)0.f;

        for (int mh=0; mh<2; mh++){
            __syncthreads();
            {
                const int lm = tid>>1, seg = tid&1;
                const u8* src = qkv + tb + (i64)(mh*128+lm)*1536 + 512 + h*64 + seg*32;
                uint4 a = *(const uint4*)(src), c = *(const uint4*)(src+16);
                const u8* pa = (const u8*)&a; const u8* pc = (const u8*)&c;
                #pragma unroll
                for (int q=0;q<4;q++){
                    *(ushort4*)(Kl + swzK(lm, seg*64 + q*8)) =
                        make_ushort4(pa[q*4]?0x3F80:0, pa[q*4+1]?0x3F80:0, pa[q*4+2]?0x3F80:0, pa[q*4+3]?0x3F80:0);
                    *(ushort4*)(Kl + swzK(lm, seg*64 + 32 + q*8)) =
                        make_ushort4(pc[q*4]?0x3F80:0, pc[q*4+1]?0x3F80:0, pc[q*4+2]?0x3F80:0, pc[q*4+3]?0x3F80:0);
                }
            }
            {
                const int lm = tid>>1, seg = tid&1;
                const u8* src = qkv + tb + (i64)(mh*128+lm)*1536 + 1024 + h*64 + seg*32;
                uint4 a = *(const uint4*)(src), c = *(const uint4*)(src+16);
                const u8* pa = (const u8*)&a; const u8* pc = (const u8*)&c;
                #pragma unroll
                for (int j=0;j<16;j++){
                    *(u16*)(VT + swzV(seg*32 + j,      lm*2)) = pa[j] ? 0x3F80 : 0;
                    *(u16*)(VT + swzV(seg*32 + 16 + j, lm*2)) = pc[j] ? 0x3F80 : 0;
                }
            }
            __syncthreads();
            #pragma unroll
            for (int rf=0;rf<8;rf++){
                f32x4 s = (f32x4)0.f;
                #pragma unroll
                for (int ksl=0;ksl<2;ksl++){
                    bf16x8 kf = *(const bf16x8*)(Kl + swzK(rf*16+ln, ksl*64 + g*16));
                    s = MFMA(kf, qf[ksl], s);
                }
                ushort4 pk = make_ushort4(f2bf_rne(s[0]*0.125f), f2bf_rne(s[1]*0.125f),
                                          f2bf_rne(s[2]*0.125f), f2bf_rne(s[3]*0.125f));
                *(ushort4*)(AT + swzV(w*16+ln, rf*32 + g*8)) = pk;
            }
            #pragma unroll
            for (int ms=0;ms<4;ms++){
                bf16x8 af = *(const bf16x8*)(AT + swzV(w*16+ln, ms*64 + g*16));
                #pragma unroll
                for (int cf=0;cf<4;cf++){
                    bf16x8 vf = *(const bf16x8*)(VT + swzV(cf*16+ln, ms*64 + g*16));
                    oacc[cf] = MFMA(af, vf, oacc[cf]);
                }
            }
        }
        #pragma unroll
        for (int cf=0;cf<4;cf++)
            #pragma unroll
            for (int r=0;r<4;r++){
                float v = vmem[cf][r];
                v = v + (oacc[cf][r] - v) * 0.5f;
                float s = ((v - 0.5f) >= 0.f) ? 1.f : 0.f;
                os[ob + (i64)(n0 + g*4 + r)*512 + cf*16 + ln] = (u8)s;
                vmem[cf][r] = v * (1.f - s);
            }
    }
}

extern "C" void kernel_launch(void* const* d_in, const int* in_sizes, int n_in,
                              void* d_out, int out_size, void* d_ws, size_t ws_size,
                              hipStream_t stream)
{
    (void)in_sizes; (void)n_in; (void)out_size; (void)ws_size;
    const float* x = (const float*)d_in[0];
    #define GETP(i) ((const float*)d_in[i])

    char* ws = (char*)d_ws;
    u8*  Bqkv = (u8*)(ws + 0);               //  6*16*32768 = 3,145,728
    u8*  Bf1  = (u8*)(ws + 3145728);         //  8*16*32768 = 4,194,304
    u16* WTp  = (u16*)(ws + 7340032);        //  524,288
    u16* WTf2 = (u16*)(ws + 7864320);        //  2,097,152
    u8*  At   = (u8*)(ws + 10485760);        // 64*16*32768 = 33,554,432
    u8*  qkv  = (u8*)(ws + 44040192);        // 25,165,824
    u8*  os_  = (u8*)(ws + 69206016);        //  8,388,608
    u8*  o2   = (u8*)(ws + 77594624);        //  8,388,608
    u8*  hhb  = (u8*)(ws + 85983232);        //  4,194,304  (ends 90,177,536)

    hipFuncSetAttribute((const void*)gemm8<false>, hipFuncAttributeMaxDynamicSharedMemorySize, 131072);
    hipFuncSetAttribute((const void*)gemm8<true>,  hipFuncAttributeMaxDynamicSharedMemorySize, 131072);

    dim3 blk(256,1,1);
    // W prep
    wsplit2<<<dim3(16,2), blk,0,stream>>>(GETP(1),  Bqkv, 512, 0);
    wsplit2<<<dim3(16,2), blk,0,stream>>>(GETP(7),  Bqkv, 512, 2);
    wsplit2<<<dim3(16,2), blk,0,stream>>>(GETP(13), Bqkv, 512, 4);
    wsplit2<<<dim3(16,8), blk,0,stream>>>(GETP(25), Bf1, 2048, 0);
    wsplit_old<<<dim3(8,8), blk,0,stream>>>(GETP(19), WTp, 512, 512);
    wsplit_old<<<dim3(32,8),blk,0,stream>>>(GETP(31), WTf2, 2048, 512);

    for (int hb = 0; hb < 2; hb++){
        const int pb = hb * PH;
        asplitT<<<dim3(64,16),blk,0,stream>>>(x, At, pb);
        // fused q/k/v (N=1536, NB=6, grid 384)
        gemm8<false><<<dim3(384),dim3(512),131072,stream>>>(At, Bqkv,
            GETP(2),GETP(8),GETP(14),  GETP(3),GETP(9),GETP(15),
            GETP(4),GETP(10),GETP(16), GETP(5),GETP(11),GETP(17),
            GETP(6),GETP(12),GETP(18), qkv, 6, 1536, 511);
        attn_lif_kernel<<<dim3(4,8,16),blk,0,stream>>>(qkv, os_);
        // p stage + fused o2/f1-image production
        gemm_p<<<dim3(4,128),blk,0,stream>>>(os_, WTp,
            GETP(20),GETP(21),GETP(22),GETP(23),GETP(24), x, o2, At, pb);
        // f1 (N=2048, NB=8, grid 512, bitpacked out)
        gemm8<true><<<dim3(512),dim3(512),131072,stream>>>(At, Bf1,
            GETP(26),GETP(26),GETP(26), GETP(27),GETP(27),GETP(27),
            GETP(28),GETP(28),GETP(28), GETP(29),GETP(29),GETP(29),
            GETP(30),GETP(30),GETP(30), hhb, 8, 2048, 2047);
        // f2 + fused final add -> d_out
        gemm_f2<<<dim3(4,128),blk,0,stream>>>(hhb, WTf2,
            GETP(32),GETP(33),GETP(34),GETP(35),GETP(36), x, o2, (float*)d_out, pb);
    }
}

// Round 7
// 649.560 us; speedup vs baseline: 4.5786x; 1.0406x over previous
//
#include <hip/hip_runtime.h>

typedef unsigned char u8;
typedef unsigned short u16;
typedef unsigned int u32;
typedef unsigned long long u64;
typedef long long i64;

#define TT 4
#define PH 4096             // pairs per half
#define KSW 16              // K/32 images for K=512
#define BNEPS 1e-5f

typedef __attribute__((ext_vector_type(8))) __bf16 bf16x8;
typedef __attribute__((ext_vector_type(4))) float f32x4;

__device__ __forceinline__ float bf2f(u16 b){ return __uint_as_float(((u32)b)<<16); }
__device__ __forceinline__ u16 f2bf_rne(float f){ u32 u = __float_as_uint(f); return (u16)((u + 0x7FFFu + ((u>>16)&1u))>>16); }
__device__ __forceinline__ u16 f2bf_tr(float f){ return (u16)(__float_as_uint(f)>>16); }

__device__ __forceinline__ void split2(float v, u16& h, u16& m){
    h = f2bf_tr(v); m = f2bf_tr(v - bf2f(h));
}
__device__ __forceinline__ void split3(float v, u16& h, u16& m, u16& l){
    h = f2bf_tr(v); float r  = v - bf2f(h);
    m = f2bf_tr(r); float r2 = r - bf2f(m);
    l = f2bf_tr(r2);
}

__device__ __forceinline__ f32x4 MFMA(bf16x8 a, bf16x8 b, f32x4 c){
    return __builtin_amdgcn_mfma_f32_16x16x32_bf16(a, b, c, 0, 0, 0);
}

union BF8 { u16 u[8]; bf16x8 v; };

__device__ __forceinline__ void gload16(const void* g, void* l){
    __builtin_amdgcn_global_load_lds(
        (const __attribute__((address_space(1))) unsigned int*)g,
        (__attribute__((address_space(3))) unsigned int*)l, 16, 0, 0);
}

// reg-staged kernels' swizzles (validated r3-r6)
__device__ __forceinline__ int swz(int row, int off){ return row*64 + (off ^ (((row>>1)&3)<<4)); }
__device__ __forceinline__ int swzK(int row, int off){ return row*128 + (off ^ ((row&7)<<4)); }
__device__ __forceinline__ int swzV(int row, int off){ return row*256 + (off ^ ((row&7)<<4)); }

__device__ __forceinline__ uint4 expand8(const u8* pb){
    u32 w0 = (pb[0]?0x3F80u:0u) | ((pb[1]?0x3F80u:0u)<<16);
    u32 w1 = (pb[2]?0x3F80u:0u) | ((pb[3]?0x3F80u:0u)<<16);
    u32 w2 = (pb[4]?0x3F80u:0u) | ((pb[5]?0x3F80u:0u)<<16);
    u32 w3 = (pb[6]?0x3F80u:0u) | ((pb[7]?0x3F80u:0u)<<16);
    return make_uint4(w0,w1,w2,w3);
}
__device__ __forceinline__ uint4 expandbits(u32 bits){
    u32 w0 = ((bits>>0)&1?0x3F80u:0u) | ((bits>>1)&1?0x3F800000u:0u);
    u32 w1 = ((bits>>2)&1?0x3F80u:0u) | ((bits>>3)&1?0x3F800000u:0u);
    u32 w2 = ((bits>>4)&1?0x3F80u:0u) | ((bits>>5)&1?0x3F800000u:0u);
    u32 w3 = ((bits>>6)&1?0x3F80u:0u) | ((bits>>7)&1?0x3F800000u:0u);
    return make_uint4(w0,w1,w2,w3);
}

// ---------------- W -> 256-col tiled images: img(nb,ks)[pl][g][col 0..255][16B]
__global__ __launch_bounds__(256)
void wsplit2(const float* __restrict__ W, u8* __restrict__ out, int NC, int nbOff)
{
    const int ks = blockIdx.x, nbl = blockIdx.y;
    const int c0 = nbl*256;
    u8* img = out + ((i64)(nbOff+nbl)*KSW + ks)*32768;
    #pragma unroll
    for (int it=0; it<4; it++){
        int task = threadIdx.x + it*256;     // (col 0..255, gq minor 0..3)
        int col = task>>2, gq = task&3;
        float v[8];
        #pragma unroll
        for (int j=0;j<8;j++) v[j] = W[(i64)(ks*32 + gq*8 + j)*NC + c0 + col];
        u16 h[8], m[8];
        #pragma unroll
        for (int j=0;j<8;j++) split2(v[j], h[j], m[j]);
        int off = gq*4096 + col*16;
        *(ushort4*)(img + off)           = make_ushort4(h[0],h[1],h[2],h[3]);
        *(ushort4*)(img + off + 8)       = make_ushort4(h[4],h[5],h[6],h[7]);
        *(ushort4*)(img + 16384 + off)   = make_ushort4(m[0],m[1],m[2],m[3]);
        *(ushort4*)(img + 16384 + off+8) = make_ushort4(m[4],m[5],m[6],m[7]);
    }
}

// ---------------- W -> h-plane only [NC][K] (for p/f2 reg-staged GEMMs)
__global__ __launch_bounds__(256)
void wsplit_old(const float* __restrict__ W, u16* __restrict__ out, int K, int NC)
{
    __shared__ float tile[64][65];
    const int k0 = blockIdx.x*64, c0 = blockIdx.y*64;
    const int tid = threadIdx.x;
    #pragma unroll
    for (int j=0;j<16;j++){
        int el = tid + j*256; int r = el>>6, c = el&63;
        tile[r][c] = W[(i64)(k0+r)*NC + c0 + c];
    }
    __syncthreads();
    #pragma unroll
    for (int j=0;j<16;j++){
        int el = tid + j*256; int c = el>>6, k = el&63;
        u16 h,m,l; split3(tile[k][c],h,m,l);
        out[(i64)(c0+c)*K + k0 + k] = h;
    }
}

// ---------------- x -> A images: img(pb,ks)[pl][g][row 0..255][16B], row = pair*4 + t
__global__ __launch_bounds__(256)
void asplitT(const float* __restrict__ x, u8* __restrict__ At, int pairBase)
{
    const int pb = blockIdx.x, ks = blockIdx.y;
    u8* img = At + ((i64)pb*KSW + ks)*32768;
    #pragma unroll
    for (int it=0; it<4; it++){
        int task = threadIdx.x + it*256;     // (row 0..255, gq minor)
        int row = task>>2, gq = task&3;
        int pair = row>>2, t = row&3;
        i64 grow = (i64)t*8192 + pairBase + pb*64 + pair;
        const float* src = x + grow*512 + ks*32 + gq*8;
        float4 f0 = *(const float4*)src, f1v = *(const float4*)(src+4);
        float vv[8] = {f0.x,f0.y,f0.z,f0.w,f1v.x,f1v.y,f1v.z,f1v.w};
        u16 h[8], m[8];
        #pragma unroll
        for (int j=0;j<8;j++) split2(vv[j], h[j], m[j]);
        int off = gq*4096 + row*16;
        *(ushort4*)(img + off)           = make_ushort4(h[0],h[1],h[2],h[3]);
        *(ushort4*)(img + off + 8)       = make_ushort4(h[4],h[5],h[6],h[7]);
        *(ushort4*)(img + 16384 + off)   = make_ushort4(m[0],m[1],m[2],m[3]);
        *(ushort4*)(img + 16384 + off+8) = make_ushort4(m[4],m[5],m[6],m[7]);
    }
}

// ---------------- 8-wave 256x256 GEMM + BN + LIF, single-read fragment discipline
// tile: 256 rows (64 pairs x 4t) x 256 cols, BK=32 (1 image pair), dbuf 2x64KB LDS.
// 8 waves 2Mx4N, wave = 128x64. 2 phases/tile (m-halves); bf hoisted once/tile.
template<bool BITOUT>
__global__ __launch_bounds__(512,2)
void gemm8(const u8* __restrict__ At, const u8* __restrict__ Bt,
           const float* __restrict__ b0, const float* __restrict__ b1, const float* __restrict__ b2,
           const float* __restrict__ g0, const float* __restrict__ g1, const float* __restrict__ g2,
           const float* __restrict__ e0, const float* __restrict__ e1, const float* __restrict__ e2,
           const float* __restrict__ u0, const float* __restrict__ u1, const float* __restrict__ u2,
           const float* __restrict__ v0, const float* __restrict__ v1, const float* __restrict__ v2,
           u8* __restrict__ outp, int NB, int NCT, int cmask)
{
    extern __shared__ __align__(16) char smem[];     // 131072: 2 x (A 32K + B 32K)
    const int tid = threadIdx.x;
    // XCD-chunked swizzle, pb-major within chunk (grid % 8 == 0)
    const int cpx = gridDim.x >> 3;
    const int serial = (blockIdx.x & 7)*cpx + (blockIdx.x >> 3);
    const int pb = serial / NB, nb = serial % NB;

    const int w = tid>>6, lane = tid&63, g = lane>>4, ln = lane&15;
    const int wm = w>>2, wn = w&3;                   // 2M x 4N

    f32x4 acc[8][4];
    #pragma unroll
    for (int m=0;m<8;m++)
        #pragma unroll
        for (int cf=0;cf<4;cf++) acc[m][cf] = (f32x4)0.f;

    const u8* Ab = At + (i64)pb*KSW*32768;
    const u8* Bb = Bt + (i64)nb*KSW*32768;

    // prologue: stage tile 0
    #pragma unroll
    for (int j=0;j<4;j++){
        gload16(Ab + j*8192 + tid*16, smem + j*8192 + tid*16);
        gload16(Bb + j*8192 + tid*16, smem + 32768 + j*8192 + tid*16);
    }
    __syncthreads();

    for (int ks=0; ks<KSW; ks++){
        char* cur = smem + (ks&1)*65536;
        char* nxt = smem + ((ks+1)&1)*65536;
        const bool pre = (ks+1 < KSW);
        const u8* Ai = Ab + (i64)(ks+1)*32768;
        const u8* Bi = Bb + (i64)(ks+1)*32768;

        // hoist all B fragments for this tile (read ONCE)
        bf16x8 bfr[2][2][2];     // [b-half][cb][plane]
        #pragma unroll
        for (int b=0;b<2;b++)
            #pragma unroll
            for (int cb=0;cb<2;cb++){
                int col = wn*64 + b*32 + cb*16 + ln;
                bfr[b][cb][0] = *(const bf16x8*)(cur + 32768 + g*4096 + col*16);
                bfr[b][cb][1] = *(const bf16x8*)(cur + 49152 + g*4096 + col*16);
            }

        #pragma unroll
        for (int a=0; a<2; a++){
            bf16x8 af[4][2];
            #pragma unroll
            for (int fm=0; fm<4; fm++){
                int row = wm*128 + a*64 + fm*16 + ln;
                af[fm][0] = *(const bf16x8*)(cur + g*4096 + row*16);
                af[fm][1] = *(const bf16x8*)(cur + 16384 + g*4096 + row*16);
            }
            if (pre && a==0){
                #pragma unroll
                for (int j=0;j<4;j++) gload16(Ai + j*8192 + tid*16, nxt + j*8192 + tid*16);
            }
            if (pre && a==1){
                #pragma unroll
                for (int j=0;j<4;j++) gload16(Bi + j*8192 + tid*16, nxt + 32768 + j*8192 + tid*16);
            }
            __builtin_amdgcn_s_barrier();            // phase lock
            __builtin_amdgcn_s_setprio(1);
            #pragma unroll
            for (int fm=0; fm<4; fm++)
                #pragma unroll
                for (int b=0;b<2;b++)
                    #pragma unroll
                    for (int cb=0;cb<2;cb++){
                        const int m = a*4+fm, cfi = b*2+cb;
                        f32x4 x4 = acc[m][cfi];
                        x4 = MFMA(af[fm][0], bfr[b][cb][0], x4);
                        x4 = MFMA(af[fm][0], bfr[b][cb][1], x4);
                        x4 = MFMA(af[fm][1], bfr[b][cb][0], x4);
                        acc[m][cfi] = x4;
                    }
            __builtin_amdgcn_s_setprio(0);
            __builtin_amdgcn_s_barrier();
        }
        __syncthreads();                             // tile boundary: drain DMA into nxt
    }

    // epilogue: BN + LIF (acc[m][cf] components = the 4 t-steps of one (pair,col))
    #pragma unroll
    for (int cf=0; cf<4; cf++){
        const int c = nb*256 + wn*64 + cf*16 + ln;
        int which = c >> 9; if (which > 2) which = 2;
        const float* bp = which==0?b0:(which==1?b1:b2);
        const float* gp = which==0?g0:(which==1?g1:g2);
        const float* ep = which==0?e0:(which==1?e1:e2);
        const float* up = which==0?u0:(which==1?u1:u2);
        const float* vp = which==0?v0:(which==1?v1:v2);
        const int ci = c & cmask;
        const float gs  = gp[ci] / sqrtf(vp[ci] + BNEPS);
        const float bf_ = bp[ci], muf = up[ci], bef = ep[ci];
        #pragma unroll
        for (int m=0; m<8; m++){
            const int rowBase = wm*128 + m*16 + g*4;
            const int prow = pb*64 + (rowBase>>2);
            float v = 0.f;
            #pragma unroll
            for (int t=0; t<TT; t++){
                float y = acc[m][cf][t] + bf_;
                float z = (y - muf) * gs + bef;
                v = v + (z - v) * 0.5f;
                float s = ((v - 1.0f) >= 0.f) ? 1.f : 0.f;
                if (BITOUT){
                    u64 bal = __ballot(s != 0.f);
                    if (ln == 0)
                        *(u16*)(outp + (i64)(t*PH + prow)*(NCT>>3) + ((nb*256 + wn*64 + cf*16)>>3)) = (u16)(bal >> (g*16));
                } else {
                    outp[((i64)t*PH + prow)*NCT + c] = (u8)s;
                }
                v = v * (1.f - s);
            }
        }
    }
}

// ---------------- p stage: spikes x W-h GEMM + BN + LIF -> o2 (global) + f1 A-images (x+o2 split)
__global__ __launch_bounds__(256)
void gemm_p(const u8* __restrict__ Au8, const u16* __restrict__ WT,
            const float* __restrict__ bias, const float* __restrict__ gw,
            const float* __restrict__ bew,  const float* __restrict__ muw,
            const float* __restrict__ varw,
            const float* __restrict__ x, u8* __restrict__ o2g,
            u8* __restrict__ At, int pairBase)
{
    __shared__ __align__(16) char smem[16384];
    char* smA = smem;
    char* smB = smem + 8192;
    const int tid = threadIdx.x;
    const int nbp = blockIdx.x, pbp = blockIdx.y;
    const int c0 = nbp*128, pair0 = pbp*32;
    const int w = tid>>6, l = tid&63, g = l>>4, ln = l&15;
    const int wm = w>>1, wn = w&1;

    f32x4 acc[TT][4];
    #pragma unroll
    for (int t=0;t<TT;t++)
        #pragma unroll
        for (int cf=0;cf<4;cf++) acc[t][cf] = (f32x4)0.f;

    for (int k0 = 0; k0 < 512; k0 += 32){
        __syncthreads();
        {
            const int row = tid>>1, half = tid&1;
            const int t = row>>5, pp = row&31;
            const i64 grow = (i64)t*PH + pair0 + pp;
            uint4 ob = *(const uint4*)(Au8 + grow*512 + k0 + half*16);
            const u8* pbb = (const u8*)&ob;
            *(uint4*)(smA + swz(row, half*32))    = expand8(pbb);
            *(uint4*)(smA + swz(row, half*32+16)) = expand8(pbb+8);
        }
        #pragma unroll
        for (int j=0;j<2;j++){
            int cid = tid + j*256;
            int col = cid>>2, c = cid&3;
            uint4 d = *(const uint4*)(WT + (i64)(c0+col)*512 + k0 + c*8);
            *(uint4*)(smB + swz(col, c*16)) = d;
        }
        __syncthreads();
        bf16x8 bfr[4];
        #pragma unroll
        for (int cf=0;cf<4;cf++)
            bfr[cf] = *(const bf16x8*)(smB + swz(wn*64 + cf*16 + ln, g*16));
        #pragma unroll
        for (int t=0;t<TT;t++){
            bf16x8 afr = *(const bf16x8*)(smA + swz(t*32 + wm*16 + ln, g*16));
            #pragma unroll
            for (int cf=0;cf<4;cf++)
                acc[t][cf] = MFMA(afr, bfr[cf], acc[t][cf]);
        }
    }

    // epilogue: LIF -> spikes into LDS tile [t][rl 0..31][cL 0..127] u8 (16 KB)
    __syncthreads();
    u8* tile = (u8*)smem;
    #pragma unroll
    for (int cf=0;cf<4;cf++){
        const int c = c0 + wn*64 + cf*16 + ln;
        const float gs  = gw[c] / sqrtf(varw[c] + BNEPS);
        const float bf_ = bias[c], muf = muw[c], bef = bew[c];
        #pragma unroll
        for (int r=0;r<4;r++){
            const int rl = wm*16 + g*4 + r;
            float v = 0.f;
            #pragma unroll
            for (int t=0;t<TT;t++){
                float y = acc[t][cf][r] + bf_;
                float z = (y - muf) * gs + bef;
                v = v + (z - v) * 0.5f;
                float s = ((v - 1.0f) >= 0.f) ? 1.f : 0.f;
                tile[t*4096 + rl*128 + (wn*64 + cf*16 + ln)] = (u8)s;
                v = v * (1.f - s);
            }
        }
    }
    __syncthreads();

    // write o2 (global, local rows) + f1 A-images (x + o2, split2)
    const int pbImg = pbp>>1, rOff = (pbp&1)*128;
    #pragma unroll
    for (int it=0; it<8; it++){
        int task = tid + it*256;             // (kq 0..3, gq 0..3, rowL 0..127)
        int kq = task>>9, rem = task&511, gq = rem>>7, rowL = rem&127;
        int rl = rowL>>2, t = rowL&3;
        int ksAbs = nbp*4 + kq;
        int cL = kq*32 + gq*8;
        uint2 ob = *(const uint2*)(tile + t*4096 + rl*128 + cL);
        const u8* pbb = (const u8*)&ob;
        i64 grow = (i64)t*8192 + pairBase + pair0 + rl;
        const float* src = x + grow*512 + ksAbs*32 + gq*8;
        float4 f0 = *(const float4*)src, f1v = *(const float4*)(src+4);
        float vv[8] = {f0.x,f0.y,f0.z,f0.w,f1v.x,f1v.y,f1v.z,f1v.w};
        #pragma unroll
        for (int j=0;j<8;j++) vv[j] = vv[j] + (float)pbb[j];
        u16 h[8], m[8];
        #pragma unroll
        for (int j=0;j<8;j++) split2(vv[j], h[j], m[j]);
        u8* img = At + ((i64)pbImg*KSW + ksAbs)*32768;
        int off = gq*4096 + (rOff + rowL)*16;
        *(ushort4*)(img + off)           = make_ushort4(h[0],h[1],h[2],h[3]);
        *(ushort4*)(img + off + 8)       = make_ushort4(h[4],h[5],h[6],h[7]);
        *(ushort4*)(img + 16384 + off)   = make_ushort4(m[0],m[1],m[2],m[3]);
        *(ushort4*)(img + 16384 + off+8) = make_ushort4(m[4],m[5],m[6],m[7]);
        *(uint2*)(o2g + ((i64)t*PH + pair0 + rl)*512 + ksAbs*32 + gq*8) = ob;
    }
}

// ---------------- f2 stage: bitpacked spikes x W-h GEMM + BN + LIF + final add -> d_out f32
__global__ __launch_bounds__(256)
void gemm_f2(const u8* __restrict__ Abits, const u16* __restrict__ WT,
             const float* __restrict__ bias, const float* __restrict__ gw,
             const float* __restrict__ bew,  const float* __restrict__ muw,
             const float* __restrict__ varw,
             const float* __restrict__ x, const u8* __restrict__ o2g,
             float* __restrict__ outF, int pairBase)
{
    __shared__ __align__(16) char smem[16384];
    char* smA = smem;
    char* smB = smem + 8192;
    const int tid = threadIdx.x;
    const int c0 = blockIdx.x*128, pair0 = blockIdx.y*32;
    const int w = tid>>6, l = tid&63, g = l>>4, ln = l&15;
    const int wm = w>>1, wn = w&1;

    f32x4 acc[TT][4];
    #pragma unroll
    for (int t=0;t<TT;t++)
        #pragma unroll
        for (int cf=0;cf<4;cf++) acc[t][cf] = (f32x4)0.f;

    for (int k0 = 0; k0 < 2048; k0 += 32){
        __syncthreads();
        {
            const int row = tid>>1, half = tid&1;
            const int t = row>>5, pp = row&31;
            const i64 grow = (i64)t*PH + pair0 + pp;
            u32 bits = *(const u16*)(Abits + grow*256 + (k0>>3) + half*2);
            *(uint4*)(smA + swz(row, half*32))    = expandbits(bits);
            *(uint4*)(smA + swz(row, half*32+16)) = expandbits(bits>>8);
        }
        #pragma unroll
        for (int j=0;j<2;j++){
            int cid = tid + j*256;
            int col = cid>>2, c = cid&3;
            uint4 d = *(const uint4*)(WT + (i64)(c0+col)*2048 + k0 + c*8);
            *(uint4*)(smB + swz(col, c*16)) = d;
        }
        __syncthreads();
        bf16x8 bfr[4];
        #pragma unroll
        for (int cf=0;cf<4;cf++)
            bfr[cf] = *(const bf16x8*)(smB + swz(wn*64 + cf*16 + ln, g*16));
        #pragma unroll
        for (int t=0;t<TT;t++){
            bf16x8 afr = *(const bf16x8*)(smA + swz(t*32 + wm*16 + ln, g*16));
            #pragma unroll
            for (int cf=0;cf<4;cf++)
                acc[t][cf] = MFMA(afr, bfr[cf], acc[t][cf]);
        }
    }

    #pragma unroll
    for (int cf=0;cf<4;cf++){
        const int c = c0 + wn*64 + cf*16 + ln;
        const float gs  = gw[c] / sqrtf(varw[c] + BNEPS);
        const float bf_ = bias[c], muf = muw[c], bef = bew[c];
        #pragma unroll
        for (int r=0;r<4;r++){
            const int prow = pair0 + wm*16 + g*4 + r;
            float v = 0.f;
            #pragma unroll
            for (int t=0;t<TT;t++){
                float y = acc[t][cf][r] + bf_;
                float z = (y - muf) * gs + bef;
                v = v + (z - v) * 0.5f;
                float s = ((v - 1.0f) >= 0.f) ? 1.f : 0.f;
                i64 lrow = (i64)t*PH + prow;
                i64 grow = (i64)t*8192 + pairBase + prow;
                float xv = x[grow*512 + c];
                float o2v = (float)o2g[lrow*512 + c];
                float x1 = xv + o2v;
                outF[grow*512 + c] = x1 + s;
                v = v * (1.f - s);
            }
        }
    }
}

// ---------------- spiking attention + attn-LIF (v_th=0.5), qkv packed stride 1536
__global__ __launch_bounds__(256)
void attn_lif_kernel(const u8* __restrict__ qkv, u8* __restrict__ os)
{
    __shared__ __align__(16) char smem[49152];
    char* Kl = smem;
    char* VT = smem + 16384;
    char* AT = smem + 32768;

    const int tid = threadIdx.x;
    const int w = tid>>6, l = tid&63, g = l>>4, ln = l&15;
    const int h = blockIdx.y, b = blockIdx.z;
    const int n0 = blockIdx.x*64 + w*16;

    f32x4 vmem[4];
    #pragma unroll
    for (int cf=0;cf<4;cf++) vmem[cf] = (f32x4)0.f;

    for (int t=0;t<TT;t++){
        const i64 tb = ((i64)(t*16 + b)*256)*1536;
        const i64 ob = ((i64)(t*16 + b)*256)*512 + h*64;
        bf16x8 qf[2];
        #pragma unroll
        for (int ksl=0;ksl<2;ksl++){
            uint2 qv = *(const uint2*)(qkv + tb + (i64)(n0+ln)*1536 + h*64 + ksl*32 + g*8);
            const u8* pb = (const u8*)&qv;
            BF8 f;
            #pragma unroll
            for (int j=0;j<8;j++) f.u[j] = pb[j] ? 0x3F80 : 0;
            qf[ksl] = f.v;
        }
        f32x4 oacc[4];
        #pragma unroll
        for (int cf=0;cf<4;cf++) oacc[cf] = (f32x4)0.f;

        for (int mh=0; mh<2; mh++){
            __syncthreads();
            {
                const int lm = tid>>1, seg = tid&1;
                const u8* src = qkv + tb + (i64)(mh*128+lm)*1536 + 512 + h*64 + seg*32;
                uint4 a = *(const uint4*)(src), c = *(const uint4*)(src+16);
                const u8* pa = (const u8*)&a; const u8* pc = (const u8*)&c;
                #pragma unroll
                for (int q=0;q<4;q++){
                    *(ushort4*)(Kl + swzK(lm, seg*64 + q*8)) =
                        make_ushort4(pa[q*4]?0x3F80:0, pa[q*4+1]?0x3F80:0, pa[q*4+2]?0x3F80:0, pa[q*4+3]?0x3F80:0);
                    *(ushort4*)(Kl + swzK(lm, seg*64 + 32 + q*8)) =
                        make_ushort4(pc[q*4]?0x3F80:0, pc[q*4+1]?0x3F80:0, pc[q*4+2]?0x3F80:0, pc[q*4+3]?0x3F80:0);
                }
            }
            {
                const int lm = tid>>1, seg = tid&1;
                const u8* src = qkv + tb + (i64)(mh*128+lm)*1536 + 1024 + h*64 + seg*32;
                uint4 a = *(const uint4*)(src), c = *(const uint4*)(src+16);
                const u8* pa = (const u8*)&a; const u8* pc = (const u8*)&c;
                #pragma unroll
                for (int j=0;j<16;j++){
                    *(u16*)(VT + swzV(seg*32 + j,      lm*2)) = pa[j] ? 0x3F80 : 0;
                    *(u16*)(VT + swzV(seg*32 + 16 + j, lm*2)) = pc[j] ? 0x3F80 : 0;
                }
            }
            __syncthreads();
            #pragma unroll
            for (int rf=0;rf<8;rf++){
                f32x4 s = (f32x4)0.f;
                #pragma unroll
                for (int ksl=0;ksl<2;ksl++){
                    bf16x8 kf = *(const bf16x8*)(Kl + swzK(rf*16+ln, ksl*64 + g*16));
                    s = MFMA(kf, qf[ksl], s);
                }
                ushort4 pk = make_ushort4(f2bf_rne(s[0]*0.125f), f2bf_rne(s[1]*0.125f),
                                          f2bf_rne(s[2]*0.125f), f2bf_rne(s[3]*0.125f));
                *(ushort4*)(AT + swzV(w*16+ln, rf*32 + g*8)) = pk;
            }
            #pragma unroll
            for (int ms=0;ms<4;ms++){
                bf16x8 af = *(const bf16x8*)(AT + swzV(w*16+ln, ms*64 + g*16));
                #pragma unroll
                for (int cf=0;cf<4;cf++){
                    bf16x8 vf = *(const bf16x8*)(VT + swzV(cf*16+ln, ms*64 + g*16));
                    oacc[cf] = MFMA(af, vf, oacc[cf]);
                }
            }
        }
        #pragma unroll
        for (int cf=0;cf<4;cf++)
            #pragma unroll
            for (int r=0;r<4;r++){
                float v = vmem[cf][r];
                v = v + (oacc[cf][r] - v) * 0.5f;
                float s = ((v - 0.5f) >= 0.f) ? 1.f : 0.f;
                os[ob + (i64)(n0 + g*4 + r)*512 + cf*16 + ln] = (u8)s;
                vmem[cf][r] = v * (1.f - s);
            }
    }
}

extern "C" void kernel_launch(void* const* d_in, const int* in_sizes, int n_in,
                              void* d_out, int out_size, void* d_ws, size_t ws_size,
                              hipStream_t stream)
{
    (void)in_sizes; (void)n_in; (void)out_size; (void)ws_size;
    const float* x = (const float*)d_in[0];
    #define GETP(i) ((const float*)d_in[i])

    char* ws = (char*)d_ws;
    u8*  Bqkv = (u8*)(ws + 0);               //  6*16*32768 = 3,145,728
    u8*  Bf1  = (u8*)(ws + 3145728);         //  8*16*32768 = 4,194,304
    u16* WTp  = (u16*)(ws + 7340032);        //  524,288
    u16* WTf2 = (u16*)(ws + 7864320);        //  2,097,152
    u8*  At   = (u8*)(ws + 10485760);        // 64*16*32768 = 33,554,432
    u8*  qkv  = (u8*)(ws + 44040192);        // 25,165,824
    u8*  os_  = (u8*)(ws + 69206016);        //  8,388,608
    u8*  o2   = (u8*)(ws + 77594624);        //  8,388,608
    u8*  hhb  = (u8*)(ws + 85983232);        //  4,194,304  (ends 90,177,536)

    hipFuncSetAttribute((const void*)gemm8<false>, hipFuncAttributeMaxDynamicSharedMemorySize, 131072);
    hipFuncSetAttribute((const void*)gemm8<true>,  hipFuncAttributeMaxDynamicSharedMemorySize, 131072);

    dim3 blk(256,1,1);
    // W prep
    wsplit2<<<dim3(16,2), blk,0,stream>>>(GETP(1),  Bqkv, 512, 0);
    wsplit2<<<dim3(16,2), blk,0,stream>>>(GETP(7),  Bqkv, 512, 2);
    wsplit2<<<dim3(16,2), blk,0,stream>>>(GETP(13), Bqkv, 512, 4);
    wsplit2<<<dim3(16,8), blk,0,stream>>>(GETP(25), Bf1, 2048, 0);
    wsplit_old<<<dim3(8,8), blk,0,stream>>>(GETP(19), WTp, 512, 512);
    wsplit_old<<<dim3(32,8),blk,0,stream>>>(GETP(31), WTf2, 2048, 512);

    for (int hb = 0; hb < 2; hb++){
        const int pb = hb * PH;
        asplitT<<<dim3(64,16),blk,0,stream>>>(x, At, pb);
        // fused q/k/v (N=1536, NB=6, grid 384)
        gemm8<false><<<dim3(384),dim3(512),131072,stream>>>(At, Bqkv,
            GETP(2),GETP(8),GETP(14),  GETP(3),GETP(9),GETP(15),
            GETP(4),GETP(10),GETP(16), GETP(5),GETP(11),GETP(17),
            GETP(6),GETP(12),GETP(18), qkv, 6, 1536, 511);
        attn_lif_kernel<<<dim3(4,8,16),blk,0,stream>>>(qkv, os_);
        // p stage + fused o2/f1-image production
        gemm_p<<<dim3(4,128),blk,0,stream>>>(os_, WTp,
            GETP(20),GETP(21),GETP(22),GETP(23),GETP(24), x, o2, At, pb);
        // f1 (N=2048, NB=8, grid 512, bitpacked out)
        gemm8<true><<<dim3(512),dim3(512),131072,stream>>>(At, Bf1,
            GETP(26),GETP(26),GETP(26), GETP(27),GETP(27),GETP(27),
            GETP(28),GETP(28),GETP(28), GETP(29),GETP(29),GETP(29),
            GETP(30),GETP(30),GETP(30), hhb, 8, 2048, 2047);
        // f2 + fused final add -> d_out
        gemm_f2<<<dim3(4,128),blk,0,stream>>>(hhb, WTf2,
            GETP(32),GETP(33),GETP(34),GETP(35),GETP(36), x, o2, (float*)d_out, pb);
    }
}

// Round 8
// 639.016 us; speedup vs baseline: 4.6541x; 1.0165x over previous
//
#include <hip/hip_runtime.h>

typedef unsigned char u8;
typedef unsigned short u16;
typedef unsigned int u32;
typedef unsigned long long u64;
typedef long long i64;

#define TT 4
#define PH 4096             // pairs per half
#define KSW 16              // K/32 images for K=512
#define BNEPS 1e-5f

typedef __attribute__((ext_vector_type(8))) __bf16 bf16x8;
typedef __attribute__((ext_vector_type(4))) float f32x4;

__device__ __forceinline__ float bf2f(u16 b){ return __uint_as_float(((u32)b)<<16); }
__device__ __forceinline__ u16 f2bf_rne(float f){ u32 u = __float_as_uint(f); return (u16)((u + 0x7FFFu + ((u>>16)&1u))>>16); }
__device__ __forceinline__ u16 f2bf_tr(float f){ return (u16)(__float_as_uint(f)>>16); }

__device__ __forceinline__ void split2(float v, u16& h, u16& m){
    h = f2bf_tr(v); m = f2bf_tr(v - bf2f(h));
}
__device__ __forceinline__ void split3(float v, u16& h, u16& m, u16& l){
    h = f2bf_tr(v); float r  = v - bf2f(h);
    m = f2bf_tr(r); float r2 = r - bf2f(m);
    l = f2bf_tr(r2);
}

__device__ __forceinline__ f32x4 MFMA(bf16x8 a, bf16x8 b, f32x4 c){
    return __builtin_amdgcn_mfma_f32_16x16x32_bf16(a, b, c, 0, 0, 0);
}

union BF8 { u16 u[8]; bf16x8 v; };

__device__ __forceinline__ void gload16(const void* g, void* l){
    __builtin_amdgcn_global_load_lds(
        (const __attribute__((address_space(1))) unsigned int*)g,
        (__attribute__((address_space(3))) unsigned int*)l, 16, 0, 0);
}

// reg-staged kernels' swizzles (validated r3-r7)
__device__ __forceinline__ int swz(int row, int off){ return row*64 + (off ^ (((row>>1)&3)<<4)); }
__device__ __forceinline__ int swzK(int row, int off){ return row*128 + (off ^ ((row&7)<<4)); }
__device__ __forceinline__ int swzV(int row, int off){ return row*256 + (off ^ ((row&7)<<4)); }

__device__ __forceinline__ uint4 expand8(const u8* pb){
    u32 w0 = (pb[0]?0x3F80u:0u) | ((pb[1]?0x3F80u:0u)<<16);
    u32 w1 = (pb[2]?0x3F80u:0u) | ((pb[3]?0x3F80u:0u)<<16);
    u32 w2 = (pb[4]?0x3F80u:0u) | ((pb[5]?0x3F80u:0u)<<16);
    u32 w3 = (pb[6]?0x3F80u:0u) | ((pb[7]?0x3F80u:0u)<<16);
    return make_uint4(w0,w1,w2,w3);
}
__device__ __forceinline__ uint4 expandbits(u32 bits){
    u32 w0 = ((bits>>0)&1?0x3F80u:0u) | ((bits>>1)&1?0x3F800000u:0u);
    u32 w1 = ((bits>>2)&1?0x3F80u:0u) | ((bits>>3)&1?0x3F800000u:0u);
    u32 w2 = ((bits>>4)&1?0x3F80u:0u) | ((bits>>5)&1?0x3F800000u:0u);
    u32 w3 = ((bits>>6)&1?0x3F80u:0u) | ((bits>>7)&1?0x3F800000u:0u);
    return make_uint4(w0,w1,w2,w3);
}

// ---------------- W -> 256-col tiled images: img(nb,ks)[pl][g][col 0..255][16B]
__global__ __launch_bounds__(256)
void wsplit2(const float* __restrict__ W, u8* __restrict__ out, int NC, int nbOff)
{
    const int ks = blockIdx.x, nbl = blockIdx.y;
    const int c0 = nbl*256;
    u8* img = out + ((i64)(nbOff+nbl)*KSW + ks)*32768;
    #pragma unroll
    for (int it=0; it<4; it++){
        int task = threadIdx.x + it*256;     // (col 0..255, gq minor 0..3)
        int col = task>>2, gq = task&3;
        float v[8];
        #pragma unroll
        for (int j=0;j<8;j++) v[j] = W[(i64)(ks*32 + gq*8 + j)*NC + c0 + col];
        u16 h[8], m[8];
        #pragma unroll
        for (int j=0;j<8;j++) split2(v[j], h[j], m[j]);
        int off = gq*4096 + col*16;
        *(ushort4*)(img + off)           = make_ushort4(h[0],h[1],h[2],h[3]);
        *(ushort4*)(img + off + 8)       = make_ushort4(h[4],h[5],h[6],h[7]);
        *(ushort4*)(img + 16384 + off)   = make_ushort4(m[0],m[1],m[2],m[3]);
        *(ushort4*)(img + 16384 + off+8) = make_ushort4(m[4],m[5],m[6],m[7]);
    }
}

// ---------------- W -> h-plane only [NC][K] (for p/f2 reg-staged GEMMs)
__global__ __launch_bounds__(256)
void wsplit_old(const float* __restrict__ W, u16* __restrict__ out, int K, int NC)
{
    __shared__ float tile[64][65];
    const int k0 = blockIdx.x*64, c0 = blockIdx.y*64;
    const int tid = threadIdx.x;
    #pragma unroll
    for (int j=0;j<16;j++){
        int el = tid + j*256; int r = el>>6, c = el&63;
        tile[r][c] = W[(i64)(k0+r)*NC + c0 + c];
    }
    __syncthreads();
    #pragma unroll
    for (int j=0;j<16;j++){
        int el = tid + j*256; int c = el>>6, k = el&63;
        u16 h,m,l; split3(tile[k][c],h,m,l);
        out[(i64)(c0+c)*K + k0 + k] = h;
    }
}

// ---------------- x -> A images: img(pb,ks)[pl][g][row 0..255][16B], row = pair*4 + t
__global__ __launch_bounds__(256)
void asplitT(const float* __restrict__ x, u8* __restrict__ At, int pairBase)
{
    const int pb = blockIdx.x, ks = blockIdx.y;
    u8* img = At + ((i64)pb*KSW + ks)*32768;
    #pragma unroll
    for (int it=0; it<4; it++){
        int task = threadIdx.x + it*256;     // (row 0..255, gq minor)
        int row = task>>2, gq = task&3;
        int pair = row>>2, t = row&3;
        i64 grow = (i64)t*8192 + pairBase + pb*64 + pair;
        const float* src = x + grow*512 + ks*32 + gq*8;
        float4 f0 = *(const float4*)src, f1v = *(const float4*)(src+4);
        float vv[8] = {f0.x,f0.y,f0.z,f0.w,f1v.x,f1v.y,f1v.z,f1v.w};
        u16 h[8], m[8];
        #pragma unroll
        for (int j=0;j<8;j++) split2(vv[j], h[j], m[j]);
        int off = gq*4096 + row*16;
        *(ushort4*)(img + off)           = make_ushort4(h[0],h[1],h[2],h[3]);
        *(ushort4*)(img + off + 8)       = make_ushort4(h[4],h[5],h[6],h[7]);
        *(ushort4*)(img + 16384 + off)   = make_ushort4(m[0],m[1],m[2],m[3]);
        *(ushort4*)(img + 16384 + off+8) = make_ushort4(m[4],m[5],m[6],m[7]);
    }
}

// ---------------- 8-wave 256x256 GEMM + BN + LIF, free-running waves (no phase locks)
// tile: 256 rows (64 pairs x 4t) x 256 cols, BK=32, dbuf 2x64KB LDS.
// 8 waves 2Mx4N, wave = 128x64. Only sync: __syncthreads at tile boundary.
template<bool BITOUT>
__global__ __launch_bounds__(512,2)
void gemm8(const u8* __restrict__ At, const u8* __restrict__ Bt,
           const float* __restrict__ b0, const float* __restrict__ b1, const float* __restrict__ b2,
           const float* __restrict__ g0, const float* __restrict__ g1, const float* __restrict__ g2,
           const float* __restrict__ e0, const float* __restrict__ e1, const float* __restrict__ e2,
           const float* __restrict__ u0, const float* __restrict__ u1, const float* __restrict__ u2,
           const float* __restrict__ v0, const float* __restrict__ v1, const float* __restrict__ v2,
           u8* __restrict__ outp, int NB, int NCT, int cmask)
{
    extern __shared__ __align__(16) char smem[];     // 131072: 2 x (A 32K + B 32K)
    const int tid = threadIdx.x;
    // XCD-chunked swizzle, pb-major within chunk (grid % 8 == 0)
    const int cpx = gridDim.x >> 3;
    const int serial = (blockIdx.x & 7)*cpx + (blockIdx.x >> 3);
    const int pb = serial / NB, nb = serial % NB;

    const int w = tid>>6, lane = tid&63, g = lane>>4, ln = lane&15;
    const int wm = w>>2, wn = w&3;                   // 2M x 4N

    f32x4 acc[8][4];
    #pragma unroll
    for (int m=0;m<8;m++)
        #pragma unroll
        for (int cf=0;cf<4;cf++) acc[m][cf] = (f32x4)0.f;

    const u8* Ab = At + (i64)pb*KSW*32768;
    const u8* Bb = Bt + (i64)nb*KSW*32768;

    // prologue: stage tile 0
    #pragma unroll
    for (int j=0;j<4;j++){
        gload16(Ab + j*8192 + tid*16, smem + j*8192 + tid*16);
        gload16(Bb + j*8192 + tid*16, smem + 32768 + j*8192 + tid*16);
    }
    __syncthreads();

    for (int ks=0; ks<KSW; ks++){
        char* cur = smem + (ks&1)*65536;
        char* nxt = smem + ((ks+1)&1)*65536;
        const bool pre = (ks+1 < KSW);
        const u8* Ai = Ab + (i64)(ks+1)*32768;
        const u8* Bi = Bb + (i64)(ks+1)*32768;

        // issue A-prefetch first (max in-flight cover)
        if (pre){
            #pragma unroll
            for (int j=0;j<4;j++) gload16(Ai + j*8192 + tid*16, nxt + j*8192 + tid*16);
        }
        // hoist all B fragments for this tile (read ONCE)
        bf16x8 bfr[2][2][2];     // [b-half][cb][plane]
        #pragma unroll
        for (int b=0;b<2;b++)
            #pragma unroll
            for (int cb=0;cb<2;cb++){
                int col = wn*64 + b*32 + cb*16 + ln;
                bfr[b][cb][0] = *(const bf16x8*)(cur + 32768 + g*4096 + col*16);
                bfr[b][cb][1] = *(const bf16x8*)(cur + 49152 + g*4096 + col*16);
            }

        // ---- phase 0 (m-half a=0): reads + MFMA, waves free-run
        {
            bf16x8 af[4][2];
            #pragma unroll
            for (int fm=0; fm<4; fm++){
                int row = wm*128 + 0*64 + fm*16 + ln;
                af[fm][0] = *(const bf16x8*)(cur + g*4096 + row*16);
                af[fm][1] = *(const bf16x8*)(cur + 16384 + g*4096 + row*16);
            }
            __builtin_amdgcn_s_setprio(1);
            #pragma unroll
            for (int fm=0; fm<4; fm++)
                #pragma unroll
                for (int b=0;b<2;b++)
                    #pragma unroll
                    for (int cb=0;cb<2;cb++){
                        const int m = 0*4+fm, cfi = b*2+cb;
                        f32x4 x4 = acc[m][cfi];
                        x4 = MFMA(af[fm][0], bfr[b][cb][0], x4);
                        x4 = MFMA(af[fm][0], bfr[b][cb][1], x4);
                        x4 = MFMA(af[fm][1], bfr[b][cb][0], x4);
                        acc[m][cfi] = x4;
                    }
            __builtin_amdgcn_s_setprio(0);
        }
        __builtin_amdgcn_sched_barrier(0);   // keep phase-1 reads below phase-0 MFMAs
        // issue B-prefetch
        if (pre){
            #pragma unroll
            for (int j=0;j<4;j++) gload16(Bi + j*8192 + tid*16, nxt + 32768 + j*8192 + tid*16);
        }
        // ---- phase 1 (m-half a=1)
        {
            bf16x8 af[4][2];
            #pragma unroll
            for (int fm=0; fm<4; fm++){
                int row = wm*128 + 1*64 + fm*16 + ln;
                af[fm][0] = *(const bf16x8*)(cur + g*4096 + row*16);
                af[fm][1] = *(const bf16x8*)(cur + 16384 + g*4096 + row*16);
            }
            __builtin_amdgcn_s_setprio(1);
            #pragma unroll
            for (int fm=0; fm<4; fm++)
                #pragma unroll
                for (int b=0;b<2;b++)
                    #pragma unroll
                    for (int cb=0;cb<2;cb++){
                        const int m = 1*4+fm, cfi = b*2+cb;
                        f32x4 x4 = acc[m][cfi];
                        x4 = MFMA(af[fm][0], bfr[b][cb][0], x4);
                        x4 = MFMA(af[fm][0], bfr[b][cb][1], x4);
                        x4 = MFMA(af[fm][1], bfr[b][cb][0], x4);
                        acc[m][cfi] = x4;
                    }
            __builtin_amdgcn_s_setprio(0);
        }
        __syncthreads();   // tile boundary: all reads of cur done, all DMAs to nxt landed
    }

    // epilogue: BN + LIF (acc[m][cf] components = the 4 t-steps of one (pair,col))
    #pragma unroll
    for (int cf=0; cf<4; cf++){
        const int c = nb*256 + wn*64 + cf*16 + ln;
        int which = c >> 9; if (which > 2) which = 2;
        const float* bp = which==0?b0:(which==1?b1:b2);
        const float* gp = which==0?g0:(which==1?g1:g2);
        const float* ep = which==0?e0:(which==1?e1:e2);
        const float* up = which==0?u0:(which==1?u1:u2);
        const float* vp = which==0?v0:(which==1?v1:v2);
        const int ci = c & cmask;
        const float gs  = gp[ci] / sqrtf(vp[ci] + BNEPS);
        const float bf_ = bp[ci], muf = up[ci], bef = ep[ci];
        #pragma unroll
        for (int m=0; m<8; m++){
            const int rowBase = wm*128 + m*16 + g*4;
            const int prow = pb*64 + (rowBase>>2);
            float v = 0.f;
            #pragma unroll
            for (int t=0; t<TT; t++){
                float y = acc[m][cf][t] + bf_;
                float z = (y - muf) * gs + bef;
                v = v + (z - v) * 0.5f;
                float s = ((v - 1.0f) >= 0.f) ? 1.f : 0.f;
                if (BITOUT){
                    u64 bal = __ballot(s != 0.f);
                    if (ln == 0)
                        *(u16*)(outp + (i64)(t*PH + prow)*(NCT>>3) + ((nb*256 + wn*64 + cf*16)>>3)) = (u16)(bal >> (g*16));
                } else {
                    outp[((i64)t*PH + prow)*NCT + c] = (u8)s;
                }
                v = v * (1.f - s);
            }
        }
    }
}

// ---------------- p stage: spikes x W-h GEMM + BN + LIF -> o2 (global) + f1 A-images (x+o2 split)
__global__ __launch_bounds__(256)
void gemm_p(const u8* __restrict__ Au8, const u16* __restrict__ WT,
            const float* __restrict__ bias, const float* __restrict__ gw,
            const float* __restrict__ bew,  const float* __restrict__ muw,
            const float* __restrict__ varw,
            const float* __restrict__ x, u8* __restrict__ o2g,
            u8* __restrict__ At, int pairBase)
{
    __shared__ __align__(16) char smem[16384];
    char* smA = smem;
    char* smB = smem + 8192;
    const int tid = threadIdx.x;
    const int nbp = blockIdx.x, pbp = blockIdx.y;
    const int c0 = nbp*128, pair0 = pbp*32;
    const int w = tid>>6, l = tid&63, g = l>>4, ln = l&15;
    const int wm = w>>1, wn = w&1;

    f32x4 acc[TT][4];
    #pragma unroll
    for (int t=0;t<TT;t++)
        #pragma unroll
        for (int cf=0;cf<4;cf++) acc[t][cf] = (f32x4)0.f;

    for (int k0 = 0; k0 < 512; k0 += 32){
        __syncthreads();
        {
            const int row = tid>>1, half = tid&1;
            const int t = row>>5, pp = row&31;
            const i64 grow = (i64)t*PH + pair0 + pp;
            uint4 ob = *(const uint4*)(Au8 + grow*512 + k0 + half*16);
            const u8* pbb = (const u8*)&ob;
            *(uint4*)(smA + swz(row, half*32))    = expand8(pbb);
            *(uint4*)(smA + swz(row, half*32+16)) = expand8(pbb+8);
        }
        #pragma unroll
        for (int j=0;j<2;j++){
            int cid = tid + j*256;
            int col = cid>>2, c = cid&3;
            uint4 d = *(const uint4*)(WT + (i64)(c0+col)*512 + k0 + c*8);
            *(uint4*)(smB + swz(col, c*16)) = d;
        }
        __syncthreads();
        bf16x8 bfr[4];
        #pragma unroll
        for (int cf=0;cf<4;cf++)
            bfr[cf] = *(const bf16x8*)(smB + swz(wn*64 + cf*16 + ln, g*16));
        #pragma unroll
        for (int t=0;t<TT;t++){
            bf16x8 afr = *(const bf16x8*)(smA + swz(t*32 + wm*16 + ln, g*16));
            #pragma unroll
            for (int cf=0;cf<4;cf++)
                acc[t][cf] = MFMA(afr, bfr[cf], acc[t][cf]);
        }
    }

    // epilogue: LIF -> spikes into LDS tile [t][rl 0..31][cL 0..127] u8 (16 KB)
    __syncthreads();
    u8* tile = (u8*)smem;
    #pragma unroll
    for (int cf=0;cf<4;cf++){
        const int c = c0 + wn*64 + cf*16 + ln;
        const float gs  = gw[c] / sqrtf(varw[c] + BNEPS);
        const float bf_ = bias[c], muf = muw[c], bef = bew[c];
        #pragma unroll
        for (int r=0;r<4;r++){
            const int rl = wm*16 + g*4 + r;
            float v = 0.f;
            #pragma unroll
            for (int t=0;t<TT;t++){
                float y = acc[t][cf][r] + bf_;
                float z = (y - muf) * gs + bef;
                v = v + (z - v) * 0.5f;
                float s = ((v - 1.0f) >= 0.f) ? 1.f : 0.f;
                tile[t*4096 + rl*128 + (wn*64 + cf*16 + ln)] = (u8)s;
                v = v * (1.f - s);
            }
        }
    }
    __syncthreads();

    // write o2 (global, local rows) + f1 A-images (x + o2, split2)
    const int pbImg = pbp>>1, rOff = (pbp&1)*128;
    #pragma unroll
    for (int it=0; it<8; it++){
        int task = tid + it*256;             // (kq 0..3, gq 0..3, rowL 0..127)
        int kq = task>>9, rem = task&511, gq = rem>>7, rowL = rem&127;
        int rl = rowL>>2, t = rowL&3;
        int ksAbs = nbp*4 + kq;
        int cL = kq*32 + gq*8;
        uint2 ob = *(const uint2*)(tile + t*4096 + rl*128 + cL);
        const u8* pbb = (const u8*)&ob;
        i64 grow = (i64)t*8192 + pairBase + pair0 + rl;
        const float* src = x + grow*512 + ksAbs*32 + gq*8;
        float4 f0 = *(const float4*)src, f1v = *(const float4*)(src+4);
        float vv[8] = {f0.x,f0.y,f0.z,f0.w,f1v.x,f1v.y,f1v.z,f1v.w};
        #pragma unroll
        for (int j=0;j<8;j++) vv[j] = vv[j] + (float)pbb[j];
        u16 h[8], m[8];
        #pragma unroll
        for (int j=0;j<8;j++) split2(vv[j], h[j], m[j]);
        u8* img = At + ((i64)pbImg*KSW + ksAbs)*32768;
        int off = gq*4096 + (rOff + rowL)*16;
        *(ushort4*)(img + off)           = make_ushort4(h[0],h[1],h[2],h[3]);
        *(ushort4*)(img + off + 8)       = make_ushort4(h[4],h[5],h[6],h[7]);
        *(ushort4*)(img + 16384 + off)   = make_ushort4(m[0],m[1],m[2],m[3]);
        *(ushort4*)(img + 16384 + off+8) = make_ushort4(m[4],m[5],m[6],m[7]);
        *(uint2*)(o2g + ((i64)t*PH + pair0 + rl)*512 + ksAbs*32 + gq*8) = ob;
    }
}

// ---------------- f2 stage: bitpacked spikes x W-h GEMM + BN + LIF + final add -> d_out f32
__global__ __launch_bounds__(256)
void gemm_f2(const u8* __restrict__ Abits, const u16* __restrict__ WT,
             const float* __restrict__ bias, const float* __restrict__ gw,
             const float* __restrict__ bew,  const float* __restrict__ muw,
             const float* __restrict__ varw,
             const float* __restrict__ x, const u8* __restrict__ o2g,
             float* __restrict__ outF, int pairBase)
{
    __shared__ __align__(16) char smem[16384];
    char* smA = smem;
    char* smB = smem + 8192;
    const int tid = threadIdx.x;
    const int c0 = blockIdx.x*128, pair0 = blockIdx.y*32;
    const int w = tid>>6, l = tid&63, g = l>>4, ln = l&15;
    const int wm = w>>1, wn = w&1;

    f32x4 acc[TT][4];
    #pragma unroll
    for (int t=0;t<TT;t++)
        #pragma unroll
        for (int cf=0;cf<4;cf++) acc[t][cf] = (f32x4)0.f;

    for (int k0 = 0; k0 < 2048; k0 += 32){
        __syncthreads();
        {
            const int row = tid>>1, half = tid&1;
            const int t = row>>5, pp = row&31;
            const i64 grow = (i64)t*PH + pair0 + pp;
            u32 bits = *(const u16*)(Abits + grow*256 + (k0>>3) + half*2);
            *(uint4*)(smA + swz(row, half*32))    = expandbits(bits);
            *(uint4*)(smA + swz(row, half*32+16)) = expandbits(bits>>8);
        }
        #pragma unroll
        for (int j=0;j<2;j++){
            int cid = tid + j*256;
            int col = cid>>2, c = cid&3;
            uint4 d = *(const uint4*)(WT + (i64)(c0+col)*2048 + k0 + c*8);
            *(uint4*)(smB + swz(col, c*16)) = d;
        }
        __syncthreads();
        bf16x8 bfr[4];
        #pragma unroll
        for (int cf=0;cf<4;cf++)
            bfr[cf] = *(const bf16x8*)(smB + swz(wn*64 + cf*16 + ln, g*16));
        #pragma unroll
        for (int t=0;t<TT;t++){
            bf16x8 afr = *(const bf16x8*)(smA + swz(t*32 + wm*16 + ln, g*16));
            #pragma unroll
            for (int cf=0;cf<4;cf++)
                acc[t][cf] = MFMA(afr, bfr[cf], acc[t][cf]);
        }
    }

    #pragma unroll
    for (int cf=0;cf<4;cf++){
        const int c = c0 + wn*64 + cf*16 + ln;
        const float gs  = gw[c] / sqrtf(varw[c] + BNEPS);
        const float bf_ = bias[c], muf = muw[c], bef = bew[c];
        #pragma unroll
        for (int r=0;r<4;r++){
            const int prow = pair0 + wm*16 + g*4 + r;
            float v = 0.f;
            #pragma unroll
            for (int t=0;t<TT;t++){
                float y = acc[t][cf][r] + bf_;
                float z = (y - muf) * gs + bef;
                v = v + (z - v) * 0.5f;
                float s = ((v - 1.0f) >= 0.f) ? 1.f : 0.f;
                i64 lrow = (i64)t*PH + prow;
                i64 grow = (i64)t*8192 + pairBase + prow;
                float xv = x[grow*512 + c];
                float o2v = (float)o2g[lrow*512 + c];
                float x1 = xv + o2v;
                outF[grow*512 + c] = x1 + s;
                v = v * (1.f - s);
            }
        }
    }
}

// ---------------- spiking attention + attn-LIF (v_th=0.5), qkv packed stride 1536
__global__ __launch_bounds__(256)
void attn_lif_kernel(const u8* __restrict__ qkv, u8* __restrict__ os)
{
    __shared__ __align__(16) char smem[49152];
    char* Kl = smem;
    char* VT = smem + 16384;
    char* AT = smem + 32768;

    const int tid = threadIdx.x;
    const int w = tid>>6, l = tid&63, g = l>>4, ln = l&15;
    const int h = blockIdx.y, b = blockIdx.z;
    const int n0 = blockIdx.x*64 + w*16;

    f32x4 vmem[4];
    #pragma unroll
    for (int cf=0;cf<4;cf++) vmem[cf] = (f32x4)0.f;

    for (int t=0;t<TT;t++){
        const i64 tb = ((i64)(t*16 + b)*256)*1536;
        const i64 ob = ((i64)(t*16 + b)*256)*512 + h*64;
        bf16x8 qf[2];
        #pragma unroll
        for (int ksl=0;ksl<2;ksl++){
            uint2 qv = *(const uint2*)(qkv + tb + (i64)(n0+ln)*1536 + h*64 + ksl*32 + g*8);
            const u8* pb = (const u8*)&qv;
            BF8 f;
            #pragma unroll
            for (int j=0;j<8;j++) f.u[j] = pb[j] ? 0x3F80 : 0;
            qf[ksl] = f.v;
        }
        f32x4 oacc[4];
        #pragma unroll
        for (int cf=0;cf<4;cf++) oacc[cf] = (f32x4)0.f;

        for (int mh=0; mh<2; mh++){
            __syncthreads();
            {
                const int lm = tid>>1, seg = tid&1;
                const u8* src = qkv + tb + (i64)(mh*128+lm)*1536 + 512 + h*64 + seg*32;
                uint4 a = *(const uint4*)(src), c = *(const uint4*)(src+16);
                const u8* pa = (const u8*)&a; const u8* pc = (const u8*)&c;
                #pragma unroll
                for (int q=0;q<4;q++){
                    *(ushort4*)(Kl + swzK(lm, seg*64 + q*8)) =
                        make_ushort4(pa[q*4]?0x3F80:0, pa[q*4+1]?0x3F80:0, pa[q*4+2]?0x3F80:0, pa[q*4+3]?0x3F80:0);
                    *(ushort4*)(Kl + swzK(lm, seg*64 + 32 + q*8)) =
                        make_ushort4(pc[q*4]?0x3F80:0, pc[q*4+1]?0x3F80:0, pc[q*4+2]?0x3F80:0, pc[q*4+3]?0x3F80:0);
                }
            }
            {
                const int lm = tid>>1, seg = tid&1;
                const u8* src = qkv + tb + (i64)(mh*128+lm)*1536 + 1024 + h*64 + seg*32;
                uint4 a = *(const uint4*)(src), c = *(const uint4*)(src+16);
                const u8* pa = (const u8*)&a; const u8* pc = (const u8*)&c;
                #pragma unroll
                for (int j=0;j<16;j++){
                    *(u16*)(VT + swzV(seg*32 + j,      lm*2)) = pa[j] ? 0x3F80 : 0;
                    *(u16*)(VT + swzV(seg*32 + 16 + j, lm*2)) = pc[j] ? 0x3F80 : 0;
                }
            }
            __syncthreads();
            #pragma unroll
            for (int rf=0;rf<8;rf++){
                f32x4 s = (f32x4)0.f;
                #pragma unroll
                for (int ksl=0;ksl<2;ksl++){
                    bf16x8 kf = *(const bf16x8*)(Kl + swzK(rf*16+ln, ksl*64 + g*16));
                    s = MFMA(kf, qf[ksl], s);
                }
                ushort4 pk = make_ushort4(f2bf_rne(s[0]*0.125f), f2bf_rne(s[1]*0.125f),
                                          f2bf_rne(s[2]*0.125f), f2bf_rne(s[3]*0.125f));
                *(ushort4*)(AT + swzV(w*16+ln, rf*32 + g*8)) = pk;
            }
            #pragma unroll
            for (int ms=0;ms<4;ms++){
                bf16x8 af = *(const bf16x8*)(AT + swzV(w*16+ln, ms*64 + g*16));
                #pragma unroll
                for (int cf=0;cf<4;cf++){
                    bf16x8 vf = *(const bf16x8*)(VT + swzV(cf*16+ln, ms*64 + g*16));
                    oacc[cf] = MFMA(af, vf, oacc[cf]);
                }
            }
        }
        #pragma unroll
        for (int cf=0;cf<4;cf++)
            #pragma unroll
            for (int r=0;r<4;r++){
                float v = vmem[cf][r];
                v = v + (oacc[cf][r] - v) * 0.5f;
                float s = ((v - 0.5f) >= 0.f) ? 1.f : 0.f;
                os[ob + (i64)(n0 + g*4 + r)*512 + cf*16 + ln] = (u8)s;
                vmem[cf][r] = v * (1.f - s);
            }
    }
}

extern "C" void kernel_launch(void* const* d_in, const int* in_sizes, int n_in,
                              void* d_out, int out_size, void* d_ws, size_t ws_size,
                              hipStream_t stream)
{
    (void)in_sizes; (void)n_in; (void)out_size; (void)ws_size;
    const float* x = (const float*)d_in[0];
    #define GETP(i) ((const float*)d_in[i])

    char* ws = (char*)d_ws;
    u8*  Bqkv = (u8*)(ws + 0);               //  6*16*32768 = 3,145,728
    u8*  Bf1  = (u8*)(ws + 3145728);         //  8*16*32768 = 4,194,304
    u16* WTp  = (u16*)(ws + 7340032);        //  524,288
    u16* WTf2 = (u16*)(ws + 7864320);        //  2,097,152
    u8*  At   = (u8*)(ws + 10485760);        // 64*16*32768 = 33,554,432
    u8*  qkv  = (u8*)(ws + 44040192);        // 25,165,824
    u8*  os_  = (u8*)(ws + 69206016);        //  8,388,608
    u8*  o2   = (u8*)(ws + 77594624);        //  8,388,608
    u8*  hhb  = (u8*)(ws + 85983232);        //  4,194,304  (ends 90,177,536)

    hipFuncSetAttribute((const void*)gemm8<false>, hipFuncAttributeMaxDynamicSharedMemorySize, 131072);
    hipFuncSetAttribute((const void*)gemm8<true>,  hipFuncAttributeMaxDynamicSharedMemorySize, 131072);

    dim3 blk(256,1,1);
    // W prep
    wsplit2<<<dim3(16,2), blk,0,stream>>>(GETP(1),  Bqkv, 512, 0);
    wsplit2<<<dim3(16,2), blk,0,stream>>>(GETP(7),  Bqkv, 512, 2);
    wsplit2<<<dim3(16,2), blk,0,stream>>>(GETP(13), Bqkv, 512, 4);
    wsplit2<<<dim3(16,8), blk,0,stream>>>(GETP(25), Bf1, 2048, 0);
    wsplit_old<<<dim3(8,8), blk,0,stream>>>(GETP(19), WTp, 512, 512);
    wsplit_old<<<dim3(32,8),blk,0,stream>>>(GETP(31), WTf2, 2048, 512);

    for (int hb = 0; hb < 2; hb++){
        const int pb = hb * PH;
        asplitT<<<dim3(64,16),blk,0,stream>>>(x, At, pb);
        // fused q/k/v (N=1536, NB=6, grid 384)
        gemm8<false><<<dim3(384),dim3(512),131072,stream>>>(At, Bqkv,
            GETP(2),GETP(8),GETP(14),  GETP(3),GETP(9),GETP(15),
            GETP(4),GETP(10),GETP(16), GETP(5),GETP(11),GETP(17),
            GETP(6),GETP(12),GETP(18), qkv, 6, 1536, 511);
        attn_lif_kernel<<<dim3(4,8,16),blk,0,stream>>>(qkv, os_);
        // p stage + fused o2/f1-image production
        gemm_p<<<dim3(4,128),blk,0,stream>>>(os_, WTp,
            GETP(20),GETP(21),GETP(22),GETP(23),GETP(24), x, o2, At, pb);
        // f1 (N=2048, NB=8, grid 512, bitpacked out)
        gemm8<true><<<dim3(512),dim3(512),131072,stream>>>(At, Bf1,
            GETP(26),GETP(26),GETP(26), GETP(27),GETP(27),GETP(27),
            GETP(28),GETP(28),GETP(28), GETP(29),GETP(29),GETP(29),
            GETP(30),GETP(30),GETP(30), hhb, 8, 2048, 2047);
        // f2 + fused final add -> d_out
        gemm_f2<<<dim3(4,128),blk,0,stream>>>(hhb, WTf2,
            GETP(32),GETP(33),GETP(34),GETP(35),GETP(36), x, o2, (float*)d_out, pb);
    }
}

// Round 9
// 569.443 us; speedup vs baseline: 5.2227x; 1.1222x over previous
//
#include <hip/hip_runtime.h>

typedef unsigned char u8;
typedef unsigned short u16;
typedef unsigned int u32;
typedef unsigned long long u64;
typedef long long i64;

#define TT 4
#define PH 4096             // pairs per half
#define KSW 16              // K/32 images for K=512
#define BNEPS 1e-5f

typedef __attribute__((ext_vector_type(8))) __bf16 bf16x8;
typedef __attribute__((ext_vector_type(4))) float f32x4;

__device__ __forceinline__ float bf2f(u16 b){ return __uint_as_float(((u32)b)<<16); }
__device__ __forceinline__ u16 f2bf_rne(float f){ u32 u = __float_as_uint(f); return (u16)((u + 0x7FFFu + ((u>>16)&1u))>>16); }
__device__ __forceinline__ u16 f2bf_tr(float f){ return (u16)(__float_as_uint(f)>>16); }

__device__ __forceinline__ void split2(float v, u16& h, u16& m){
    h = f2bf_tr(v); m = f2bf_tr(v - bf2f(h));
}

__device__ __forceinline__ f32x4 MFMA(bf16x8 a, bf16x8 b, f32x4 c){
    return __builtin_amdgcn_mfma_f32_16x16x32_bf16(a, b, c, 0, 0, 0);
}

union BF8 { u16 u[8]; bf16x8 v; };

__device__ __forceinline__ void gload16(const void* g, void* l){
    __builtin_amdgcn_global_load_lds(
        (const __attribute__((address_space(1))) unsigned int*)g,
        (__attribute__((address_space(3))) unsigned int*)l, 16, 0, 0);
}

// reg-staged kernels' swizzles (validated r3-r8)
__device__ __forceinline__ int swz(int row, int off){ return row*64 + (off ^ (((row>>1)&3)<<4)); }
__device__ __forceinline__ int swzK(int row, int off){ return row*128 + (off ^ ((row&7)<<4)); }
__device__ __forceinline__ int swzV(int row, int off){ return row*256 + (off ^ ((row&7)<<4)); }

__device__ __forceinline__ uint4 expand8(const u8* pb){
    u32 w0 = (pb[0]?0x3F80u:0u) | ((pb[1]?0x3F80u:0u)<<16);
    u32 w1 = (pb[2]?0x3F80u:0u) | ((pb[3]?0x3F80u:0u)<<16);
    u32 w2 = (pb[4]?0x3F80u:0u) | ((pb[5]?0x3F80u:0u)<<16);
    u32 w3 = (pb[6]?0x3F80u:0u) | ((pb[7]?0x3F80u:0u)<<16);
    return make_uint4(w0,w1,w2,w3);
}
__device__ __forceinline__ uint4 expandbits(u32 bits){
    u32 w0 = ((bits>>0)&1?0x3F80u:0u) | ((bits>>1)&1?0x3F800000u:0u);
    u32 w1 = ((bits>>2)&1?0x3F80u:0u) | ((bits>>3)&1?0x3F800000u:0u);
    u32 w2 = ((bits>>4)&1?0x3F80u:0u) | ((bits>>5)&1?0x3F800000u:0u);
    u32 w3 = ((bits>>6)&1?0x3F80u:0u) | ((bits>>7)&1?0x3F800000u:0u);
    return make_uint4(w0,w1,w2,w3);
}

// ---------------- W -> 256-col 1-plane RNE images: img(nb,ks)[g][col 0..255][16B], 16KB
__global__ __launch_bounds__(256)
void wsplit_rne(const float* __restrict__ W, u8* __restrict__ out, int NC, int nbOff)
{
    const int ks = blockIdx.x, nbl = blockIdx.y;
    const int c0 = nbl*256;
    u8* img = out + ((i64)(nbOff+nbl)*KSW + ks)*16384;
    #pragma unroll
    for (int it=0; it<4; it++){
        int task = threadIdx.x + it*256;     // (col 0..255, gq minor 0..3)
        int col = task>>2, gq = task&3;
        float v[8];
        #pragma unroll
        for (int j=0;j<8;j++) v[j] = W[(i64)(ks*32 + gq*8 + j)*NC + c0 + col];
        u16 h[8];
        #pragma unroll
        for (int j=0;j<8;j++) h[j] = f2bf_rne(v[j]);
        int off = gq*4096 + col*16;
        *(ushort4*)(img + off)     = make_ushort4(h[0],h[1],h[2],h[3]);
        *(ushort4*)(img + off + 8) = make_ushort4(h[4],h[5],h[6],h[7]);
    }
}

// ---------------- W -> RNE bf16 [NC][K] (for p/f2 reg-staged GEMMs)
__global__ __launch_bounds__(256)
void wsplit_old(const float* __restrict__ W, u16* __restrict__ out, int K, int NC)
{
    __shared__ float tile[64][65];
    const int k0 = blockIdx.x*64, c0 = blockIdx.y*64;
    const int tid = threadIdx.x;
    #pragma unroll
    for (int j=0;j<16;j++){
        int el = tid + j*256; int r = el>>6, c = el&63;
        tile[r][c] = W[(i64)(k0+r)*NC + c0 + c];
    }
    __syncthreads();
    #pragma unroll
    for (int j=0;j<16;j++){
        int el = tid + j*256; int c = el>>6, k = el&63;
        out[(i64)(c0+c)*K + k0 + k] = f2bf_rne(tile[k][c]);
    }
}

// ---------------- x -> A images: img(pb,ks)[pl][g][row 0..255][16B], row = pair*4 + t, 32KB
__global__ __launch_bounds__(256)
void asplitT(const float* __restrict__ x, u8* __restrict__ At, int pairBase)
{
    const int pb = blockIdx.x, ks = blockIdx.y;
    u8* img = At + ((i64)pb*KSW + ks)*32768;
    #pragma unroll
    for (int it=0; it<4; it++){
        int task = threadIdx.x + it*256;     // (row 0..255, gq minor)
        int row = task>>2, gq = task&3;
        int pair = row>>2, t = row&3;
        i64 grow = (i64)t*8192 + pairBase + pb*64 + pair;
        const float* src = x + grow*512 + ks*32 + gq*8;
        float4 f0 = *(const float4*)src, f1v = *(const float4*)(src+4);
        float vv[8] = {f0.x,f0.y,f0.z,f0.w,f1v.x,f1v.y,f1v.z,f1v.w};
        u16 h[8], m[8];
        #pragma unroll
        for (int j=0;j<8;j++) split2(vv[j], h[j], m[j]);
        int off = gq*4096 + row*16;
        *(ushort4*)(img + off)           = make_ushort4(h[0],h[1],h[2],h[3]);
        *(ushort4*)(img + off + 8)       = make_ushort4(h[4],h[5],h[6],h[7]);
        *(ushort4*)(img + 16384 + off)   = make_ushort4(m[0],m[1],m[2],m[3]);
        *(ushort4*)(img + 16384 + off+8) = make_ushort4(m[4],m[5],m[6],m[7]);
    }
}

// ---------------- 8-wave 256x256 GEMM + BN + LIF, 2-product (A_h+A_m)*RNE(W)
// tile: 256 rows x 256 cols, BK=32; A 2-plane 32KB + B 1-plane 16KB, dbuf 2x48KB.
// 8 waves 2Mx4N, wave = 128x64. Free-running phases, sync only at tile boundary.
template<bool BITOUT>
__global__ __launch_bounds__(512,2)
void gemm8(const u8* __restrict__ At, const u8* __restrict__ Bt,
           const float* __restrict__ b0, const float* __restrict__ b1, const float* __restrict__ b2,
           const float* __restrict__ g0, const float* __restrict__ g1, const float* __restrict__ g2,
           const float* __restrict__ e0, const float* __restrict__ e1, const float* __restrict__ e2,
           const float* __restrict__ u0, const float* __restrict__ u1, const float* __restrict__ u2,
           const float* __restrict__ v0, const float* __restrict__ v1, const float* __restrict__ v2,
           u8* __restrict__ outp, int NB, int NCT, int cmask)
{
    extern __shared__ __align__(16) char smem[];     // 98304: 2 x (A 32K + B 16K)
    const int tid = threadIdx.x;
    const int cpx = gridDim.x >> 3;
    const int serial = (blockIdx.x & 7)*cpx + (blockIdx.x >> 3);
    const int pb = serial / NB, nb = serial % NB;

    const int w = tid>>6, lane = tid&63, g = lane>>4, ln = lane&15;
    const int wm = w>>2, wn = w&3;                   // 2M x 4N

    f32x4 acc[8][4];
    #pragma unroll
    for (int m=0;m<8;m++)
        #pragma unroll
        for (int cf=0;cf<4;cf++) acc[m][cf] = (f32x4)0.f;

    const u8* Ab = At + (i64)pb*KSW*32768;
    const u8* Bb = Bt + (i64)nb*KSW*16384;

    // prologue: stage tile 0 (A 32KB, B 16KB)
    #pragma unroll
    for (int j=0;j<4;j++)
        gload16(Ab + j*8192 + tid*16, smem + j*8192 + tid*16);
    #pragma unroll
    for (int j=0;j<2;j++)
        gload16(Bb + j*8192 + tid*16, smem + 32768 + j*8192 + tid*16);
    __syncthreads();

    for (int ks=0; ks<KSW; ks++){
        char* cur = smem + (ks&1)*49152;
        char* nxt = smem + ((ks+1)&1)*49152;
        const bool pre = (ks+1 < KSW);
        const u8* Ai = Ab + (i64)(ks+1)*32768;
        const u8* Bi = Bb + (i64)(ks+1)*16384;

        // issue A-prefetch first (max in-flight cover)
        if (pre){
            #pragma unroll
            for (int j=0;j<4;j++) gload16(Ai + j*8192 + tid*16, nxt + j*8192 + tid*16);
        }
        // hoist all B fragments for this tile (read ONCE, single plane)
        bf16x8 bfr[2][2];     // [b-half][cb]
        #pragma unroll
        for (int b=0;b<2;b++)
            #pragma unroll
            for (int cb=0;cb<2;cb++){
                int col = wn*64 + b*32 + cb*16 + ln;
                bfr[b][cb] = *(const bf16x8*)(cur + 32768 + g*4096 + col*16);
            }

        // ---- phase 0 (m-half a=0)
        {
            bf16x8 af[4][2];
            #pragma unroll
            for (int fm=0; fm<4; fm++){
                int row = wm*128 + 0*64 + fm*16 + ln;
                af[fm][0] = *(const bf16x8*)(cur + g*4096 + row*16);
                af[fm][1] = *(const bf16x8*)(cur + 16384 + g*4096 + row*16);
            }
            __builtin_amdgcn_s_setprio(1);
            #pragma unroll
            for (int fm=0; fm<4; fm++)
                #pragma unroll
                for (int b=0;b<2;b++)
                    #pragma unroll
                    for (int cb=0;cb<2;cb++){
                        const int m = 0*4+fm, cfi = b*2+cb;
                        f32x4 x4 = acc[m][cfi];
                        x4 = MFMA(af[fm][0], bfr[b][cb], x4);
                        x4 = MFMA(af[fm][1], bfr[b][cb], x4);
                        acc[m][cfi] = x4;
                    }
            __builtin_amdgcn_s_setprio(0);
        }
        __builtin_amdgcn_sched_barrier(0);   // keep phase-1 reads below phase-0 MFMAs
        // issue B-prefetch
        if (pre){
            #pragma unroll
            for (int j=0;j<2;j++) gload16(Bi + j*8192 + tid*16, nxt + 32768 + j*8192 + tid*16);
        }
        // ---- phase 1 (m-half a=1)
        {
            bf16x8 af[4][2];
            #pragma unroll
            for (int fm=0; fm<4; fm++){
                int row = wm*128 + 1*64 + fm*16 + ln;
                af[fm][0] = *(const bf16x8*)(cur + g*4096 + row*16);
                af[fm][1] = *(const bf16x8*)(cur + 16384 + g*4096 + row*16);
            }
            __builtin_amdgcn_s_setprio(1);
            #pragma unroll
            for (int fm=0; fm<4; fm++)
                #pragma unroll
                for (int b=0;b<2;b++)
                    #pragma unroll
                    for (int cb=0;cb<2;cb++){
                        const int m = 1*4+fm, cfi = b*2+cb;
                        f32x4 x4 = acc[m][cfi];
                        x4 = MFMA(af[fm][0], bfr[b][cb], x4);
                        x4 = MFMA(af[fm][1], bfr[b][cb], x4);
                        acc[m][cfi] = x4;
                    }
            __builtin_amdgcn_s_setprio(0);
        }
        __syncthreads();   // tile boundary: all reads of cur done, all DMAs to nxt landed
    }

    // epilogue: BN + LIF (acc[m][cf] components = the 4 t-steps of one (pair,col))
    #pragma unroll
    for (int cf=0; cf<4; cf++){
        const int c = nb*256 + wn*64 + cf*16 + ln;
        int which = c >> 9; if (which > 2) which = 2;
        const float* bp = which==0?b0:(which==1?b1:b2);
        const float* gp = which==0?g0:(which==1?g1:g2);
        const float* ep = which==0?e0:(which==1?e1:e2);
        const float* up = which==0?u0:(which==1?u1:u2);
        const float* vp = which==0?v0:(which==1?v1:v2);
        const int ci = c & cmask;
        const float gs  = gp[ci] / sqrtf(vp[ci] + BNEPS);
        const float bf_ = bp[ci], muf = up[ci], bef = ep[ci];
        #pragma unroll
        for (int m=0; m<8; m++){
            const int rowBase = wm*128 + m*16 + g*4;
            const int prow = pb*64 + (rowBase>>2);
            float v = 0.f;
            #pragma unroll
            for (int t=0; t<TT; t++){
                float y = acc[m][cf][t] + bf_;
                float z = (y - muf) * gs + bef;
                v = v + (z - v) * 0.5f;
                float s = ((v - 1.0f) >= 0.f) ? 1.f : 0.f;
                if (BITOUT){
                    u64 bal = __ballot(s != 0.f);
                    if (ln == 0)
                        *(u16*)(outp + (i64)(t*PH + prow)*(NCT>>3) + ((nb*256 + wn*64 + cf*16)>>3)) = (u16)(bal >> (g*16));
                } else {
                    outp[((i64)t*PH + prow)*NCT + c] = (u8)s;
                }
                v = v * (1.f - s);
            }
        }
    }
}

// ---------------- p stage: spikes x W GEMM + BN + LIF -> o2 (global) + f1 A-images (x+o2 split)
__global__ __launch_bounds__(256)
void gemm_p(const u8* __restrict__ Au8, const u16* __restrict__ WT,
            const float* __restrict__ bias, const float* __restrict__ gw,
            const float* __restrict__ bew,  const float* __restrict__ muw,
            const float* __restrict__ varw,
            const float* __restrict__ x, u8* __restrict__ o2g,
            u8* __restrict__ At, int pairBase)
{
    __shared__ __align__(16) char smem[16384];
    char* smA = smem;
    char* smB = smem + 8192;
    const int tid = threadIdx.x;
    const int nbp = blockIdx.x, pbp = blockIdx.y;
    const int c0 = nbp*128, pair0 = pbp*32;
    const int w = tid>>6, l = tid&63, g = l>>4, ln = l&15;
    const int wm = w>>1, wn = w&1;

    f32x4 acc[TT][4];
    #pragma unroll
    for (int t=0;t<TT;t++)
        #pragma unroll
        for (int cf=0;cf<4;cf++) acc[t][cf] = (f32x4)0.f;

    for (int k0 = 0; k0 < 512; k0 += 32){
        __syncthreads();
        {
            const int row = tid>>1, half = tid&1;
            const int t = row>>5, pp = row&31;
            const i64 grow = (i64)t*PH + pair0 + pp;
            uint4 ob = *(const uint4*)(Au8 + grow*512 + k0 + half*16);
            const u8* pbb = (const u8*)&ob;
            *(uint4*)(smA + swz(row, half*32))    = expand8(pbb);
            *(uint4*)(smA + swz(row, half*32+16)) = expand8(pbb+8);
        }
        #pragma unroll
        for (int j=0;j<2;j++){
            int cid = tid + j*256;
            int col = cid>>2, c = cid&3;
            uint4 d = *(const uint4*)(WT + (i64)(c0+col)*512 + k0 + c*8);
            *(uint4*)(smB + swz(col, c*16)) = d;
        }
        __syncthreads();
        bf16x8 bfr[4];
        #pragma unroll
        for (int cf=0;cf<4;cf++)
            bfr[cf] = *(const bf16x8*)(smB + swz(wn*64 + cf*16 + ln, g*16));
        #pragma unroll
        for (int t=0;t<TT;t++){
            bf16x8 afr = *(const bf16x8*)(smA + swz(t*32 + wm*16 + ln, g*16));
            #pragma unroll
            for (int cf=0;cf<4;cf++)
                acc[t][cf] = MFMA(afr, bfr[cf], acc[t][cf]);
        }
    }

    // epilogue: LIF -> spikes into LDS tile [t][rl 0..31][cL 0..127] u8 (16 KB)
    __syncthreads();
    u8* tile = (u8*)smem;
    #pragma unroll
    for (int cf=0;cf<4;cf++){
        const int c = c0 + wn*64 + cf*16 + ln;
        const float gs  = gw[c] / sqrtf(varw[c] + BNEPS);
        const float bf_ = bias[c], muf = muw[c], bef = bew[c];
        #pragma unroll
        for (int r=0;r<4;r++){
            const int rl = wm*16 + g*4 + r;
            float v = 0.f;
            #pragma unroll
            for (int t=0;t<TT;t++){
                float y = acc[t][cf][r] + bf_;
                float z = (y - muf) * gs + bef;
                v = v + (z - v) * 0.5f;
                float s = ((v - 1.0f) >= 0.f) ? 1.f : 0.f;
                tile[t*4096 + rl*128 + (wn*64 + cf*16 + ln)] = (u8)s;
                v = v * (1.f - s);
            }
        }
    }
    __syncthreads();

    // write o2 (global, local rows) + f1 A-images (x + o2, split2)
    const int pbImg = pbp>>1, rOff = (pbp&1)*128;
    #pragma unroll
    for (int it=0; it<8; it++){
        int task = tid + it*256;             // (kq 0..3, gq 0..3, rowL 0..127)
        int kq = task>>9, rem = task&511, gq = rem>>7, rowL = rem&127;
        int rl = rowL>>2, t = rowL&3;
        int ksAbs = nbp*4 + kq;
        int cL = kq*32 + gq*8;
        uint2 ob = *(const uint2*)(tile + t*4096 + rl*128 + cL);
        const u8* pbb = (const u8*)&ob;
        i64 grow = (i64)t*8192 + pairBase + pair0 + rl;
        const float* src = x + grow*512 + ksAbs*32 + gq*8;
        float4 f0 = *(const float4*)src, f1v = *(const float4*)(src+4);
        float vv[8] = {f0.x,f0.y,f0.z,f0.w,f1v.x,f1v.y,f1v.z,f1v.w};
        #pragma unroll
        for (int j=0;j<8;j++) vv[j] = vv[j] + (float)pbb[j];
        u16 h[8], m[8];
        #pragma unroll
        for (int j=0;j<8;j++) split2(vv[j], h[j], m[j]);
        u8* img = At + ((i64)pbImg*KSW + ksAbs)*32768;
        int off = gq*4096 + (rOff + rowL)*16;
        *(ushort4*)(img + off)           = make_ushort4(h[0],h[1],h[2],h[3]);
        *(ushort4*)(img + off + 8)       = make_ushort4(h[4],h[5],h[6],h[7]);
        *(ushort4*)(img + 16384 + off)   = make_ushort4(m[0],m[1],m[2],m[3]);
        *(ushort4*)(img + 16384 + off+8) = make_ushort4(m[4],m[5],m[6],m[7]);
        *(uint2*)(o2g + ((i64)t*PH + pair0 + rl)*512 + ksAbs*32 + gq*8) = ob;
    }
}

// ---------------- f2 stage: bitpacked spikes x W GEMM + BN + LIF + final add -> d_out f32
__global__ __launch_bounds__(256)
void gemm_f2(const u8* __restrict__ Abits, const u16* __restrict__ WT,
             const float* __restrict__ bias, const float* __restrict__ gw,
             const float* __restrict__ bew,  const float* __restrict__ muw,
             const float* __restrict__ varw,
             const float* __restrict__ x, const u8* __restrict__ o2g,
             float* __restrict__ outF, int pairBase)
{
    __shared__ __align__(16) char smem[16384];
    char* smA = smem;
    char* smB = smem + 8192;
    const int tid = threadIdx.x;
    const int c0 = blockIdx.x*128, pair0 = blockIdx.y*32;
    const int w = tid>>6, l = tid&63, g = l>>4, ln = l&15;
    const int wm = w>>1, wn = w&1;

    f32x4 acc[TT][4];
    #pragma unroll
    for (int t=0;t<TT;t++)
        #pragma unroll
        for (int cf=0;cf<4;cf++) acc[t][cf] = (f32x4)0.f;

    for (int k0 = 0; k0 < 2048; k0 += 32){
        __syncthreads();
        {
            const int row = tid>>1, half = tid&1;
            const int t = row>>5, pp = row&31;
            const i64 grow = (i64)t*PH + pair0 + pp;
            u32 bits = *(const u16*)(Abits + grow*256 + (k0>>3) + half*2);
            *(uint4*)(smA + swz(row, half*32))    = expandbits(bits);
            *(uint4*)(smA + swz(row, half*32+16)) = expandbits(bits>>8);
        }
        #pragma unroll
        for (int j=0;j<2;j++){
            int cid = tid + j*256;
            int col = cid>>2, c = cid&3;
            uint4 d = *(const uint4*)(WT + (i64)(c0+col)*2048 + k0 + c*8);
            *(uint4*)(smB + swz(col, c*16)) = d;
        }
        __syncthreads();
        bf16x8 bfr[4];
        #pragma unroll
        for (int cf=0;cf<4;cf++)
            bfr[cf] = *(const bf16x8*)(smB + swz(wn*64 + cf*16 + ln, g*16));
        #pragma unroll
        for (int t=0;t<TT;t++){
            bf16x8 afr = *(const bf16x8*)(smA + swz(t*32 + wm*16 + ln, g*16));
            #pragma unroll
            for (int cf=0;cf<4;cf++)
                acc[t][cf] = MFMA(afr, bfr[cf], acc[t][cf]);
        }
    }

    #pragma unroll
    for (int cf=0;cf<4;cf++){
        const int c = c0 + wn*64 + cf*16 + ln;
        const float gs  = gw[c] / sqrtf(varw[c] + BNEPS);
        const float bf_ = bias[c], muf = muw[c], bef = bew[c];
        #pragma unroll
        for (int r=0;r<4;r++){
            const int prow = pair0 + wm*16 + g*4 + r;
            float v = 0.f;
            #pragma unroll
            for (int t=0;t<TT;t++){
                float y = acc[t][cf][r] + bf_;
                float z = (y - muf) * gs + bef;
                v = v + (z - v) * 0.5f;
                float s = ((v - 1.0f) >= 0.f) ? 1.f : 0.f;
                i64 lrow = (i64)t*PH + prow;
                i64 grow = (i64)t*8192 + pairBase + prow;
                float xv = x[grow*512 + c];
                float o2v = (float)o2g[lrow*512 + c];
                float x1 = xv + o2v;
                outF[grow*512 + c] = x1 + s;
                v = v * (1.f - s);
            }
        }
    }
}

// ---------------- spiking attention + attn-LIF (v_th=0.5), qkv packed stride 1536
__global__ __launch_bounds__(256)
void attn_lif_kernel(const u8* __restrict__ qkv, u8* __restrict__ os)
{
    __shared__ __align__(16) char smem[49152];
    char* Kl = smem;
    char* VT = smem + 16384;
    char* AT = smem + 32768;

    const int tid = threadIdx.x;
    const int w = tid>>6, l = tid&63, g = l>>4, ln = l&15;
    const int h = blockIdx.y, b = blockIdx.z;
    const int n0 = blockIdx.x*64 + w*16;

    f32x4 vmem[4];
    #pragma unroll
    for (int cf=0;cf<4;cf++) vmem[cf] = (f32x4)0.f;

    for (int t=0;t<TT;t++){
        const i64 tb = ((i64)(t*16 + b)*256)*1536;
        const i64 ob = ((i64)(t*16 + b)*256)*512 + h*64;
        bf16x8 qf[2];
        #pragma unroll
        for (int ksl=0;ksl<2;ksl++){
            uint2 qv = *(const uint2*)(qkv + tb + (i64)(n0+ln)*1536 + h*64 + ksl*32 + g*8);
            const u8* pb = (const u8*)&qv;
            BF8 f;
            #pragma unroll
            for (int j=0;j<8;j++) f.u[j] = pb[j] ? 0x3F80 : 0;
            qf[ksl] = f.v;
        }
        f32x4 oacc[4];
        #pragma unroll
        for (int cf=0;cf<4;cf++) oacc[cf] = (f32x4)0.f;

        for (int mh=0; mh<2; mh++){
            __syncthreads();
            {
                const int lm = tid>>1, seg = tid&1;
                const u8* src = qkv + tb + (i64)(mh*128+lm)*1536 + 512 + h*64 + seg*32;
                uint4 a = *(const uint4*)(src), c = *(const uint4*)(src+16);
                const u8* pa = (const u8*)&a; const u8* pc = (const u8*)&c;
                #pragma unroll
                for (int q=0;q<4;q++){
                    *(ushort4*)(Kl + swzK(lm, seg*64 + q*8)) =
                        make_ushort4(pa[q*4]?0x3F80:0, pa[q*4+1]?0x3F80:0, pa[q*4+2]?0x3F80:0, pa[q*4+3]?0x3F80:0);
                    *(ushort4*)(Kl + swzK(lm, seg*64 + 32 + q*8)) =
                        make_ushort4(pc[q*4]?0x3F80:0, pc[q*4+1]?0x3F80:0, pc[q*4+2]?0x3F80:0, pc[q*4+3]?0x3F80:0);
                }
            }
            {
                const int lm = tid>>1, seg = tid&1;
                const u8* src = qkv + tb + (i64)(mh*128+lm)*1536 + 1024 + h*64 + seg*32;
                uint4 a = *(const uint4*)(src), c = *(const uint4*)(src+16);
                const u8* pa = (const u8*)&a; const u8* pc = (const u8*)&c;
                #pragma unroll
                for (int j=0;j<16;j++){
                    *(u16*)(VT + swzV(seg*32 + j,      lm*2)) = pa[j] ? 0x3F80 : 0;
                    *(u16*)(VT + swzV(seg*32 + 16 + j, lm*2)) = pc[j] ? 0x3F80 : 0;
                }
            }
            __syncthreads();
            #pragma unroll
            for (int rf=0;rf<8;rf++){
                f32x4 s = (f32x4)0.f;
                #pragma unroll
                for (int ksl=0;ksl<2;ksl++){
                    bf16x8 kf = *(const bf16x8*)(Kl + swzK(rf*16+ln, ksl*64 + g*16));
                    s = MFMA(kf, qf[ksl], s);
                }
                ushort4 pk = make_ushort4(f2bf_rne(s[0]*0.125f), f2bf_rne(s[1]*0.125f),
                                          f2bf_rne(s[2]*0.125f), f2bf_rne(s[3]*0.125f));
                *(ushort4*)(AT + swzV(w*16+ln, rf*32 + g*8)) = pk;
            }
            #pragma unroll
            for (int ms=0;ms<4;ms++){
                bf16x8 af = *(const bf16x8*)(AT + swzV(w*16+ln, ms*64 + g*16));
                #pragma unroll
                for (int cf=0;cf<4;cf++){
                    bf16x8 vf = *(const bf16x8*)(VT + swzV(cf*16+ln, ms*64 + g*16));
                    oacc[cf] = MFMA(af, vf, oacc[cf]);
                }
            }
        }
        #pragma unroll
        for (int cf=0;cf<4;cf++)
            #pragma unroll
            for (int r=0;r<4;r++){
                float v = vmem[cf][r];
                v = v + (oacc[cf][r] - v) * 0.5f;
                float s = ((v - 0.5f) >= 0.f) ? 1.f : 0.f;
                os[ob + (i64)(n0 + g*4 + r)*512 + cf*16 + ln] = (u8)s;
                vmem[cf][r] = v * (1.f - s);
            }
    }
}

extern "C" void kernel_launch(void* const* d_in, const int* in_sizes, int n_in,
                              void* d_out, int out_size, void* d_ws, size_t ws_size,
                              hipStream_t stream)
{
    (void)in_sizes; (void)n_in; (void)out_size; (void)ws_size;
    const float* x = (const float*)d_in[0];
    #define GETP(i) ((const float*)d_in[i])

    char* ws = (char*)d_ws;
    u8*  Bqkv = (u8*)(ws + 0);               //  6*16*16384 = 1,572,864
    u8*  Bf1  = (u8*)(ws + 1572864);         //  8*16*16384 = 2,097,152
    u16* WTp  = (u16*)(ws + 3670016);        //  524,288
    u16* WTf2 = (u16*)(ws + 4194304);        //  2,097,152
    u8*  At   = (u8*)(ws + 6291456);         // 64*16*32768 = 33,554,432
    u8*  qkv  = (u8*)(ws + 39845888);        // 25,165,824
    u8*  os_  = (u8*)(ws + 65011712);        //  8,388,608
    u8*  o2   = (u8*)(ws + 73400320);        //  8,388,608
    u8*  hhb  = (u8*)(ws + 81788928);        //  4,194,304  (ends 85,983,232)

    hipFuncSetAttribute((const void*)gemm8<false>, hipFuncAttributeMaxDynamicSharedMemorySize, 98304);
    hipFuncSetAttribute((const void*)gemm8<true>,  hipFuncAttributeMaxDynamicSharedMemorySize, 98304);

    dim3 blk(256,1,1);
    // W prep
    wsplit_rne<<<dim3(16,2), blk,0,stream>>>(GETP(1),  Bqkv, 512, 0);
    wsplit_rne<<<dim3(16,2), blk,0,stream>>>(GETP(7),  Bqkv, 512, 2);
    wsplit_rne<<<dim3(16,2), blk,0,stream>>>(GETP(13), Bqkv, 512, 4);
    wsplit_rne<<<dim3(16,8), blk,0,stream>>>(GETP(25), Bf1, 2048, 0);
    wsplit_old<<<dim3(8,8), blk,0,stream>>>(GETP(19), WTp, 512, 512);
    wsplit_old<<<dim3(32,8),blk,0,stream>>>(GETP(31), WTf2, 2048, 512);

    for (int hb = 0; hb < 2; hb++){
        const int pb = hb * PH;
        asplitT<<<dim3(64,16),blk,0,stream>>>(x, At, pb);
        // fused q/k/v (N=1536, NB=6, grid 384)
        gemm8<false><<<dim3(384),dim3(512),98304,stream>>>(At, Bqkv,
            GETP(2),GETP(8),GETP(14),  GETP(3),GETP(9),GETP(15),
            GETP(4),GETP(10),GETP(16), GETP(5),GETP(11),GETP(17),
            GETP(6),GETP(12),GETP(18), qkv, 6, 1536, 511);
        attn_lif_kernel<<<dim3(4,8,16),blk,0,stream>>>(qkv, os_);
        // p stage + fused o2/f1-image production
        gemm_p<<<dim3(4,128),blk,0,stream>>>(os_, WTp,
            GETP(20),GETP(21),GETP(22),GETP(23),GETP(24), x, o2, At, pb);
        // f1 (N=2048, NB=8, grid 512, bitpacked out)
        gemm8<true><<<dim3(512),dim3(512),98304,stream>>>(At, Bf1,
            GETP(26),GETP(26),GETP(26), GETP(27),GETP(27),GETP(27),
            GETP(28),GETP(28),GETP(28), GETP(29),GETP(29),GETP(29),
            GETP(30),GETP(30),GETP(30), hhb, 8, 2048, 2047);
        // f2 + fused final add -> d_out
        gemm_f2<<<dim3(4,128),blk,0,stream>>>(hhb, WTf2,
            GETP(32),GETP(33),GETP(34),GETP(35),GETP(36), x, o2, (float*)d_out, pb);
    }
}

// Round 10
// 554.342 us; speedup vs baseline: 5.3650x; 1.0272x over previous
//
#include <hip/hip_runtime.h>

typedef unsigned char u8;
typedef unsigned short u16;
typedef unsigned int u32;
typedef unsigned long long u64;
typedef long long i64;

#define TT 4
#define PH 4096             // pairs per half
#define KSW 16              // K/32 images for K=512
#define BNEPS 1e-5f

typedef __attribute__((ext_vector_type(8))) __bf16 bf16x8;
typedef __attribute__((ext_vector_type(4))) float f32x4;

__device__ __forceinline__ float bf2f(u16 b){ return __uint_as_float(((u32)b)<<16); }
__device__ __forceinline__ u16 f2bf_rne(float f){ u32 u = __float_as_uint(f); return (u16)((u + 0x7FFFu + ((u>>16)&1u))>>16); }
__device__ __forceinline__ u16 f2bf_tr(float f){ return (u16)(__float_as_uint(f)>>16); }

__device__ __forceinline__ void split2(float v, u16& h, u16& m){
    h = f2bf_tr(v); m = f2bf_tr(v - bf2f(h));
}

__device__ __forceinline__ f32x4 MFMA(bf16x8 a, bf16x8 b, f32x4 c){
    return __builtin_amdgcn_mfma_f32_16x16x32_bf16(a, b, c, 0, 0, 0);
}

union BF8 { u16 u[8]; bf16x8 v; };

__device__ __forceinline__ void gload16(const void* g, void* l){
    __builtin_amdgcn_global_load_lds(
        (const __attribute__((address_space(1))) unsigned int*)g,
        (__attribute__((address_space(3))) unsigned int*)l, 16, 0, 0);
}

// reg-staged kernels' swizzles (validated r3-r9)
__device__ __forceinline__ int swz(int row, int off){ return row*64 + (off ^ (((row>>1)&3)<<4)); }
__device__ __forceinline__ int swzK(int row, int off){ return row*128 + (off ^ ((row&7)<<4)); }
__device__ __forceinline__ int swzV(int row, int off){ return row*256 + (off ^ ((row&7)<<4)); }

__device__ __forceinline__ uint4 expand8(const u8* pb){
    u32 w0 = (pb[0]?0x3F80u:0u) | ((pb[1]?0x3F80u:0u)<<16);
    u32 w1 = (pb[2]?0x3F80u:0u) | ((pb[3]?0x3F80u:0u)<<16);
    u32 w2 = (pb[4]?0x3F80u:0u) | ((pb[5]?0x3F80u:0u)<<16);
    u32 w3 = (pb[6]?0x3F80u:0u) | ((pb[7]?0x3F80u:0u)<<16);
    return make_uint4(w0,w1,w2,w3);
}
__device__ __forceinline__ uint4 expandbits(u32 bits){
    u32 w0 = ((bits>>0)&1?0x3F80u:0u) | ((bits>>1)&1?0x3F800000u:0u);
    u32 w1 = ((bits>>2)&1?0x3F80u:0u) | ((bits>>3)&1?0x3F800000u:0u);
    u32 w2 = ((bits>>4)&1?0x3F80u:0u) | ((bits>>5)&1?0x3F800000u:0u);
    u32 w3 = ((bits>>6)&1?0x3F80u:0u) | ((bits>>7)&1?0x3F800000u:0u);
    return make_uint4(w0,w1,w2,w3);
}

// ---------------- W -> 256-col 1-plane RNE images: img(nb,ks)[g][col 0..255][16B], 16KB
__global__ __launch_bounds__(256)
void wsplit_rne(const float* __restrict__ W, u8* __restrict__ out, int NC, int nbOff, int ksn)
{
    const int ks = blockIdx.x, nbl = blockIdx.y;
    const int c0 = nbl*256;
    u8* img = out + ((i64)(nbOff+nbl)*ksn + ks)*16384;
    #pragma unroll
    for (int it=0; it<4; it++){
        int task = threadIdx.x + it*256;     // (col 0..255, gq minor 0..3)
        int col = task>>2, gq = task&3;
        float v[8];
        #pragma unroll
        for (int j=0;j<8;j++) v[j] = W[(i64)(ks*32 + gq*8 + j)*NC + c0 + col];
        u16 h[8];
        #pragma unroll
        for (int j=0;j<8;j++) h[j] = f2bf_rne(v[j]);
        int off = gq*4096 + col*16;
        *(ushort4*)(img + off)     = make_ushort4(h[0],h[1],h[2],h[3]);
        *(ushort4*)(img + off + 8) = make_ushort4(h[4],h[5],h[6],h[7]);
    }
}

// ---------------- W -> RNE bf16 [NC][K] (for p reg-staged GEMM)
__global__ __launch_bounds__(256)
void wsplit_old(const float* __restrict__ W, u16* __restrict__ out, int K, int NC)
{
    __shared__ float tile[64][65];
    const int k0 = blockIdx.x*64, c0 = blockIdx.y*64;
    const int tid = threadIdx.x;
    #pragma unroll
    for (int j=0;j<16;j++){
        int el = tid + j*256; int r = el>>6, c = el&63;
        tile[r][c] = W[(i64)(k0+r)*NC + c0 + c];
    }
    __syncthreads();
    #pragma unroll
    for (int j=0;j<16;j++){
        int el = tid + j*256; int c = el>>6, k = el&63;
        out[(i64)(c0+c)*K + k0 + k] = f2bf_rne(tile[k][c]);
    }
}

// ---------------- x -> A images: img(pb,ks)[pl][g][row 0..255][16B], row = pair*4 + t, 32KB
__global__ __launch_bounds__(256)
void asplitT(const float* __restrict__ x, u8* __restrict__ At, int pairBase)
{
    const int pb = blockIdx.x, ks = blockIdx.y;
    u8* img = At + ((i64)pb*KSW + ks)*32768;
    #pragma unroll
    for (int it=0; it<4; it++){
        int task = threadIdx.x + it*256;     // (row 0..255, gq minor)
        int row = task>>2, gq = task&3;
        int pair = row>>2, t = row&3;
        i64 grow = (i64)t*8192 + pairBase + pb*64 + pair;
        const float* src = x + grow*512 + ks*32 + gq*8;
        float4 f0 = *(const float4*)src, f1v = *(const float4*)(src+4);
        float vv[8] = {f0.x,f0.y,f0.z,f0.w,f1v.x,f1v.y,f1v.z,f1v.w};
        u16 h[8], m[8];
        #pragma unroll
        for (int j=0;j<8;j++) split2(vv[j], h[j], m[j]);
        int off = gq*4096 + row*16;
        *(ushort4*)(img + off)           = make_ushort4(h[0],h[1],h[2],h[3]);
        *(ushort4*)(img + off + 8)       = make_ushort4(h[4],h[5],h[6],h[7]);
        *(ushort4*)(img + 16384 + off)   = make_ushort4(m[0],m[1],m[2],m[3]);
        *(ushort4*)(img + 16384 + off+8) = make_ushort4(m[4],m[5],m[6],m[7]);
    }
}

// ---------------- 8-wave 256x256 GEMM + BN + LIF, 2-product (A_h+A_m)*RNE(W)
template<bool BITOUT>
__global__ __launch_bounds__(512,2)
void gemm8(const u8* __restrict__ At, const u8* __restrict__ Bt,
           const float* __restrict__ b0, const float* __restrict__ b1, const float* __restrict__ b2,
           const float* __restrict__ g0, const float* __restrict__ g1, const float* __restrict__ g2,
           const float* __restrict__ e0, const float* __restrict__ e1, const float* __restrict__ e2,
           const float* __restrict__ u0, const float* __restrict__ u1, const float* __restrict__ u2,
           const float* __restrict__ v0, const float* __restrict__ v1, const float* __restrict__ v2,
           u8* __restrict__ outp, int NB, int NCT, int cmask)
{
    extern __shared__ __align__(16) char smem[];     // 98304: 2 x (A 32K + B 16K)
    const int tid = threadIdx.x;
    const int cpx = gridDim.x >> 3;
    const int serial = (blockIdx.x & 7)*cpx + (blockIdx.x >> 3);
    const int pb = serial / NB, nb = serial % NB;

    const int w = tid>>6, lane = tid&63, g = lane>>4, ln = lane&15;
    const int wm = w>>2, wn = w&3;                   // 2M x 4N

    f32x4 acc[8][4];
    #pragma unroll
    for (int m=0;m<8;m++)
        #pragma unroll
        for (int cf=0;cf<4;cf++) acc[m][cf] = (f32x4)0.f;

    const u8* Ab = At + (i64)pb*KSW*32768;
    const u8* Bb = Bt + (i64)nb*KSW*16384;

    #pragma unroll
    for (int j=0;j<4;j++)
        gload16(Ab + j*8192 + tid*16, smem + j*8192 + tid*16);
    #pragma unroll
    for (int j=0;j<2;j++)
        gload16(Bb + j*8192 + tid*16, smem + 32768 + j*8192 + tid*16);
    __syncthreads();

    for (int ks=0; ks<KSW; ks++){
        char* cur = smem + (ks&1)*49152;
        char* nxt = smem + ((ks+1)&1)*49152;
        const bool pre = (ks+1 < KSW);
        const u8* Ai = Ab + (i64)(ks+1)*32768;
        const u8* Bi = Bb + (i64)(ks+1)*16384;

        if (pre){
            #pragma unroll
            for (int j=0;j<4;j++) gload16(Ai + j*8192 + tid*16, nxt + j*8192 + tid*16);
        }
        bf16x8 bfr[2][2];     // [b-half][cb]
        #pragma unroll
        for (int b=0;b<2;b++)
            #pragma unroll
            for (int cb=0;cb<2;cb++){
                int col = wn*64 + b*32 + cb*16 + ln;
                bfr[b][cb] = *(const bf16x8*)(cur + 32768 + g*4096 + col*16);
            }

        // ---- phase 0 (m-half a=0)
        {
            bf16x8 af[4][2];
            #pragma unroll
            for (int fm=0; fm<4; fm++){
                int row = wm*128 + 0*64 + fm*16 + ln;
                af[fm][0] = *(const bf16x8*)(cur + g*4096 + row*16);
                af[fm][1] = *(const bf16x8*)(cur + 16384 + g*4096 + row*16);
            }
            __builtin_amdgcn_s_setprio(1);
            #pragma unroll
            for (int fm=0; fm<4; fm++)
                #pragma unroll
                for (int b=0;b<2;b++)
                    #pragma unroll
                    for (int cb=0;cb<2;cb++){
                        const int m = 0*4+fm, cfi = b*2+cb;
                        f32x4 x4 = acc[m][cfi];
                        x4 = MFMA(af[fm][0], bfr[b][cb], x4);
                        x4 = MFMA(af[fm][1], bfr[b][cb], x4);
                        acc[m][cfi] = x4;
                    }
            __builtin_amdgcn_s_setprio(0);
        }
        __builtin_amdgcn_sched_barrier(0);
        if (pre){
            #pragma unroll
            for (int j=0;j<2;j++) gload16(Bi + j*8192 + tid*16, nxt + 32768 + j*8192 + tid*16);
        }
        // ---- phase 1 (m-half a=1)
        {
            bf16x8 af[4][2];
            #pragma unroll
            for (int fm=0; fm<4; fm++){
                int row = wm*128 + 1*64 + fm*16 + ln;
                af[fm][0] = *(const bf16x8*)(cur + g*4096 + row*16);
                af[fm][1] = *(const bf16x8*)(cur + 16384 + g*4096 + row*16);
            }
            __builtin_amdgcn_s_setprio(1);
            #pragma unroll
            for (int fm=0; fm<4; fm++)
                #pragma unroll
                for (int b=0;b<2;b++)
                    #pragma unroll
                    for (int cb=0;cb<2;cb++){
                        const int m = 1*4+fm, cfi = b*2+cb;
                        f32x4 x4 = acc[m][cfi];
                        x4 = MFMA(af[fm][0], bfr[b][cb], x4);
                        x4 = MFMA(af[fm][1], bfr[b][cb], x4);
                        acc[m][cfi] = x4;
                    }
            __builtin_amdgcn_s_setprio(0);
        }
        __syncthreads();
    }

    #pragma unroll
    for (int cf=0; cf<4; cf++){
        const int c = nb*256 + wn*64 + cf*16 + ln;
        int which = c >> 9; if (which > 2) which = 2;
        const float* bp = which==0?b0:(which==1?b1:b2);
        const float* gp = which==0?g0:(which==1?g1:g2);
        const float* ep = which==0?e0:(which==1?e1:e2);
        const float* up = which==0?u0:(which==1?u1:u2);
        const float* vp = which==0?v0:(which==1?v1:v2);
        const int ci = c & cmask;
        const float gs  = gp[ci] / sqrtf(vp[ci] + BNEPS);
        const float bf_ = bp[ci], muf = up[ci], bef = ep[ci];
        #pragma unroll
        for (int m=0; m<8; m++){
            const int rowBase = wm*128 + m*16 + g*4;
            const int prow = pb*64 + (rowBase>>2);
            float v = 0.f;
            #pragma unroll
            for (int t=0; t<TT; t++){
                float y = acc[m][cf][t] + bf_;
                float z = (y - muf) * gs + bef;
                v = v + (z - v) * 0.5f;
                float s = ((v - 1.0f) >= 0.f) ? 1.f : 0.f;
                if (BITOUT){
                    u64 bal = __ballot(s != 0.f);
                    if (ln == 0)
                        *(u16*)(outp + (i64)(t*PH + prow)*(NCT>>3) + ((nb*256 + wn*64 + cf*16)>>3)) = (u16)(bal >> (g*16));
                } else {
                    outp[((i64)t*PH + prow)*NCT + c] = (u8)s;
                }
                v = v * (1.f - s);
            }
        }
    }
}

// ---------------- f2: 8-wave 256x256, K=2048, A = bitpacked spikes (reg-expand), B = RNE images.
// Both halves in one dispatch (grid 256). Fused BN + LIF + (x+o2)+spike add -> d_out f32.
__global__ __launch_bounds__(512,2)
void gemm8_f2(const u8* __restrict__ hh0, const u8* __restrict__ hh1,
              const u8* __restrict__ Bt,
              const float* __restrict__ bias, const float* __restrict__ gw,
              const float* __restrict__ bew,  const float* __restrict__ muw,
              const float* __restrict__ varw,
              const float* __restrict__ x,
              const u8* __restrict__ o20, const u8* __restrict__ o21,
              float* __restrict__ outF)
{
    __shared__ __align__(16) char smem[65536];       // 2 x (A 16K + B 16K)
    const int tid = threadIdx.x;
    const int cpx = gridDim.x >> 3;
    const int serial = (blockIdx.x & 7)*cpx + (blockIdx.x >> 3);
    const int pbg = serial >> 1, nb = serial & 1;    // 128 pb-tiles x 2 nb
    const int half = pbg >> 6, pb = pbg & 63;
    const int pairBase = half * PH;
    const u8* Abits = half ? hh1 : hh0;
    const u8* o2g   = half ? o21 : o20;

    const int w = tid>>6, lane = tid&63, g = lane>>4, ln = lane&15;
    const int wm = w>>2, wn = w&3;                   // 2M x 4N, wave = 128x64

    f32x4 acc[8][4];
    #pragma unroll
    for (int m=0;m<8;m++)
        #pragma unroll
        for (int cf=0;cf<4;cf++) acc[m][cf] = (f32x4)0.f;

    const u8* Bb = Bt + (i64)nb*64*16384;

    // A expand: tid<256 -> one row (pair*4+t), one u32 = 32 k-bits -> 4 x ds_write_b128
    auto stageA = [&](char* buf, int ks){
        if (tid < 256){
            int row = tid;
            int pair = row>>2, tt = row&3;
            i64 grow = (i64)tt*PH + pb*64 + pair;
            u32 b4 = *(const u32*)(Abits + grow*256 + ks*4);
            *(uint4*)(buf + 0*4096 + row*16) = expandbits(b4);
            *(uint4*)(buf + 1*4096 + row*16) = expandbits(b4>>8);
            *(uint4*)(buf + 2*4096 + row*16) = expandbits(b4>>16);
            *(uint4*)(buf + 3*4096 + row*16) = expandbits(b4>>24);
        }
    };

    // prologue: tile 0
    stageA(smem, 0);
    #pragma unroll
    for (int j=0;j<2;j++)
        gload16(Bb + j*8192 + tid*16, smem + 16384 + j*8192 + tid*16);
    __syncthreads();

    for (int ks=0; ks<64; ks++){
        char* cur = smem + (ks&1)*32768;
        char* nxt = smem + ((ks+1)&1)*32768;
        const bool pre = (ks+1 < 64);
        if (pre){
            #pragma unroll
            for (int j=0;j<2;j++)
                gload16(Bb + (i64)(ks+1)*16384 + j*8192 + tid*16, nxt + 16384 + j*8192 + tid*16);
            stageA(nxt, ks+1);
        }
        bf16x8 bfr[4];
        #pragma unroll
        for (int cf=0;cf<4;cf++){
            int col = wn*64 + cf*16 + ln;
            bfr[cf] = *(const bf16x8*)(cur + 16384 + g*4096 + col*16);
        }
        // phase 0
        {
            bf16x8 af[4];
            #pragma unroll
            for (int fm=0; fm<4; fm++){
                int row = wm*128 + 0*64 + fm*16 + ln;
                af[fm] = *(const bf16x8*)(cur + g*4096 + row*16);
            }
            __builtin_amdgcn_s_setprio(1);
            #pragma unroll
            for (int fm=0; fm<4; fm++)
                #pragma unroll
                for (int cf=0;cf<4;cf++)
                    acc[0*4+fm][cf] = MFMA(af[fm], bfr[cf], acc[0*4+fm][cf]);
            __builtin_amdgcn_s_setprio(0);
        }
        __builtin_amdgcn_sched_barrier(0);
        // phase 1
        {
            bf16x8 af[4];
            #pragma unroll
            for (int fm=0; fm<4; fm++){
                int row = wm*128 + 1*64 + fm*16 + ln;
                af[fm] = *(const bf16x8*)(cur + g*4096 + row*16);
            }
            __builtin_amdgcn_s_setprio(1);
            #pragma unroll
            for (int fm=0; fm<4; fm++)
                #pragma unroll
                for (int cf=0;cf<4;cf++)
                    acc[1*4+fm][cf] = MFMA(af[fm], bfr[cf], acc[1*4+fm][cf]);
            __builtin_amdgcn_s_setprio(0);
        }
        __syncthreads();
    }

    // epilogue: BN + LIF + (x + o2) + spike -> f32 out
    #pragma unroll
    for (int cf=0; cf<4; cf++){
        const int c = nb*256 + wn*64 + cf*16 + ln;
        const float gs  = gw[c] / sqrtf(varw[c] + BNEPS);
        const float bf_ = bias[c], muf = muw[c], bef = bew[c];
        #pragma unroll
        for (int m=0; m<8; m++){
            const int rowBase = wm*128 + m*16 + g*4;
            const int prow = pb*64 + (rowBase>>2);
            float v = 0.f;
            #pragma unroll
            for (int t=0; t<TT; t++){
                float y = acc[m][cf][t] + bf_;
                float z = (y - muf) * gs + bef;
                v = v + (z - v) * 0.5f;
                float s = ((v - 1.0f) >= 0.f) ? 1.f : 0.f;
                i64 lrow = (i64)t*PH + prow;
                i64 grow = (i64)t*8192 + pairBase + prow;
                float xv = x[grow*512 + c];
                float o2v = (float)o2g[lrow*512 + c];
                outF[grow*512 + c] = (xv + o2v) + s;
                v = v * (1.f - s);
            }
        }
    }
}

// ---------------- p stage: spikes x W GEMM + BN + LIF -> o2 (global) + f1 A-images (x+o2 split)
__global__ __launch_bounds__(256)
void gemm_p(const u8* __restrict__ Au8, const u16* __restrict__ WT,
            const float* __restrict__ bias, const float* __restrict__ gw,
            const float* __restrict__ bew,  const float* __restrict__ muw,
            const float* __restrict__ varw,
            const float* __restrict__ x, u8* __restrict__ o2g,
            u8* __restrict__ At, int pairBase)
{
    __shared__ __align__(16) char smem[16384];
    char* smA = smem;
    char* smB = smem + 8192;
    const int tid = threadIdx.x;
    const int nbp = blockIdx.x, pbp = blockIdx.y;
    const int c0 = nbp*128, pair0 = pbp*32;
    const int w = tid>>6, l = tid&63, g = l>>4, ln = l&15;
    const int wm = w>>1, wn = w&1;

    f32x4 acc[TT][4];
    #pragma unroll
    for (int t=0;t<TT;t++)
        #pragma unroll
        for (int cf=0;cf<4;cf++) acc[t][cf] = (f32x4)0.f;

    for (int k0 = 0; k0 < 512; k0 += 32){
        __syncthreads();
        {
            const int row = tid>>1, half = tid&1;
            const int t = row>>5, pp = row&31;
            const i64 grow = (i64)t*PH + pair0 + pp;
            uint4 ob = *(const uint4*)(Au8 + grow*512 + k0 + half*16);
            const u8* pbb = (const u8*)&ob;
            *(uint4*)(smA + swz(row, half*32))    = expand8(pbb);
            *(uint4*)(smA + swz(row, half*32+16)) = expand8(pbb+8);
        }
        #pragma unroll
        for (int j=0;j<2;j++){
            int cid = tid + j*256;
            int col = cid>>2, c = cid&3;
            uint4 d = *(const uint4*)(WT + (i64)(c0+col)*512 + k0 + c*8);
            *(uint4*)(smB + swz(col, c*16)) = d;
        }
        __syncthreads();
        bf16x8 bfr[4];
        #pragma unroll
        for (int cf=0;cf<4;cf++)
            bfr[cf] = *(const bf16x8*)(smB + swz(wn*64 + cf*16 + ln, g*16));
        #pragma unroll
        for (int t=0;t<TT;t++){
            bf16x8 afr = *(const bf16x8*)(smA + swz(t*32 + wm*16 + ln, g*16));
            #pragma unroll
            for (int cf=0;cf<4;cf++)
                acc[t][cf] = MFMA(afr, bfr[cf], acc[t][cf]);
        }
    }

    __syncthreads();
    u8* tile = (u8*)smem;
    #pragma unroll
    for (int cf=0;cf<4;cf++){
        const int c = c0 + wn*64 + cf*16 + ln;
        const float gs  = gw[c] / sqrtf(varw[c] + BNEPS);
        const float bf_ = bias[c], muf = muw[c], bef = bew[c];
        #pragma unroll
        for (int r=0;r<4;r++){
            const int rl = wm*16 + g*4 + r;
            float v = 0.f;
            #pragma unroll
            for (int t=0;t<TT;t++){
                float y = acc[t][cf][r] + bf_;
                float z = (y - muf) * gs + bef;
                v = v + (z - v) * 0.5f;
                float s = ((v - 1.0f) >= 0.f) ? 1.f : 0.f;
                tile[t*4096 + rl*128 + (wn*64 + cf*16 + ln)] = (u8)s;
                v = v * (1.f - s);
            }
        }
    }
    __syncthreads();

    const int pbImg = pbp>>1, rOff = (pbp&1)*128;
    #pragma unroll
    for (int it=0; it<8; it++){
        int task = tid + it*256;
        int kq = task>>9, rem = task&511, gq = rem>>7, rowL = rem&127;
        int rl = rowL>>2, t = rowL&3;
        int ksAbs = nbp*4 + kq;
        int cL = kq*32 + gq*8;
        uint2 ob = *(const uint2*)(tile + t*4096 + rl*128 + cL);
        const u8* pbb = (const u8*)&ob;
        i64 grow = (i64)t*8192 + pairBase + pair0 + rl;
        const float* src = x + grow*512 + ksAbs*32 + gq*8;
        float4 f0 = *(const float4*)src, f1v = *(const float4*)(src+4);
        float vv[8] = {f0.x,f0.y,f0.z,f0.w,f1v.x,f1v.y,f1v.z,f1v.w};
        #pragma unroll
        for (int j=0;j<8;j++) vv[j] = vv[j] + (float)pbb[j];
        u16 h[8], m[8];
        #pragma unroll
        for (int j=0;j<8;j++) split2(vv[j], h[j], m[j]);
        u8* img = At + ((i64)pbImg*KSW + ksAbs)*32768;
        int off = gq*4096 + (rOff + rowL)*16;
        *(ushort4*)(img + off)           = make_ushort4(h[0],h[1],h[2],h[3]);
        *(ushort4*)(img + off + 8)       = make_ushort4(h[4],h[5],h[6],h[7]);
        *(ushort4*)(img + 16384 + off)   = make_ushort4(m[0],m[1],m[2],m[3]);
        *(ushort4*)(img + 16384 + off+8) = make_ushort4(m[4],m[5],m[6],m[7]);
        *(uint2*)(o2g + ((i64)t*PH + pair0 + rl)*512 + ksAbs*32 + gq*8) = ob;
    }
}

// ---------------- spiking attention + attn-LIF (v_th=0.5), qkv packed stride 1536
__global__ __launch_bounds__(256)
void attn_lif_kernel(const u8* __restrict__ qkv, u8* __restrict__ os)
{
    __shared__ __align__(16) char smem[49152];
    char* Kl = smem;
    char* VT = smem + 16384;
    char* AT = smem + 32768;

    const int tid = threadIdx.x;
    const int w = tid>>6, l = tid&63, g = l>>4, ln = l&15;
    const int h = blockIdx.y, b = blockIdx.z;
    const int n0 = blockIdx.x*64 + w*16;

    f32x4 vmem[4];
    #pragma unroll
    for (int cf=0;cf<4;cf++) vmem[cf] = (f32x4)0.f;

    for (int t=0;t<TT;t++){
        const i64 tb = ((i64)(t*16 + b)*256)*1536;
        const i64 ob = ((i64)(t*16 + b)*256)*512 + h*64;
        bf16x8 qf[2];
        #pragma unroll
        for (int ksl=0;ksl<2;ksl++){
            uint2 qv = *(const uint2*)(qkv + tb + (i64)(n0+ln)*1536 + h*64 + ksl*32 + g*8);
            const u8* pb = (const u8*)&qv;
            BF8 f;
            #pragma unroll
            for (int j=0;j<8;j++) f.u[j] = pb[j] ? 0x3F80 : 0;
            qf[ksl] = f.v;
        }
        f32x4 oacc[4];
        #pragma unroll
        for (int cf=0;cf<4;cf++) oacc[cf] = (f32x4)0.f;

        for (int mh=0; mh<2; mh++){
            __syncthreads();
            {
                const int lm = tid>>1, seg = tid&1;
                const u8* src = qkv + tb + (i64)(mh*128+lm)*1536 + 512 + h*64 + seg*32;
                uint4 a = *(const uint4*)(src), c = *(const uint4*)(src+16);
                const u8* pa = (const u8*)&a; const u8* pc = (const u8*)&c;
                #pragma unroll
                for (int q=0;q<4;q++){
                    *(ushort4*)(Kl + swzK(lm, seg*64 + q*8)) =
                        make_ushort4(pa[q*4]?0x3F80:0, pa[q*4+1]?0x3F80:0, pa[q*4+2]?0x3F80:0, pa[q*4+3]?0x3F80:0);
                    *(ushort4*)(Kl + swzK(lm, seg*64 + 32 + q*8)) =
                        make_ushort4(pc[q*4]?0x3F80:0, pc[q*4+1]?0x3F80:0, pc[q*4+2]?0x3F80:0, pc[q*4+3]?0x3F80:0);
                }
            }
            {
                const int lm = tid>>1, seg = tid&1;
                const u8* src = qkv + tb + (i64)(mh*128+lm)*1536 + 1024 + h*64 + seg*32;
                uint4 a = *(const uint4*)(src), c = *(const uint4*)(src+16);
                const u8* pa = (const u8*)&a; const u8* pc = (const u8*)&c;
                #pragma unroll
                for (int j=0;j<16;j++){
                    *(u16*)(VT + swzV(seg*32 + j,      lm*2)) = pa[j] ? 0x3F80 : 0;
                    *(u16*)(VT + swzV(seg*32 + 16 + j, lm*2)) = pc[j] ? 0x3F80 : 0;
                }
            }
            __syncthreads();
            #pragma unroll
            for (int rf=0;rf<8;rf++){
                f32x4 s = (f32x4)0.f;
                #pragma unroll
                for (int ksl=0;ksl<2;ksl++){
                    bf16x8 kf = *(const bf16x8*)(Kl + swzK(rf*16+ln, ksl*64 + g*16));
                    s = MFMA(kf, qf[ksl], s);
                }
                ushort4 pk = make_ushort4(f2bf_rne(s[0]*0.125f), f2bf_rne(s[1]*0.125f),
                                          f2bf_rne(s[2]*0.125f), f2bf_rne(s[3]*0.125f));
                *(ushort4*)(AT + swzV(w*16+ln, rf*32 + g*8)) = pk;
            }
            #pragma unroll
            for (int ms=0;ms<4;ms++){
                bf16x8 af = *(const bf16x8*)(AT + swzV(w*16+ln, ms*64 + g*16));
                #pragma unroll
                for (int cf=0;cf<4;cf++){
                    bf16x8 vf = *(const bf16x8*)(VT + swzV(cf*16+ln, ms*64 + g*16));
                    oacc[cf] = MFMA(af, vf, oacc[cf]);
                }
            }
        }
        #pragma unroll
        for (int cf=0;cf<4;cf++)
            #pragma unroll
            for (int r=0;r<4;r++){
                float v = vmem[cf][r];
                v = v + (oacc[cf][r] - v) * 0.5f;
                float s = ((v - 0.5f) >= 0.f) ? 1.f : 0.f;
                os[ob + (i64)(n0 + g*4 + r)*512 + cf*16 + ln] = (u8)s;
                vmem[cf][r] = v * (1.f - s);
            }
    }
}

extern "C" void kernel_launch(void* const* d_in, const int* in_sizes, int n_in,
                              void* d_out, int out_size, void* d_ws, size_t ws_size,
                              hipStream_t stream)
{
    (void)in_sizes; (void)n_in; (void)out_size; (void)ws_size;
    const float* x = (const float*)d_in[0];
    #define GETP(i) ((const float*)d_in[i])

    char* ws = (char*)d_ws;
    u8*  Bqkv = (u8*)(ws + 0);               //  6*16*16384 = 1,572,864
    u8*  Bf1  = (u8*)(ws + 1572864);         //  8*16*16384 = 2,097,152
    u8*  Bf2  = (u8*)(ws + 3670016);         //  2*64*16384 = 2,097,152
    u16* WTp  = (u16*)(ws + 5767168);        //  524,288
    u8*  At   = (u8*)(ws + 6291456);         // 64*16*32768 = 33,554,432
    u8*  qkv  = (u8*)(ws + 39845888);        // 25,165,824
    u8*  os_  = (u8*)(ws + 65011712);        //  8,388,608
    u8*  o2h[2] = { (u8*)(ws + 73400320), (u8*)(ws + 81788928) };   // 8,388,608 each
    u8*  hhb[2] = { (u8*)(ws + 90177536), (u8*)(ws + 94371840) };   // 4,194,304 each -> ends 98,566,144

    hipFuncSetAttribute((const void*)gemm8<false>, hipFuncAttributeMaxDynamicSharedMemorySize, 98304);
    hipFuncSetAttribute((const void*)gemm8<true>,  hipFuncAttributeMaxDynamicSharedMemorySize, 98304);

    dim3 blk(256,1,1);
    // W prep
    wsplit_rne<<<dim3(16,2), blk,0,stream>>>(GETP(1),  Bqkv, 512, 0, 16);
    wsplit_rne<<<dim3(16,2), blk,0,stream>>>(GETP(7),  Bqkv, 512, 2, 16);
    wsplit_rne<<<dim3(16,2), blk,0,stream>>>(GETP(13), Bqkv, 512, 4, 16);
    wsplit_rne<<<dim3(16,8), blk,0,stream>>>(GETP(25), Bf1, 2048, 0, 16);
    wsplit_rne<<<dim3(64,2), blk,0,stream>>>(GETP(31), Bf2,  512, 0, 64);
    wsplit_old<<<dim3(8,8),  blk,0,stream>>>(GETP(19), WTp,  512, 512);

    for (int hb = 0; hb < 2; hb++){
        const int pb = hb * PH;
        asplitT<<<dim3(64,16),blk,0,stream>>>(x, At, pb);
        // fused q/k/v (N=1536, NB=6, grid 384)
        gemm8<false><<<dim3(384),dim3(512),98304,stream>>>(At, Bqkv,
            GETP(2),GETP(8),GETP(14),  GETP(3),GETP(9),GETP(15),
            GETP(4),GETP(10),GETP(16), GETP(5),GETP(11),GETP(17),
            GETP(6),GETP(12),GETP(18), qkv, 6, 1536, 511);
        attn_lif_kernel<<<dim3(4,8,16),blk,0,stream>>>(qkv, os_);
        // p stage + fused o2/f1-image production
        gemm_p<<<dim3(4,128),blk,0,stream>>>(os_, WTp,
            GETP(20),GETP(21),GETP(22),GETP(23),GETP(24), x, o2h[hb], At, pb);
        // f1 (N=2048, NB=8, grid 512, bitpacked out)
        gemm8<true><<<dim3(512),dim3(512),98304,stream>>>(At, Bf1,
            GETP(26),GETP(26),GETP(26), GETP(27),GETP(27),GETP(27),
            GETP(28),GETP(28),GETP(28), GETP(29),GETP(29),GETP(29),
            GETP(30),GETP(30),GETP(30), hhb[hb], 8, 2048, 2047);
    }
    // f2 both halves, full chip (grid 256), fused final add -> d_out
    gemm8_f2<<<dim3(256),dim3(512),0,stream>>>(hhb[0], hhb[1], Bf2,
        GETP(32),GETP(33),GETP(34),GETP(35),GETP(36), x, o2h[0], o2h[1], (float*)d_out);
}

// Round 11
// 535.428 us; speedup vs baseline: 5.5545x; 1.0353x over previous
//
#include <hip/hip_runtime.h>

typedef unsigned char u8;
typedef unsigned short u16;
typedef unsigned int u32;
typedef unsigned long long u64;
typedef long long i64;

#define TT 4
#define PH 4096             // pairs per half
#define KSW 16              // K/32 images for K=512
#define BNEPS 1e-5f

typedef __attribute__((ext_vector_type(8))) __bf16 bf16x8;
typedef __attribute__((ext_vector_type(4))) float f32x4;

__device__ __forceinline__ float bf2f(u16 b){ return __uint_as_float(((u32)b)<<16); }
__device__ __forceinline__ u16 f2bf_rne(float f){ u32 u = __float_as_uint(f); return (u16)((u + 0x7FFFu + ((u>>16)&1u))>>16); }
__device__ __forceinline__ u16 f2bf_tr(float f){ return (u16)(__float_as_uint(f)>>16); }

__device__ __forceinline__ void split2(float v, u16& h, u16& m){
    h = f2bf_tr(v); m = f2bf_tr(v - bf2f(h));
}

__device__ __forceinline__ f32x4 MFMA(bf16x8 a, bf16x8 b, f32x4 c){
    return __builtin_amdgcn_mfma_f32_16x16x32_bf16(a, b, c, 0, 0, 0);
}

union BF8 { u16 u[8]; bf16x8 v; };

__device__ __forceinline__ void gload16(const void* g, void* l){
    __builtin_amdgcn_global_load_lds(
        (const __attribute__((address_space(1))) unsigned int*)g,
        (__attribute__((address_space(3))) unsigned int*)l, 16, 0, 0);
}

// reg-staged kernels' swizzles (validated r3-r10)
__device__ __forceinline__ int swz(int row, int off){ return row*64 + (off ^ (((row>>1)&3)<<4)); }
__device__ __forceinline__ int swzK(int row, int off){ return row*128 + (off ^ ((row&7)<<4)); }
__device__ __forceinline__ int swzV(int row, int off){ return row*256 + (off ^ ((row&7)<<4)); }

__device__ __forceinline__ uint4 expand8(const u8* pb){
    u32 w0 = (pb[0]?0x3F80u:0u) | ((pb[1]?0x3F80u:0u)<<16);
    u32 w1 = (pb[2]?0x3F80u:0u) | ((pb[3]?0x3F80u:0u)<<16);
    u32 w2 = (pb[4]?0x3F80u:0u) | ((pb[5]?0x3F80u:0u)<<16);
    u32 w3 = (pb[6]?0x3F80u:0u) | ((pb[7]?0x3F80u:0u)<<16);
    return make_uint4(w0,w1,w2,w3);
}
__device__ __forceinline__ uint4 expandbits(u32 bits){
    u32 w0 = ((bits>>0)&1?0x3F80u:0u) | ((bits>>1)&1?0x3F800000u:0u);
    u32 w1 = ((bits>>2)&1?0x3F80u:0u) | ((bits>>3)&1?0x3F800000u:0u);
    u32 w2 = ((bits>>4)&1?0x3F80u:0u) | ((bits>>5)&1?0x3F800000u:0u);
    u32 w3 = ((bits>>6)&1?0x3F80u:0u) | ((bits>>7)&1?0x3F800000u:0u);
    return make_uint4(w0,w1,w2,w3);
}

// ---------------- W -> 256-col 1-plane RNE images: img(nb,ks)[g][col 0..255][16B], 16KB
__global__ __launch_bounds__(256)
void wsplit_rne(const float* __restrict__ W, u8* __restrict__ out, int NC, int nbOff, int ksn)
{
    const int ks = blockIdx.x, nbl = blockIdx.y;
    const int c0 = nbl*256;
    u8* img = out + ((i64)(nbOff+nbl)*ksn + ks)*16384;
    #pragma unroll
    for (int it=0; it<4; it++){
        int task = threadIdx.x + it*256;     // (col 0..255, gq minor 0..3)
        int col = task>>2, gq = task&3;
        float v[8];
        #pragma unroll
        for (int j=0;j<8;j++) v[j] = W[(i64)(ks*32 + gq*8 + j)*NC + c0 + col];
        u16 h[8];
        #pragma unroll
        for (int j=0;j<8;j++) h[j] = f2bf_rne(v[j]);
        int off = gq*4096 + col*16;
        *(ushort4*)(img + off)     = make_ushort4(h[0],h[1],h[2],h[3]);
        *(ushort4*)(img + off + 8) = make_ushort4(h[4],h[5],h[6],h[7]);
    }
}

// ---------------- W -> RNE bf16 [NC][K] (for p reg-staged GEMM)
__global__ __launch_bounds__(256)
void wsplit_old(const float* __restrict__ W, u16* __restrict__ out, int K, int NC)
{
    __shared__ float tile[64][65];
    const int k0 = blockIdx.x*64, c0 = blockIdx.y*64;
    const int tid = threadIdx.x;
    #pragma unroll
    for (int j=0;j<16;j++){
        int el = tid + j*256; int r = el>>6, c = el&63;
        tile[r][c] = W[(i64)(k0+r)*NC + c0 + c];
    }
    __syncthreads();
    #pragma unroll
    for (int j=0;j<16;j++){
        int el = tid + j*256; int c = el>>6, k = el&63;
        out[(i64)(c0+c)*K + k0 + k] = f2bf_rne(tile[k][c]);
    }
}

// ---------------- x -> A images: img(pb,ks)[pl][g][row 0..255][16B], row = pair*4 + t, 32KB
__global__ __launch_bounds__(256)
void asplitT(const float* __restrict__ x, u8* __restrict__ At, int pairBase)
{
    const int pb = blockIdx.x, ks = blockIdx.y;
    u8* img = At + ((i64)pb*KSW + ks)*32768;
    #pragma unroll
    for (int it=0; it<4; it++){
        int task = threadIdx.x + it*256;     // (row 0..255, gq minor)
        int row = task>>2, gq = task&3;
        int pair = row>>2, t = row&3;
        i64 grow = (i64)t*8192 + pairBase + pb*64 + pair;
        const float* src = x + grow*512 + ks*32 + gq*8;
        float4 f0 = *(const float4*)src, f1v = *(const float4*)(src+4);
        float vv[8] = {f0.x,f0.y,f0.z,f0.w,f1v.x,f1v.y,f1v.z,f1v.w};
        u16 h[8], m[8];
        #pragma unroll
        for (int j=0;j<8;j++) split2(vv[j], h[j], m[j]);
        int off = gq*4096 + row*16;
        *(ushort4*)(img + off)           = make_ushort4(h[0],h[1],h[2],h[3]);
        *(ushort4*)(img + off + 8)       = make_ushort4(h[4],h[5],h[6],h[7]);
        *(ushort4*)(img + 16384 + off)   = make_ushort4(m[0],m[1],m[2],m[3]);
        *(ushort4*)(img + 16384 + off+8) = make_ushort4(m[4],m[5],m[6],m[7]);
    }
}

// ---------------- 8-wave 256x256 GEMM + BN + LIF, 2-product (A_h+A_m)*RNE(W)
template<bool BITOUT>
__global__ __launch_bounds__(512,2)
void gemm8(const u8* __restrict__ At, const u8* __restrict__ Bt,
           const float* __restrict__ b0, const float* __restrict__ b1, const float* __restrict__ b2,
           const float* __restrict__ g0, const float* __restrict__ g1, const float* __restrict__ g2,
           const float* __restrict__ e0, const float* __restrict__ e1, const float* __restrict__ e2,
           const float* __restrict__ u0, const float* __restrict__ u1, const float* __restrict__ u2,
           const float* __restrict__ v0, const float* __restrict__ v1, const float* __restrict__ v2,
           u8* __restrict__ outp, int NB, int NCT, int cmask)
{
    extern __shared__ __align__(16) char smem[];     // 98304: 2 x (A 32K + B 16K)
    const int tid = threadIdx.x;
    const int cpx = gridDim.x >> 3;
    const int serial = (blockIdx.x & 7)*cpx + (blockIdx.x >> 3);
    const int pb = serial / NB, nb = serial % NB;

    const int w = tid>>6, lane = tid&63, g = lane>>4, ln = lane&15;
    const int wm = w>>2, wn = w&3;                   // 2M x 4N

    f32x4 acc[8][4];
    #pragma unroll
    for (int m=0;m<8;m++)
        #pragma unroll
        for (int cf=0;cf<4;cf++) acc[m][cf] = (f32x4)0.f;

    const u8* Ab = At + (i64)pb*KSW*32768;
    const u8* Bb = Bt + (i64)nb*KSW*16384;

    #pragma unroll
    for (int j=0;j<4;j++)
        gload16(Ab + j*8192 + tid*16, smem + j*8192 + tid*16);
    #pragma unroll
    for (int j=0;j<2;j++)
        gload16(Bb + j*8192 + tid*16, smem + 32768 + j*8192 + tid*16);
    __syncthreads();

    for (int ks=0; ks<KSW; ks++){
        char* cur = smem + (ks&1)*49152;
        char* nxt = smem + ((ks+1)&1)*49152;
        const bool pre = (ks+1 < KSW);
        const u8* Ai = Ab + (i64)(ks+1)*32768;
        const u8* Bi = Bb + (i64)(ks+1)*16384;

        if (pre){
            #pragma unroll
            for (int j=0;j<4;j++) gload16(Ai + j*8192 + tid*16, nxt + j*8192 + tid*16);
        }
        bf16x8 bfr[2][2];     // [b-half][cb]
        #pragma unroll
        for (int b=0;b<2;b++)
            #pragma unroll
            for (int cb=0;cb<2;cb++){
                int col = wn*64 + b*32 + cb*16 + ln;
                bfr[b][cb] = *(const bf16x8*)(cur + 32768 + g*4096 + col*16);
            }

        // ---- phase 0 (m-half a=0)
        {
            bf16x8 af[4][2];
            #pragma unroll
            for (int fm=0; fm<4; fm++){
                int row = wm*128 + 0*64 + fm*16 + ln;
                af[fm][0] = *(const bf16x8*)(cur + g*4096 + row*16);
                af[fm][1] = *(const bf16x8*)(cur + 16384 + g*4096 + row*16);
            }
            __builtin_amdgcn_s_setprio(1);
            #pragma unroll
            for (int fm=0; fm<4; fm++)
                #pragma unroll
                for (int b=0;b<2;b++)
                    #pragma unroll
                    for (int cb=0;cb<2;cb++){
                        const int m = 0*4+fm, cfi = b*2+cb;
                        f32x4 x4 = acc[m][cfi];
                        x4 = MFMA(af[fm][0], bfr[b][cb], x4);
                        x4 = MFMA(af[fm][1], bfr[b][cb], x4);
                        acc[m][cfi] = x4;
                    }
            __builtin_amdgcn_s_setprio(0);
        }
        __builtin_amdgcn_sched_barrier(0);
        if (pre){
            #pragma unroll
            for (int j=0;j<2;j++) gload16(Bi + j*8192 + tid*16, nxt + 32768 + j*8192 + tid*16);
        }
        // ---- phase 1 (m-half a=1)
        {
            bf16x8 af[4][2];
            #pragma unroll
            for (int fm=0; fm<4; fm++){
                int row = wm*128 + 1*64 + fm*16 + ln;
                af[fm][0] = *(const bf16x8*)(cur + g*4096 + row*16);
                af[fm][1] = *(const bf16x8*)(cur + 16384 + g*4096 + row*16);
            }
            __builtin_amdgcn_s_setprio(1);
            #pragma unroll
            for (int fm=0; fm<4; fm++)
                #pragma unroll
                for (int b=0;b<2;b++)
                    #pragma unroll
                    for (int cb=0;cb<2;cb++){
                        const int m = 1*4+fm, cfi = b*2+cb;
                        f32x4 x4 = acc[m][cfi];
                        x4 = MFMA(af[fm][0], bfr[b][cb], x4);
                        x4 = MFMA(af[fm][1], bfr[b][cb], x4);
                        acc[m][cfi] = x4;
                    }
            __builtin_amdgcn_s_setprio(0);
        }
        __syncthreads();
    }

    #pragma unroll
    for (int cf=0; cf<4; cf++){
        const int c = nb*256 + wn*64 + cf*16 + ln;
        int which = c >> 9; if (which > 2) which = 2;
        const float* bp = which==0?b0:(which==1?b1:b2);
        const float* gp = which==0?g0:(which==1?g1:g2);
        const float* ep = which==0?e0:(which==1?e1:e2);
        const float* up = which==0?u0:(which==1?u1:u2);
        const float* vp = which==0?v0:(which==1?v1:v2);
        const int ci = c & cmask;
        const float gs  = gp[ci] / sqrtf(vp[ci] + BNEPS);
        const float bf_ = bp[ci], muf = up[ci], bef = ep[ci];
        #pragma unroll
        for (int m=0; m<8; m++){
            const int rowBase = wm*128 + m*16 + g*4;
            const int prow = pb*64 + (rowBase>>2);
            float v = 0.f;
            #pragma unroll
            for (int t=0; t<TT; t++){
                float y = acc[m][cf][t] + bf_;
                float z = (y - muf) * gs + bef;
                v = v + (z - v) * 0.5f;
                float s = ((v - 1.0f) >= 0.f) ? 1.f : 0.f;
                if (BITOUT){
                    u64 bal = __ballot(s != 0.f);
                    if (ln == 0)
                        *(u16*)(outp + (i64)(t*PH + prow)*(NCT>>3) + ((nb*256 + wn*64 + cf*16)>>3)) = (u16)(bal >> (g*16));
                } else {
                    outp[((i64)t*PH + prow)*NCT + c] = (u8)s;
                }
                v = v * (1.f - s);
            }
        }
    }
}

// ---------------- f2 v2: BM=128 x BN=256, K=2048, grid 512 (2 blocks/CU), 8 waves 2Mx4N (wave 64x64).
// A = bitpacked spikes reg-expanded -> swz LDS; B = gload16 from 256-col RNE images.
// Fused BN + LIF + (x+o2)+spike add -> d_out f32. Both halves in one dispatch.
__global__ __launch_bounds__(512,4)
void gemm8_f2(const u8* __restrict__ hh0, const u8* __restrict__ hh1,
              const u8* __restrict__ Bt,
              const float* __restrict__ bias, const float* __restrict__ gw,
              const float* __restrict__ bew,  const float* __restrict__ muw,
              const float* __restrict__ varw,
              const float* __restrict__ x,
              const u8* __restrict__ o20, const u8* __restrict__ o21,
              float* __restrict__ outF)
{
    __shared__ __align__(16) char smem[49152];       // 2 x (A 8K + B 16K)
    const int tid = threadIdx.x;
    const int cpx = gridDim.x >> 3;                  // 64
    const int serial = (blockIdx.x & 7)*cpx + (blockIdx.x >> 3);
    const int nb = serial & 1, pbg = serial >> 1;    // 256 pb-tiles x 2 nb
    const int half = pbg >> 7, pb = pbg & 127;       // 128 tiles of 32 pairs per half
    const u8* Abits = half ? hh1 : hh0;
    const u8* o2g   = half ? o21 : o20;

    const int w = tid>>6, lane = tid&63, g = lane>>4, ln = lane&15;
    const int wm = w>>2, wn = w&3;                   // 2M x 4N, wave 64x64

    f32x4 acc[4][4];
    #pragma unroll
    for (int fm=0;fm<4;fm++)
        #pragma unroll
        for (int cb=0;cb<4;cb++) acc[fm][cb] = (f32x4)0.f;

    const u8* Bb = Bt + (i64)nb*64*16384;

    // A stage: 512 threads = 128 rows x 4 gq; row = pair*4 + t
    auto stageA = [&](char* buf, int ks){
        const int row = tid>>2, gq = tid&3;
        i64 grow = (i64)(row&3)*PH + pb*32 + (row>>2);
        u32 b4 = *(const u32*)(Abits + grow*256 + ks*4);
        *(uint4*)(buf + swz(row, gq*16)) = expandbits(b4 >> (8*gq));
    };

    // prologue: tile 0
    stageA(smem, 0);
    #pragma unroll
    for (int j=0;j<2;j++)
        gload16(Bb + (tid + j*512)*16, smem + 8192 + (tid + j*512)*16);
    __syncthreads();

    for (int ks=0; ks<64; ks++){
        char* cur = smem + (ks&1)*24576;
        char* nxt = smem + ((ks+1)&1)*24576;
        if (ks+1 < 64){
            #pragma unroll
            for (int j=0;j<2;j++)
                gload16(Bb + (i64)(ks+1)*16384 + (tid+j*512)*16, nxt + 8192 + (tid+j*512)*16);
            stageA(nxt, ks+1);
        }
        bf16x8 bfr[4], af[4];
        #pragma unroll
        for (int cb=0;cb<4;cb++)
            bfr[cb] = *(const bf16x8*)(cur + 8192 + g*4096 + (wn*64 + cb*16 + ln)*16);
        #pragma unroll
        for (int fm=0;fm<4;fm++)
            af[fm] = *(const bf16x8*)(cur + swz(wm*64 + fm*16 + ln, g*16));
        __builtin_amdgcn_s_setprio(1);
        #pragma unroll
        for (int fm=0;fm<4;fm++)
            #pragma unroll
            for (int cb=0;cb<4;cb++)
                acc[fm][cb] = MFMA(af[fm], bfr[cb], acc[fm][cb]);
        __builtin_amdgcn_s_setprio(0);
        __syncthreads();
    }

    // epilogue: BN + LIF + (x + o2) + spike -> f32 out
    #pragma unroll
    for (int cb=0; cb<4; cb++){
        const int c = nb*256 + wn*64 + cb*16 + ln;
        const float gs  = gw[c] / sqrtf(varw[c] + BNEPS);
        const float bf_ = bias[c], muf = muw[c], bef = bew[c];
        #pragma unroll
        for (int fm=0; fm<4; fm++){
            const int prow = pb*32 + wm*16 + fm*4 + g;
            float v = 0.f;
            #pragma unroll
            for (int t=0; t<TT; t++){
                float y = acc[fm][cb][t] + bf_;
                float z = (y - muf) * gs + bef;
                v = v + (z - v) * 0.5f;
                float s = ((v - 1.0f) >= 0.f) ? 1.f : 0.f;
                i64 lrow = (i64)t*PH + prow;
                i64 grow = (i64)t*8192 + half*PH + prow;
                float xv = x[grow*512 + c];
                float o2v = (float)o2g[lrow*512 + c];
                outF[grow*512 + c] = (xv + o2v) + s;
                v = v * (1.f - s);
            }
        }
    }
}

// ---------------- p stage: spikes x W GEMM + BN + LIF -> o2 (global) + f1 A-images (x+o2 split)
__global__ __launch_bounds__(256)
void gemm_p(const u8* __restrict__ Au8, const u16* __restrict__ WT,
            const float* __restrict__ bias, const float* __restrict__ gw,
            const float* __restrict__ bew,  const float* __restrict__ muw,
            const float* __restrict__ varw,
            const float* __restrict__ x, u8* __restrict__ o2g,
            u8* __restrict__ At, int pairBase)
{
    __shared__ __align__(16) char smem[16384];
    char* smA = smem;
    char* smB = smem + 8192;
    const int tid = threadIdx.x;
    const int nbp = blockIdx.x, pbp = blockIdx.y;
    const int c0 = nbp*128, pair0 = pbp*32;
    const int w = tid>>6, l = tid&63, g = l>>4, ln = l&15;
    const int wm = w>>1, wn = w&1;

    f32x4 acc[TT][4];
    #pragma unroll
    for (int t=0;t<TT;t++)
        #pragma unroll
        for (int cf=0;cf<4;cf++) acc[t][cf] = (f32x4)0.f;

    for (int k0 = 0; k0 < 512; k0 += 32){
        __syncthreads();
        {
            const int row = tid>>1, half = tid&1;
            const int t = row>>5, pp = row&31;
            const i64 grow = (i64)t*PH + pair0 + pp;
            uint4 ob = *(const uint4*)(Au8 + grow*512 + k0 + half*16);
            const u8* pbb = (const u8*)&ob;
            *(uint4*)(smA + swz(row, half*32))    = expand8(pbb);
            *(uint4*)(smA + swz(row, half*32+16)) = expand8(pbb+8);
        }
        #pragma unroll
        for (int j=0;j<2;j++){
            int cid = tid + j*256;
            int col = cid>>2, c = cid&3;
            uint4 d = *(const uint4*)(WT + (i64)(c0+col)*512 + k0 + c*8);
            *(uint4*)(smB + swz(col, c*16)) = d;
        }
        __syncthreads();
        bf16x8 bfr[4];
        #pragma unroll
        for (int cf=0;cf<4;cf++)
            bfr[cf] = *(const bf16x8*)(smB + swz(wn*64 + cf*16 + ln, g*16));
        #pragma unroll
        for (int t=0;t<TT;t++){
            bf16x8 afr = *(const bf16x8*)(smA + swz(t*32 + wm*16 + ln, g*16));
            #pragma unroll
            for (int cf=0;cf<4;cf++)
                acc[t][cf] = MFMA(afr, bfr[cf], acc[t][cf]);
        }
    }

    __syncthreads();
    u8* tile = (u8*)smem;
    #pragma unroll
    for (int cf=0;cf<4;cf++){
        const int c = c0 + wn*64 + cf*16 + ln;
        const float gs  = gw[c] / sqrtf(varw[c] + BNEPS);
        const float bf_ = bias[c], muf = muw[c], bef = bew[c];
        #pragma unroll
        for (int r=0;r<4;r++){
            const int rl = wm*16 + g*4 + r;
            float v = 0.f;
            #pragma unroll
            for (int t=0;t<TT;t++){
                float y = acc[t][cf][r] + bf_;
                float z = (y - muf) * gs + bef;
                v = v + (z - v) * 0.5f;
                float s = ((v - 1.0f) >= 0.f) ? 1.f : 0.f;
                tile[t*4096 + rl*128 + (wn*64 + cf*16 + ln)] = (u8)s;
                v = v * (1.f - s);
            }
        }
    }
    __syncthreads();

    const int pbImg = pbp>>1, rOff = (pbp&1)*128;
    #pragma unroll
    for (int it=0; it<8; it++){
        int task = tid + it*256;
        int kq = task>>9, rem = task&511, gq = rem>>7, rowL = rem&127;
        int rl = rowL>>2, t = rowL&3;
        int ksAbs = nbp*4 + kq;
        int cL = kq*32 + gq*8;
        uint2 ob = *(const uint2*)(tile + t*4096 + rl*128 + cL);
        const u8* pbb = (const u8*)&ob;
        i64 grow = (i64)t*8192 + pairBase + pair0 + rl;
        const float* src = x + grow*512 + ksAbs*32 + gq*8;
        float4 f0 = *(const float4*)src, f1v = *(const float4*)(src+4);
        float vv[8] = {f0.x,f0.y,f0.z,f0.w,f1v.x,f1v.y,f1v.z,f1v.w};
        #pragma unroll
        for (int j=0;j<8;j++) vv[j] = vv[j] + (float)pbb[j];
        u16 h[8], m[8];
        #pragma unroll
        for (int j=0;j<8;j++) split2(vv[j], h[j], m[j]);
        u8* img = At + ((i64)pbImg*KSW + ksAbs)*32768;
        int off = gq*4096 + (rOff + rowL)*16;
        *(ushort4*)(img + off)           = make_ushort4(h[0],h[1],h[2],h[3]);
        *(ushort4*)(img + off + 8)       = make_ushort4(h[4],h[5],h[6],h[7]);
        *(ushort4*)(img + 16384 + off)   = make_ushort4(m[0],m[1],m[2],m[3]);
        *(ushort4*)(img + 16384 + off+8) = make_ushort4(m[4],m[5],m[6],m[7]);
        *(uint2*)(o2g + ((i64)t*PH + pair0 + rl)*512 + ksAbs*32 + gq*8) = ob;
    }
}

// ---------------- spiking attention + attn-LIF (v_th=0.5), qkv packed stride 1536
__global__ __launch_bounds__(256)
void attn_lif_kernel(const u8* __restrict__ qkv, u8* __restrict__ os)
{
    __shared__ __align__(16) char smem[49152];
    char* Kl = smem;
    char* VT = smem + 16384;
    char* AT = smem + 32768;

    const int tid = threadIdx.x;
    const int w = tid>>6, l = tid&63, g = l>>4, ln = l&15;
    const int h = blockIdx.y, b = blockIdx.z;
    const int n0 = blockIdx.x*64 + w*16;

    f32x4 vmem[4];
    #pragma unroll
    for (int cf=0;cf<4;cf++) vmem[cf] = (f32x4)0.f;

    for (int t=0;t<TT;t++){
        const i64 tb = ((i64)(t*16 + b)*256)*1536;
        const i64 ob = ((i64)(t*16 + b)*256)*512 + h*64;
        bf16x8 qf[2];
        #pragma unroll
        for (int ksl=0;ksl<2;ksl++){
            uint2 qv = *(const uint2*)(qkv + tb + (i64)(n0+ln)*1536 + h*64 + ksl*32 + g*8);
            const u8* pb = (const u8*)&qv;
            BF8 f;
            #pragma unroll
            for (int j=0;j<8;j++) f.u[j] = pb[j] ? 0x3F80 : 0;
            qf[ksl] = f.v;
        }
        f32x4 oacc[4];
        #pragma unroll
        for (int cf=0;cf<4;cf++) oacc[cf] = (f32x4)0.f;

        for (int mh=0; mh<2; mh++){
            __syncthreads();
            {
                const int lm = tid>>1, seg = tid&1;
                const u8* src = qkv + tb + (i64)(mh*128+lm)*1536 + 512 + h*64 + seg*32;
                uint4 a = *(const uint4*)(src), c = *(const uint4*)(src+16);
                const u8* pa = (const u8*)&a; const u8* pc = (const u8*)&c;
                #pragma unroll
                for (int q=0;q<4;q++){
                    *(ushort4*)(Kl + swzK(lm, seg*64 + q*8)) =
                        make_ushort4(pa[q*4]?0x3F80:0, pa[q*4+1]?0x3F80:0, pa[q*4+2]?0x3F80:0, pa[q*4+3]?0x3F80:0);
                    *(ushort4*)(Kl + swzK(lm, seg*64 + 32 + q*8)) =
                        make_ushort4(pc[q*4]?0x3F80:0, pc[q*4+1]?0x3F80:0, pc[q*4+2]?0x3F80:0, pc[q*4+3]?0x3F80:0);
                }
            }
            {
                const int lm = tid>>1, seg = tid&1;
                const u8* src = qkv + tb + (i64)(mh*128+lm)*1536 + 1024 + h*64 + seg*32;
                uint4 a = *(const uint4*)(src), c = *(const uint4*)(src+16);
                const u8* pa = (const u8*)&a; const u8* pc = (const u8*)&c;
                #pragma unroll
                for (int j=0;j<16;j++){
                    *(u16*)(VT + swzV(seg*32 + j,      lm*2)) = pa[j] ? 0x3F80 : 0;
                    *(u16*)(VT + swzV(seg*32 + 16 + j, lm*2)) = pc[j] ? 0x3F80 : 0;
                }
            }
            __syncthreads();
            #pragma unroll
            for (int rf=0;rf<8;rf++){
                f32x4 s = (f32x4)0.f;
                #pragma unroll
                for (int ksl=0;ksl<2;ksl++){
                    bf16x8 kf = *(const bf16x8*)(Kl + swzK(rf*16+ln, ksl*64 + g*16));
                    s = MFMA(kf, qf[ksl], s);
                }
                ushort4 pk = make_ushort4(f2bf_rne(s[0]*0.125f), f2bf_rne(s[1]*0.125f),
                                          f2bf_rne(s[2]*0.125f), f2bf_rne(s[3]*0.125f));
                *(ushort4*)(AT + swzV(w*16+ln, rf*32 + g*8)) = pk;
            }
            #pragma unroll
            for (int ms=0;ms<4;ms++){
                bf16x8 af = *(const bf16x8*)(AT + swzV(w*16+ln, ms*64 + g*16));
                #pragma unroll
                for (int cf=0;cf<4;cf++){
                    bf16x8 vf = *(const bf16x8*)(VT + swzV(cf*16+ln, ms*64 + g*16));
                    oacc[cf] = MFMA(af, vf, oacc[cf]);
                }
            }
        }
        #pragma unroll
        for (int cf=0;cf<4;cf++)
            #pragma unroll
            for (int r=0;r<4;r++){
                float v = vmem[cf][r];
                v = v + (oacc[cf][r] - v) * 0.5f;
                float s = ((v - 0.5f) >= 0.f) ? 1.f : 0.f;
                os[ob + (i64)(n0 + g*4 + r)*512 + cf*16 + ln] = (u8)s;
                vmem[cf][r] = v * (1.f - s);
            }
    }
}

extern "C" void kernel_launch(void* const* d_in, const int* in_sizes, int n_in,
                              void* d_out, int out_size, void* d_ws, size_t ws_size,
                              hipStream_t stream)
{
    (void)in_sizes; (void)n_in; (void)out_size; (void)ws_size;
    const float* x = (const float*)d_in[0];
    #define GETP(i) ((const float*)d_in[i])

    char* ws = (char*)d_ws;
    u8*  Bqkv = (u8*)(ws + 0);               //  6*16*16384 = 1,572,864
    u8*  Bf1  = (u8*)(ws + 1572864);         //  8*16*16384 = 2,097,152
    u8*  Bf2  = (u8*)(ws + 3670016);         //  2*64*16384 = 2,097,152
    u16* WTp  = (u16*)(ws + 5767168);        //  524,288
    u8*  At   = (u8*)(ws + 6291456);         // 64*16*32768 = 33,554,432
    u8*  qkv  = (u8*)(ws + 39845888);        // 25,165,824
    u8*  os_  = (u8*)(ws + 65011712);        //  8,388,608
    u8*  o2h[2] = { (u8*)(ws + 73400320), (u8*)(ws + 81788928) };   // 8,388,608 each
    u8*  hhb[2] = { (u8*)(ws + 90177536), (u8*)(ws + 94371840) };   // 4,194,304 each -> ends 98,566,144

    hipFuncSetAttribute((const void*)gemm8<false>, hipFuncAttributeMaxDynamicSharedMemorySize, 98304);
    hipFuncSetAttribute((const void*)gemm8<true>,  hipFuncAttributeMaxDynamicSharedMemorySize, 98304);

    dim3 blk(256,1,1);
    // W prep
    wsplit_rne<<<dim3(16,2), blk,0,stream>>>(GETP(1),  Bqkv, 512, 0, 16);
    wsplit_rne<<<dim3(16,2), blk,0,stream>>>(GETP(7),  Bqkv, 512, 2, 16);
    wsplit_rne<<<dim3(16,2), blk,0,stream>>>(GETP(13), Bqkv, 512, 4, 16);
    wsplit_rne<<<dim3(16,8), blk,0,stream>>>(GETP(25), Bf1, 2048, 0, 16);
    wsplit_rne<<<dim3(64,2), blk,0,stream>>>(GETP(31), Bf2,  512, 0, 64);
    wsplit_old<<<dim3(8,8),  blk,0,stream>>>(GETP(19), WTp,  512, 512);

    for (int hb = 0; hb < 2; hb++){
        const int pb = hb * PH;
        asplitT<<<dim3(64,16),blk,0,stream>>>(x, At, pb);
        // fused q/k/v (N=1536, NB=6, grid 384)
        gemm8<false><<<dim3(384),dim3(512),98304,stream>>>(At, Bqkv,
            GETP(2),GETP(8),GETP(14),  GETP(3),GETP(9),GETP(15),
            GETP(4),GETP(10),GETP(16), GETP(5),GETP(11),GETP(17),
            GETP(6),GETP(12),GETP(18), qkv, 6, 1536, 511);
        attn_lif_kernel<<<dim3(4,8,16),blk,0,stream>>>(qkv, os_);
        // p stage + fused o2/f1-image production
        gemm_p<<<dim3(4,128),blk,0,stream>>>(os_, WTp,
            GETP(20),GETP(21),GETP(22),GETP(23),GETP(24), x, o2h[hb], At, pb);
        // f1 (N=2048, NB=8, grid 512, bitpacked out)
        gemm8<true><<<dim3(512),dim3(512),98304,stream>>>(At, Bf1,
            GETP(26),GETP(26),GETP(26), GETP(27),GETP(27),GETP(27),
            GETP(28),GETP(28),GETP(28), GETP(29),GETP(29),GETP(29),
            GETP(30),GETP(30),GETP(30), hhb[hb], 8, 2048, 2047);
    }
    // f2 v2: both halves, grid 512 (2 blocks/CU), fused final add -> d_out
    gemm8_f2<<<dim3(512),dim3(512),0,stream>>>(hhb[0], hhb[1], Bf2,
        GETP(32),GETP(33),GETP(34),GETP(35),GETP(36), x, o2h[0], o2h[1], (float*)d_out);
}